// Round 6
// baseline (197.081 us; speedup 1.0000x reference)
//
#include <hip/hip_runtime.h>
#include <hip/hip_bf16.h>
#include <hip/hip_fp16.h>
#include <math.h>

#define N_NODES 10000
#define DIM 128
#define N_EDGES 640000
#define BN_EPS 1e-3f

#define PART_BLOCKS 125       // 640000 / 5120
#define EDGES_PER_PART 5120   // 256 thr * 4 edges * 5 steps
#define MSG64_BLOCKS 157      // ceil(10000 / 64)
#define UPD_BLOCKS 313        // ceil(10000 / 32)

typedef _Float16 half8 __attribute__((ext_vector_type(8)));
typedef float f32x4 __attribute__((ext_vector_type(4)));

__device__ __forceinline__ float gelu_exact(float x) {
  return 0.5f * x * (1.0f + erff(x * 0.70710678f));
}

// Swizzled per-wave LDS tile: [16 rows][128 cols] f16, row stride 256 B.
__device__ __forceinline__ int lds_swz(int row, int colbyte) {
  return ((row * 256 + colbyte) ^ ((row & 7) << 4));
}

struct FoldAll {
  const float* g[4];
  const float* bb[4];
  const float* m[4];
  const float* v[4];
  const float* W[4];
  const float* bias[4];
  _Float16* pk[4];
  float* bf[4];
  int din[4];
  int S[4];  // K/32
};

// K1: grid = 169 blocks x 256 thr.
// b in [0,40): pack W fragments (f16, B-frag layout, BN-scale folded).
// b in [40,44): folded bias: bf = bias + t @ W.
// b in [44,169): per-block LDS histogram -> partial row (plain stores).
__global__ __launch_bounds__(256) void fold_hist_kernel(FoldAll fa,
                                                        const int* __restrict__ node_idx,
                                                        int* __restrict__ part) {
  __shared__ int lh[N_NODES];
  __shared__ float t_sh[256];
  __shared__ float bpart[128];
  int b = blockIdx.x, t = threadIdx.x;
  if (b >= 44) {
    int pb = b - 44;
    for (int i = t; i < N_NODES; i += 256) lh[i] = 0;
    __syncthreads();
    int base0 = pb * EDGES_PER_PART;
#pragma unroll
    for (int s = 0; s < 5; ++s) {
      int base = base0 + s * 1024 + t * 4;
      int4 vv = *reinterpret_cast<const int4*>(&node_idx[base]);
      atomicAdd(&lh[vv.x], 1);
      atomicAdd(&lh[vv.y], 1);
      atomicAdd(&lh[vv.z], 1);
      atomicAdd(&lh[vv.w], 1);
    }
    __syncthreads();
    int* prow = part + (size_t)pb * N_NODES;
    for (int i = t; i < N_NODES; i += 256) prow[i] = lh[i];
    return;
  }
  if (b >= 40) {
    int p = b - 40;
    int din = fa.din[p];
    const float* W = fa.W[p];
    for (int k = t; k < din; k += 256) {
      float sc = fa.g[p][k] * rsqrtf(fa.v[p][k] + BN_EPS);
      t_sh[k] = fa.bb[p][k] - fa.m[p][k] * sc;
    }
    __syncthreads();
    int j = t & 127, kh = t >> 7;
    int half = din >> 1;
    float acc = 0.f;
    for (int k = kh * half; k < (kh + 1) * half; ++k)
      acc = fmaf(t_sh[k], W[k * 128 + j], acc);
    if (kh == 1) bpart[j] = acc;
    __syncthreads();
    if (kh == 0) fa.bf[p][j] = acc + bpart[j] + fa.bias[p][j];
    return;
  }
  int p, lf;
  if (b < 8)       { p = 0; lf = b * 256 + t; }
  else if (b < 16) { p = 1; lf = (b - 8) * 256 + t; }
  else if (b < 32) { p = 2; lf = (b - 16) * 256 + t; }
  else             { p = 3; lf = (b - 32) * 256 + t; }
  int S = fa.S[p];
  int l = lf & 63;
  int fs = lf >> 6;
  int f = fs & 7, s = fs >> 3;
  if (s >= S) return;
  const float* W = fa.W[p];
  const float* g = fa.g[p];
  const float* v = fa.v[p];
  int k0 = s * 32 + (l >> 4) * 8;
  int col = f * 16 + (l & 15);
  half8 h;
#pragma unroll
  for (int i = 0; i < 8; ++i) {
    int k = k0 + i;
    float sc = g[k] * rsqrtf(v[k] + BN_EPS);
    h[i] = (_Float16)(sc * W[k * 128 + col]);
  }
  *reinterpret_cast<half8*>(fa.pk[p] + (size_t)lf * 8) = h;
}

// K2: grid = 197 blocks x 256 thr.
// b in [0,40): merge — per bin, prefix over 125 partials (chunked independent
//   loads), total -> hist[bin].
// b in [40,197): per-node message via f16 MFMA, 4 waves x 16 rows.
__global__ __launch_bounds__(256) void merge_msg_kernel(
    int* __restrict__ part, int* __restrict__ hist,
    const float* __restrict__ x,
    const _Float16* __restrict__ W1pk, const float* __restrict__ b1f,
    const _Float16* __restrict__ W2pk, const float* __restrict__ b2f,
    _Float16* __restrict__ M) {
  __shared__ char lds_raw[4 * 4096];
  int b = blockIdx.x, t = threadIdx.x;
  if (b < 40) {
    int bin = b * 256 + t;
    if (bin >= N_NODES) return;
    int sum = 0;
#pragma unroll
    for (int c = 0; c < PART_BLOCKS; c += 25) {
      int vals[25];
#pragma unroll
      for (int i = 0; i < 25; ++i) vals[i] = part[(size_t)(c + i) * N_NODES + bin];
#pragma unroll
      for (int i = 0; i < 25; ++i) {
        part[(size_t)(c + i) * N_NODES + bin] = sum;
        sum += vals[i];
      }
    }
    hist[bin] = sum;
    return;
  }
  int wid = t >> 6, lane = t & 63;
  int r = lane & 15, g = lane >> 4;
  int row0 = (b - 40) * 64 + wid * 16;
  char* lbase = lds_raw + wid * 4096;

  int arow = row0 + r;
  if (arow > N_NODES - 1) arow = N_NODES - 1;
  const float* xp = x + (size_t)arow * DIM;

  half8 a[4];
#pragma unroll
  for (int s = 0; s < 4; ++s) {
    float4 lo = *reinterpret_cast<const float4*>(xp + s * 32 + g * 8);
    float4 hi = *reinterpret_cast<const float4*>(xp + s * 32 + g * 8 + 4);
    half8 h;
    h[0] = (_Float16)lo.x; h[1] = (_Float16)lo.y; h[2] = (_Float16)lo.z; h[3] = (_Float16)lo.w;
    h[4] = (_Float16)hi.x; h[5] = (_Float16)hi.y; h[6] = (_Float16)hi.z; h[7] = (_Float16)hi.w;
    a[s] = h;
  }

  f32x4 zero = {0.f, 0.f, 0.f, 0.f};
  f32x4 acc[8];
#pragma unroll
  for (int f = 0; f < 8; ++f) acc[f] = zero;
#pragma unroll
  for (int f = 0; f < 8; ++f)
#pragma unroll
    for (int s = 0; s < 4; ++s) {
      half8 bfrag = *reinterpret_cast<const half8*>(W1pk + (size_t)((s * 8 + f) * 64 + lane) * 8);
      acc[f] = __builtin_amdgcn_mfma_f32_16x16x32_f16(a[s], bfrag, acc[f], 0, 0, 0);
    }

#pragma unroll
  for (int f = 0; f < 8; ++f) {
    int col = f * 16 + r;
    float bv = b1f[col];
#pragma unroll
    for (int j = 0; j < 4; ++j) {
      int rl = g * 4 + j;
      float gv = gelu_exact(acc[f][j] + bv);
      *reinterpret_cast<_Float16*>(lbase + lds_swz(rl, col * 2)) = (_Float16)gv;
    }
  }

  half8 a2[4];
#pragma unroll
  for (int s = 0; s < 4; ++s)
    a2[s] = *reinterpret_cast<const half8*>(lbase + lds_swz(r, (s * 32 + g * 8) * 2));

  f32x4 acc2[8];
#pragma unroll
  for (int f = 0; f < 8; ++f) acc2[f] = zero;
#pragma unroll
  for (int f = 0; f < 8; ++f)
#pragma unroll
    for (int s = 0; s < 4; ++s) {
      half8 bfrag = *reinterpret_cast<const half8*>(W2pk + (size_t)((s * 8 + f) * 64 + lane) * 8);
      acc2[f] = __builtin_amdgcn_mfma_f32_16x16x32_f16(a2[s], bfrag, acc2[f], 0, 0, 0);
    }

#pragma unroll
  for (int f = 0; f < 8; ++f) {
    int col = f * 16 + r;
    float bv = b2f[col];
#pragma unroll
    for (int j = 0; j < 4; ++j) {
      int grow = row0 + g * 4 + j;
      if (grow < N_NODES)
        M[(size_t)grow * DIM + col] = (_Float16)gelu_exact(acc2[f][j] + bv);
    }
  }
}

// One block, 256 threads, each owns 40 contiguous elements.
__global__ __launch_bounds__(256) void scan_kernel(const int* __restrict__ hist,
                                                   int* __restrict__ row_start, int n) {
  const int PER = 40;
  __shared__ int sums[256];
  int t = threadIdx.x;
  int i0 = t * PER;
  int total = 0;
  for (int i = 0; i < PER; ++i) {
    int idx = i0 + i;
    total += (idx < n) ? hist[idx] : 0;
  }
  sums[t] = total;
  __syncthreads();
  for (int off = 1; off < 256; off <<= 1) {
    int v = (t >= off) ? sums[t - off] : 0;
    __syncthreads();
    sums[t] += v;
    __syncthreads();
  }
  int running = sums[t] - total;
  for (int i = 0; i < PER; ++i) {
    int idx = i0 + i;
    if (idx < n) {
      row_start[idx] = running;
      running += hist[idx];
    }
  }
  if (t == 255) row_start[n] = sums[255];
}

// Scatter with LDS-only atomics: cursor[d] = row_start[d] + part[b][d].
__global__ __launch_bounds__(256) void scatter_kernel(
    const int* __restrict__ node_idx, const int* __restrict__ nbr_idx,
    const float* __restrict__ ew, const int* __restrict__ row_start,
    const int* __restrict__ part, uint2* __restrict__ edge_s) {
  __shared__ int cur[N_NODES];
  int b = blockIdx.x, t = threadIdx.x;
  const int* prow = part + (size_t)b * N_NODES;
  for (int i = t; i < N_NODES; i += 256) cur[i] = row_start[i] + prow[i];
  __syncthreads();
  int base0 = b * EDGES_PER_PART;
#pragma unroll
  for (int s = 0; s < 5; ++s) {
    int base = base0 + s * 1024 + t * 4;
    int4 ni = *reinterpret_cast<const int4*>(&node_idx[base]);
    int4 nb = *reinterpret_cast<const int4*>(&nbr_idx[base]);
    float4 wv = *reinterpret_cast<const float4*>(&ew[base]);
    int p0 = atomicAdd(&cur[ni.x], 1);
    edge_s[p0] = make_uint2((unsigned)nb.x, __float_as_uint(wv.x));
    int p1 = atomicAdd(&cur[ni.y], 1);
    edge_s[p1] = make_uint2((unsigned)nb.y, __float_as_uint(wv.y));
    int p2 = atomicAdd(&cur[ni.z], 1);
    edge_s[p2] = make_uint2((unsigned)nb.z, __float_as_uint(wv.z));
    int p3 = atomicAdd(&cur[ni.w], 1);
    edge_s[p3] = make_uint2((unsigned)nb.w, __float_as_uint(wv.w));
  }
}

// agg[i] = (sum over CSR row i of w_e * M[nbr_e]) / max(cnt,1)
// 2-deep software pipeline: edges prefetched 2 iters ahead, M row 1 iter ahead.
__global__ __launch_bounds__(256) void spmm_kernel(
    const int* __restrict__ row_start, const uint2* __restrict__ edge_s,
    const __half* __restrict__ M, float* __restrict__ agg) {
  __shared__ float4 red4[8][32];
  int i = blockIdx.x;
  int t = threadIdx.x;
  int cg = t & 31;
  int slice = t >> 5;
  int s = row_start[i];
  int e_end = row_start[i + 1];

  float a0 = 0.f, a1 = 0.f, a2 = 0.f, a3 = 0.f;
  int e = s + slice;
  if (e < e_end) {
    uint2 pk0 = edge_s[e];
    uint2 pk1 = (e + 8 < e_end) ? edge_s[e + 8] : pk0;
    uint2 raw0 = *reinterpret_cast<const uint2*>(M + (size_t)pk0.x * DIM + cg * 4);
    for (; e < e_end; e += 8) {
      uint2 pk2 = (e + 16 < e_end) ? edge_s[e + 16] : pk1;
      uint2 raw1 = (e + 8 < e_end)
                       ? *reinterpret_cast<const uint2*>(M + (size_t)pk1.x * DIM + cg * 4)
                       : raw0;
      float w = __uint_as_float(pk0.y);
      __half2 h01 = *reinterpret_cast<__half2*>(&raw0.x);
      __half2 h23 = *reinterpret_cast<__half2*>(&raw0.y);
      float2 f01 = __half22float2(h01);
      float2 f23 = __half22float2(h23);
      a0 = fmaf(w, f01.x, a0);
      a1 = fmaf(w, f01.y, a1);
      a2 = fmaf(w, f23.x, a2);
      a3 = fmaf(w, f23.y, a3);
      pk0 = pk1;
      pk1 = pk2;
      raw0 = raw1;
    }
  }
  red4[slice][cg] = make_float4(a0, a1, a2, a3);
  __syncthreads();

  if (t < 128) {
    const float* redf = (const float*)red4;
    float acc = 0.f;
#pragma unroll
    for (int sl = 0; sl < 8; ++sl) acc += redf[sl * 128 + t];
    int cnt = e_end - s;
    agg[(size_t)i * DIM + t] = acc / (float)(cnt > 0 ? cnt : 1);
  }
}

// update: out = gelu(gelu([x,agg]@U1+bu1)@U2+bu2), f16 MFMA, K1=256.
__global__ __launch_bounds__(128) void update_mfma_kernel(
    const float* __restrict__ x, const float* __restrict__ agg,
    const _Float16* __restrict__ U1pk, const float* __restrict__ bu1,
    const _Float16* __restrict__ U2pk, const float* __restrict__ bu2,
    float* __restrict__ out) {
  __shared__ char lds_raw[2 * 4096];
  int t = threadIdx.x;
  int wid = t >> 6, lane = t & 63;
  int r = lane & 15, g = lane >> 4;
  int row0 = blockIdx.x * 32 + wid * 16;
  char* lbase = lds_raw + wid * 4096;

  int arow = row0 + r;
  if (arow > N_NODES - 1) arow = N_NODES - 1;
  const float* xp = x + (size_t)arow * DIM;
  const float* ap = agg + (size_t)arow * DIM;

  half8 a[8];
#pragma unroll
  for (int s = 0; s < 8; ++s) {
    const float* src = (s < 4) ? (xp + s * 32 + g * 8) : (ap + (s - 4) * 32 + g * 8);
    float4 lo = *reinterpret_cast<const float4*>(src);
    float4 hi = *reinterpret_cast<const float4*>(src + 4);
    half8 h;
    h[0] = (_Float16)lo.x; h[1] = (_Float16)lo.y; h[2] = (_Float16)lo.z; h[3] = (_Float16)lo.w;
    h[4] = (_Float16)hi.x; h[5] = (_Float16)hi.y; h[6] = (_Float16)hi.z; h[7] = (_Float16)hi.w;
    a[s] = h;
  }

  f32x4 zero = {0.f, 0.f, 0.f, 0.f};
  f32x4 acc[8];
#pragma unroll
  for (int f = 0; f < 8; ++f) acc[f] = zero;
#pragma unroll
  for (int f = 0; f < 8; ++f)
#pragma unroll
    for (int s = 0; s < 8; ++s) {
      half8 bfrag = *reinterpret_cast<const half8*>(U1pk + (size_t)((s * 8 + f) * 64 + lane) * 8);
      acc[f] = __builtin_amdgcn_mfma_f32_16x16x32_f16(a[s], bfrag, acc[f], 0, 0, 0);
    }

#pragma unroll
  for (int f = 0; f < 8; ++f) {
    int col = f * 16 + r;
    float bv = bu1[col];
#pragma unroll
    for (int j = 0; j < 4; ++j) {
      int rl = g * 4 + j;
      float gv = gelu_exact(acc[f][j] + bv);
      *reinterpret_cast<_Float16*>(lbase + lds_swz(rl, col * 2)) = (_Float16)gv;
    }
  }

  half8 a2[4];
#pragma unroll
  for (int s = 0; s < 4; ++s)
    a2[s] = *reinterpret_cast<const half8*>(lbase + lds_swz(r, (s * 32 + g * 8) * 2));

  f32x4 acc2[8];
#pragma unroll
  for (int f = 0; f < 8; ++f) acc2[f] = zero;
#pragma unroll
  for (int f = 0; f < 8; ++f)
#pragma unroll
    for (int s = 0; s < 4; ++s) {
      half8 bfrag = *reinterpret_cast<const half8*>(U2pk + (size_t)((s * 8 + f) * 64 + lane) * 8);
      acc2[f] = __builtin_amdgcn_mfma_f32_16x16x32_f16(a2[s], bfrag, acc2[f], 0, 0, 0);
    }

#pragma unroll
  for (int f = 0; f < 8; ++f) {
    int col = f * 16 + r;
    float bv = bu2[col];
#pragma unroll
    for (int j = 0; j < 4; ++j) {
      int grow = row0 + g * 4 + j;
      if (grow < N_NODES)
        out[(size_t)grow * DIM + col] = gelu_exact(acc2[f][j] + bv);
    }
  }
}

extern "C" void kernel_launch(void* const* d_in, const int* in_sizes, int n_in,
                              void* d_out, int out_size, void* d_ws, size_t ws_size,
                              hipStream_t stream) {
  const float* x = (const float*)d_in[0];
  const int* edges = (const int*)d_in[1];
  const float* ew = (const float*)d_in[2];

  const int* node_idx = edges;            // edges[0, :]
  const int* nbr_idx = edges + N_EDGES;   // edges[1, :]

  char* wsp = (char*)d_ws;
  auto alloc = [&](size_t bytes) {
    char* p = wsp;
    wsp += (bytes + 255) & ~(size_t)255;
    return p;
  };
  _Float16* M = (_Float16*)alloc((size_t)N_NODES * DIM * 2);
  float* agg = (float*)alloc((size_t)N_NODES * DIM * 4);
  _Float16* W1pk = (_Float16*)alloc(128 * 128 * 2);
  _Float16* W2pk = (_Float16*)alloc(128 * 128 * 2);
  _Float16* U1pk = (_Float16*)alloc(256 * 128 * 2);
  _Float16* U2pk = (_Float16*)alloc(128 * 128 * 2);
  float* b1f = (float*)alloc(128 * 4);
  float* b2f = (float*)alloc(128 * 4);
  float* bu1 = (float*)alloc(128 * 4);
  float* bu2 = (float*)alloc(128 * 4);
  int* hist = (int*)alloc(N_NODES * 4);
  int* row_start = (int*)alloc((N_NODES + 1) * 4);
  int* part = (int*)alloc((size_t)PART_BLOCKS * N_NODES * 4);
  uint2* edge_s = (uint2*)alloc((size_t)N_EDGES * 8);

  FoldAll fa;
  fa.g[0] = (const float*)d_in[3];  fa.bb[0] = (const float*)d_in[4];
  fa.m[0] = (const float*)d_in[5];  fa.v[0] = (const float*)d_in[6];
  fa.W[0] = (const float*)d_in[7];  fa.bias[0] = (const float*)d_in[8];
  fa.g[1] = (const float*)d_in[9];  fa.bb[1] = (const float*)d_in[10];
  fa.m[1] = (const float*)d_in[11]; fa.v[1] = (const float*)d_in[12];
  fa.W[1] = (const float*)d_in[13]; fa.bias[1] = (const float*)d_in[14];
  fa.g[2] = (const float*)d_in[15]; fa.bb[2] = (const float*)d_in[16];
  fa.m[2] = (const float*)d_in[17]; fa.v[2] = (const float*)d_in[18];
  fa.W[2] = (const float*)d_in[19]; fa.bias[2] = (const float*)d_in[20];
  fa.g[3] = (const float*)d_in[21]; fa.bb[3] = (const float*)d_in[22];
  fa.m[3] = (const float*)d_in[23]; fa.v[3] = (const float*)d_in[24];
  fa.W[3] = (const float*)d_in[25]; fa.bias[3] = (const float*)d_in[26];
  fa.pk[0] = W1pk; fa.pk[1] = W2pk; fa.pk[2] = U1pk; fa.pk[3] = U2pk;
  fa.bf[0] = b1f; fa.bf[1] = b2f; fa.bf[2] = bu1; fa.bf[3] = bu2;
  fa.din[0] = 128; fa.din[1] = 128; fa.din[2] = 256; fa.din[3] = 128;
  fa.S[0] = 4; fa.S[1] = 4; fa.S[2] = 8; fa.S[3] = 4;

  fold_hist_kernel<<<44 + PART_BLOCKS, 256, 0, stream>>>(fa, node_idx, part);
  merge_msg_kernel<<<40 + MSG64_BLOCKS, 256, 0, stream>>>(
      part, hist, x, W1pk, b1f, W2pk, b2f, M);
  scan_kernel<<<1, 256, 0, stream>>>(hist, row_start, N_NODES);
  scatter_kernel<<<PART_BLOCKS, 256, 0, stream>>>(node_idx, nbr_idx, ew, row_start, part, edge_s);
  spmm_kernel<<<N_NODES, 256, 0, stream>>>(row_start, edge_s, (const __half*)M, agg);
  update_mfma_kernel<<<UPD_BLOCKS, 128, 0, stream>>>(
      x, agg, U1pk, bu1, U2pk, bu2, (float*)d_out);
}

// Round 7
// 156.025 us; speedup vs baseline: 1.2631x; 1.2631x over previous
//
#include <hip/hip_runtime.h>
#include <hip/hip_bf16.h>
#include <hip/hip_fp16.h>
#include <math.h>

#define N_NODES 10000
#define DIM 128
#define N_EDGES 640000
#define BN_EPS 1e-3f

#define PART_BLOCKS 125       // 640000 / 5120
#define EDGES_PER_PART 5120   // 256 thr * 4 edges * 5 steps
#define MSG64_BLOCKS 157      // ceil(10000 / 64)
#define UPD_BLOCKS 313        // ceil(10000 / 32)

typedef _Float16 half8 __attribute__((ext_vector_type(8)));
typedef float f32x4 __attribute__((ext_vector_type(4)));

__device__ __forceinline__ float gelu_exact(float x) {
  return 0.5f * x * (1.0f + erff(x * 0.70710678f));
}

// Swizzled per-wave LDS tile: [16 rows][128 cols] f16, row stride 256 B.
__device__ __forceinline__ int lds_swz(int row, int colbyte) {
  return ((row * 256 + colbyte) ^ ((row & 7) << 4));
}

struct FoldAll {
  const float* g[4];
  const float* bb[4];
  const float* m[4];
  const float* v[4];
  const float* W[4];
  const float* bias[4];
  _Float16* pk[4];
  float* bf[4];
  int din[4];
  int S[4];  // K/32
};

// K1: grid = 169 blocks x 256 thr.
// b in [0,40): pack W fragments (f16, B-frag layout, BN-scale folded).
// b in [40,44): folded bias: bf = bias + t @ W.
// b in [44,169): per-block LDS histogram -> partial row (plain stores).
__global__ __launch_bounds__(256) void fold_hist_kernel(FoldAll fa,
                                                        const int* __restrict__ node_idx,
                                                        int* __restrict__ part) {
  __shared__ int lh[N_NODES];
  __shared__ float t_sh[256];
  __shared__ float bpart[128];
  int b = blockIdx.x, t = threadIdx.x;
  if (b >= 44) {
    int pb = b - 44;
    for (int i = t; i < N_NODES; i += 256) lh[i] = 0;
    __syncthreads();
    int base0 = pb * EDGES_PER_PART;
#pragma unroll
    for (int s = 0; s < 5; ++s) {
      int base = base0 + s * 1024 + t * 4;
      int4 vv = *reinterpret_cast<const int4*>(&node_idx[base]);
      atomicAdd(&lh[vv.x], 1);
      atomicAdd(&lh[vv.y], 1);
      atomicAdd(&lh[vv.z], 1);
      atomicAdd(&lh[vv.w], 1);
    }
    __syncthreads();
    int* prow = part + (size_t)pb * N_NODES;
    for (int i = t; i < N_NODES; i += 256) prow[i] = lh[i];
    return;
  }
  if (b >= 40) {
    int p = b - 40;
    int din = fa.din[p];
    const float* W = fa.W[p];
    for (int k = t; k < din; k += 256) {
      float sc = fa.g[p][k] * rsqrtf(fa.v[p][k] + BN_EPS);
      t_sh[k] = fa.bb[p][k] - fa.m[p][k] * sc;
    }
    __syncthreads();
    int j = t & 127, kh = t >> 7;
    int half = din >> 1;
    float acc = 0.f;
    for (int k = kh * half; k < (kh + 1) * half; ++k)
      acc = fmaf(t_sh[k], W[k * 128 + j], acc);
    if (kh == 1) bpart[j] = acc;
    __syncthreads();
    if (kh == 0) fa.bf[p][j] = acc + bpart[j] + fa.bias[p][j];
    return;
  }
  int p, lf;
  if (b < 8)       { p = 0; lf = b * 256 + t; }
  else if (b < 16) { p = 1; lf = (b - 8) * 256 + t; }
  else if (b < 32) { p = 2; lf = (b - 16) * 256 + t; }
  else             { p = 3; lf = (b - 32) * 256 + t; }
  int S = fa.S[p];
  int l = lf & 63;
  int fs = lf >> 6;
  int f = fs & 7, s = fs >> 3;
  if (s >= S) return;
  const float* W = fa.W[p];
  const float* g = fa.g[p];
  const float* v = fa.v[p];
  int k0 = s * 32 + (l >> 4) * 8;
  int col = f * 16 + (l & 15);
  half8 h;
#pragma unroll
  for (int i = 0; i < 8; ++i) {
    int k = k0 + i;
    float sc = g[k] * rsqrtf(v[k] + BN_EPS);
    h[i] = (_Float16)(sc * W[k * 128 + col]);
  }
  *reinterpret_cast<half8*>(fa.pk[p] + (size_t)lf * 8) = h;
}

// K2: grid = 197 blocks x 256 thr.
// b in [0,40): merge — per bin, prefix over 125 partials (chunked independent
//   loads), total -> hist[bin].
// b in [40,197): per-node message via f16 MFMA, 4 waves x 16 rows.
__global__ __launch_bounds__(256) void merge_msg_kernel(
    int* __restrict__ part, int* __restrict__ hist,
    const float* __restrict__ x,
    const _Float16* __restrict__ W1pk, const float* __restrict__ b1f,
    const _Float16* __restrict__ W2pk, const float* __restrict__ b2f,
    _Float16* __restrict__ M) {
  __shared__ char lds_raw[4 * 4096];
  int b = blockIdx.x, t = threadIdx.x;
  if (b < 40) {
    int bin = b * 256 + t;
    if (bin >= N_NODES) return;
    int sum = 0;
#pragma unroll
    for (int c = 0; c < PART_BLOCKS; c += 25) {
      int vals[25];
#pragma unroll
      for (int i = 0; i < 25; ++i) vals[i] = part[(size_t)(c + i) * N_NODES + bin];
#pragma unroll
      for (int i = 0; i < 25; ++i) {
        part[(size_t)(c + i) * N_NODES + bin] = sum;
        sum += vals[i];
      }
    }
    hist[bin] = sum;
    return;
  }
  int wid = t >> 6, lane = t & 63;
  int r = lane & 15, g = lane >> 4;
  int row0 = (b - 40) * 64 + wid * 16;
  char* lbase = lds_raw + wid * 4096;

  int arow = row0 + r;
  if (arow > N_NODES - 1) arow = N_NODES - 1;
  const float* xp = x + (size_t)arow * DIM;

  half8 a[4];
#pragma unroll
  for (int s = 0; s < 4; ++s) {
    float4 lo = *reinterpret_cast<const float4*>(xp + s * 32 + g * 8);
    float4 hi = *reinterpret_cast<const float4*>(xp + s * 32 + g * 8 + 4);
    half8 h;
    h[0] = (_Float16)lo.x; h[1] = (_Float16)lo.y; h[2] = (_Float16)lo.z; h[3] = (_Float16)lo.w;
    h[4] = (_Float16)hi.x; h[5] = (_Float16)hi.y; h[6] = (_Float16)hi.z; h[7] = (_Float16)hi.w;
    a[s] = h;
  }

  f32x4 zero = {0.f, 0.f, 0.f, 0.f};
  f32x4 acc[8];
#pragma unroll
  for (int f = 0; f < 8; ++f) acc[f] = zero;
#pragma unroll
  for (int f = 0; f < 8; ++f)
#pragma unroll
    for (int s = 0; s < 4; ++s) {
      half8 bfrag = *reinterpret_cast<const half8*>(W1pk + (size_t)((s * 8 + f) * 64 + lane) * 8);
      acc[f] = __builtin_amdgcn_mfma_f32_16x16x32_f16(a[s], bfrag, acc[f], 0, 0, 0);
    }

#pragma unroll
  for (int f = 0; f < 8; ++f) {
    int col = f * 16 + r;
    float bv = b1f[col];
#pragma unroll
    for (int j = 0; j < 4; ++j) {
      int rl = g * 4 + j;
      float gv = gelu_exact(acc[f][j] + bv);
      *reinterpret_cast<_Float16*>(lbase + lds_swz(rl, col * 2)) = (_Float16)gv;
    }
  }

  half8 a2[4];
#pragma unroll
  for (int s = 0; s < 4; ++s)
    a2[s] = *reinterpret_cast<const half8*>(lbase + lds_swz(r, (s * 32 + g * 8) * 2));

  f32x4 acc2[8];
#pragma unroll
  for (int f = 0; f < 8; ++f) acc2[f] = zero;
#pragma unroll
  for (int f = 0; f < 8; ++f)
#pragma unroll
    for (int s = 0; s < 4; ++s) {
      half8 bfrag = *reinterpret_cast<const half8*>(W2pk + (size_t)((s * 8 + f) * 64 + lane) * 8);
      acc2[f] = __builtin_amdgcn_mfma_f32_16x16x32_f16(a2[s], bfrag, acc2[f], 0, 0, 0);
    }

#pragma unroll
  for (int f = 0; f < 8; ++f) {
    int col = f * 16 + r;
    float bv = b2f[col];
#pragma unroll
    for (int j = 0; j < 4; ++j) {
      int grow = row0 + g * 4 + j;
      if (grow < N_NODES)
        M[(size_t)grow * DIM + col] = (_Float16)gelu_exact(acc2[f][j] + bv);
    }
  }
}

// One block, 256 threads, each owns 40 contiguous elements.
__global__ __launch_bounds__(256) void scan_kernel(const int* __restrict__ hist,
                                                   int* __restrict__ row_start, int n) {
  const int PER = 40;
  __shared__ int sums[256];
  int t = threadIdx.x;
  int i0 = t * PER;
  int total = 0;
  for (int i = 0; i < PER; ++i) {
    int idx = i0 + i;
    total += (idx < n) ? hist[idx] : 0;
  }
  sums[t] = total;
  __syncthreads();
  for (int off = 1; off < 256; off <<= 1) {
    int v = (t >= off) ? sums[t - off] : 0;
    __syncthreads();
    sums[t] += v;
    __syncthreads();
  }
  int running = sums[t] - total;
  for (int i = 0; i < PER; ++i) {
    int idx = i0 + i;
    if (idx < n) {
      row_start[idx] = running;
      running += hist[idx];
    }
  }
  if (t == 255) row_start[n] = sums[255];
}

// Scatter with LDS-only atomics: cursor[d] = row_start[d] + part[b][d].
__global__ __launch_bounds__(256) void scatter_kernel(
    const int* __restrict__ node_idx, const int* __restrict__ nbr_idx,
    const float* __restrict__ ew, const int* __restrict__ row_start,
    const int* __restrict__ part, uint2* __restrict__ edge_s) {
  __shared__ int cur[N_NODES];
  int b = blockIdx.x, t = threadIdx.x;
  const int* prow = part + (size_t)b * N_NODES;
  for (int i = t; i < N_NODES; i += 256) cur[i] = row_start[i] + prow[i];
  __syncthreads();
  int base0 = b * EDGES_PER_PART;
#pragma unroll
  for (int s = 0; s < 5; ++s) {
    int base = base0 + s * 1024 + t * 4;
    int4 ni = *reinterpret_cast<const int4*>(&node_idx[base]);
    int4 nb = *reinterpret_cast<const int4*>(&nbr_idx[base]);
    float4 wv = *reinterpret_cast<const float4*>(&ew[base]);
    int p0 = atomicAdd(&cur[ni.x], 1);
    edge_s[p0] = make_uint2((unsigned)nb.x, __float_as_uint(wv.x));
    int p1 = atomicAdd(&cur[ni.y], 1);
    edge_s[p1] = make_uint2((unsigned)nb.y, __float_as_uint(wv.y));
    int p2 = atomicAdd(&cur[ni.z], 1);
    edge_s[p2] = make_uint2((unsigned)nb.z, __float_as_uint(wv.z));
    int p3 = atomicAdd(&cur[ni.w], 1);
    edge_s[p3] = make_uint2((unsigned)nb.w, __float_as_uint(wv.w));
  }
}

// agg[i] = (sum over CSR row i of w_e * M[nbr_e]) / max(cnt,1)
// Batched gathers: 64 edges per outer iter (8 per slice); all edge loads
// issued first (independent), then all 8 M-row gathers (independent), then
// FMAs. Out-of-range lanes clamp to a valid address with weight forced to 0,
// so every load is unconditional -> deep VMEM queue instead of serial chain.
__global__ __launch_bounds__(256) void spmm_kernel(
    const int* __restrict__ row_start, const uint2* __restrict__ edge_s,
    const __half* __restrict__ M, float* __restrict__ agg) {
  __shared__ float4 red4[8][32];
  int i = blockIdx.x;
  int t = threadIdx.x;
  int cg = t & 31;
  int slice = t >> 5;
  int s = row_start[i];
  int e_end = row_start[i + 1];

  float a0 = 0.f, a1 = 0.f, a2 = 0.f, a3 = 0.f;
  for (int base = s; base < e_end; base += 64) {
    uint2 pk[8];
#pragma unroll
    for (int k = 0; k < 8; ++k) {
      int e = base + slice + k * 8;
      pk[k] = edge_s[(e < e_end) ? e : s];
      if (e >= e_end) pk[k].y = 0u;  // weight = 0 for padded lanes
    }
    uint2 raw[8];
#pragma unroll
    for (int k = 0; k < 8; ++k)
      raw[k] = *reinterpret_cast<const uint2*>(M + (size_t)pk[k].x * DIM + cg * 4);
#pragma unroll
    for (int k = 0; k < 8; ++k) {
      float w = __uint_as_float(pk[k].y);
      __half2 h01 = *reinterpret_cast<__half2*>(&raw[k].x);
      __half2 h23 = *reinterpret_cast<__half2*>(&raw[k].y);
      float2 f01 = __half22float2(h01);
      float2 f23 = __half22float2(h23);
      a0 = fmaf(w, f01.x, a0);
      a1 = fmaf(w, f01.y, a1);
      a2 = fmaf(w, f23.x, a2);
      a3 = fmaf(w, f23.y, a3);
    }
  }
  red4[slice][cg] = make_float4(a0, a1, a2, a3);
  __syncthreads();

  if (t < 128) {
    const float* redf = (const float*)red4;
    float acc = 0.f;
#pragma unroll
    for (int sl = 0; sl < 8; ++sl) acc += redf[sl * 128 + t];
    int cnt = e_end - s;
    agg[(size_t)i * DIM + t] = acc / (float)(cnt > 0 ? cnt : 1);
  }
}

// update: out = gelu(gelu([x,agg]@U1+bu1)@U2+bu2), f16 MFMA, K1=256.
__global__ __launch_bounds__(128) void update_mfma_kernel(
    const float* __restrict__ x, const float* __restrict__ agg,
    const _Float16* __restrict__ U1pk, const float* __restrict__ bu1,
    const _Float16* __restrict__ U2pk, const float* __restrict__ bu2,
    float* __restrict__ out) {
  __shared__ char lds_raw[2 * 4096];
  int t = threadIdx.x;
  int wid = t >> 6, lane = t & 63;
  int r = lane & 15, g = lane >> 4;
  int row0 = blockIdx.x * 32 + wid * 16;
  char* lbase = lds_raw + wid * 4096;

  int arow = row0 + r;
  if (arow > N_NODES - 1) arow = N_NODES - 1;
  const float* xp = x + (size_t)arow * DIM;
  const float* ap = agg + (size_t)arow * DIM;

  half8 a[8];
#pragma unroll
  for (int s = 0; s < 8; ++s) {
    const float* src = (s < 4) ? (xp + s * 32 + g * 8) : (ap + (s - 4) * 32 + g * 8);
    float4 lo = *reinterpret_cast<const float4*>(src);
    float4 hi = *reinterpret_cast<const float4*>(src + 4);
    half8 h;
    h[0] = (_Float16)lo.x; h[1] = (_Float16)lo.y; h[2] = (_Float16)lo.z; h[3] = (_Float16)lo.w;
    h[4] = (_Float16)hi.x; h[5] = (_Float16)hi.y; h[6] = (_Float16)hi.z; h[7] = (_Float16)hi.w;
    a[s] = h;
  }

  f32x4 zero = {0.f, 0.f, 0.f, 0.f};
  f32x4 acc[8];
#pragma unroll
  for (int f = 0; f < 8; ++f) acc[f] = zero;
#pragma unroll
  for (int f = 0; f < 8; ++f)
#pragma unroll
    for (int s = 0; s < 8; ++s) {
      half8 bfrag = *reinterpret_cast<const half8*>(U1pk + (size_t)((s * 8 + f) * 64 + lane) * 8);
      acc[f] = __builtin_amdgcn_mfma_f32_16x16x32_f16(a[s], bfrag, acc[f], 0, 0, 0);
    }

#pragma unroll
  for (int f = 0; f < 8; ++f) {
    int col = f * 16 + r;
    float bv = bu1[col];
#pragma unroll
    for (int j = 0; j < 4; ++j) {
      int rl = g * 4 + j;
      float gv = gelu_exact(acc[f][j] + bv);
      *reinterpret_cast<_Float16*>(lbase + lds_swz(rl, col * 2)) = (_Float16)gv;
    }
  }

  half8 a2[4];
#pragma unroll
  for (int s = 0; s < 4; ++s)
    a2[s] = *reinterpret_cast<const half8*>(lbase + lds_swz(r, (s * 32 + g * 8) * 2));

  f32x4 acc2[8];
#pragma unroll
  for (int f = 0; f < 8; ++f) acc2[f] = zero;
#pragma unroll
  for (int f = 0; f < 8; ++f)
#pragma unroll
    for (int s = 0; s < 4; ++s) {
      half8 bfrag = *reinterpret_cast<const half8*>(U2pk + (size_t)((s * 8 + f) * 64 + lane) * 8);
      acc2[f] = __builtin_amdgcn_mfma_f32_16x16x32_f16(a2[s], bfrag, acc2[f], 0, 0, 0);
    }

#pragma unroll
  for (int f = 0; f < 8; ++f) {
    int col = f * 16 + r;
    float bv = bu2[col];
#pragma unroll
    for (int j = 0; j < 4; ++j) {
      int grow = row0 + g * 4 + j;
      if (grow < N_NODES)
        out[(size_t)grow * DIM + col] = gelu_exact(acc2[f][j] + bv);
    }
  }
}

extern "C" void kernel_launch(void* const* d_in, const int* in_sizes, int n_in,
                              void* d_out, int out_size, void* d_ws, size_t ws_size,
                              hipStream_t stream) {
  const float* x = (const float*)d_in[0];
  const int* edges = (const int*)d_in[1];
  const float* ew = (const float*)d_in[2];

  const int* node_idx = edges;            // edges[0, :]
  const int* nbr_idx = edges + N_EDGES;   // edges[1, :]

  char* wsp = (char*)d_ws;
  auto alloc = [&](size_t bytes) {
    char* p = wsp;
    wsp += (bytes + 255) & ~(size_t)255;
    return p;
  };
  _Float16* M = (_Float16*)alloc((size_t)N_NODES * DIM * 2);
  float* agg = (float*)alloc((size_t)N_NODES * DIM * 4);
  _Float16* W1pk = (_Float16*)alloc(128 * 128 * 2);
  _Float16* W2pk = (_Float16*)alloc(128 * 128 * 2);
  _Float16* U1pk = (_Float16*)alloc(256 * 128 * 2);
  _Float16* U2pk = (_Float16*)alloc(128 * 128 * 2);
  float* b1f = (float*)alloc(128 * 4);
  float* b2f = (float*)alloc(128 * 4);
  float* bu1 = (float*)alloc(128 * 4);
  float* bu2 = (float*)alloc(128 * 4);
  int* hist = (int*)alloc(N_NODES * 4);
  int* row_start = (int*)alloc((N_NODES + 1) * 4);
  int* part = (int*)alloc((size_t)PART_BLOCKS * N_NODES * 4);
  uint2* edge_s = (uint2*)alloc((size_t)N_EDGES * 8);

  FoldAll fa;
  fa.g[0] = (const float*)d_in[3];  fa.bb[0] = (const float*)d_in[4];
  fa.m[0] = (const float*)d_in[5];  fa.v[0] = (const float*)d_in[6];
  fa.W[0] = (const float*)d_in[7];  fa.bias[0] = (const float*)d_in[8];
  fa.g[1] = (const float*)d_in[9];  fa.bb[1] = (const float*)d_in[10];
  fa.m[1] = (const float*)d_in[11]; fa.v[1] = (const float*)d_in[12];
  fa.W[1] = (const float*)d_in[13]; fa.bias[1] = (const float*)d_in[14];
  fa.g[2] = (const float*)d_in[15]; fa.bb[2] = (const float*)d_in[16];
  fa.m[2] = (const float*)d_in[17]; fa.v[2] = (const float*)d_in[18];
  fa.W[2] = (const float*)d_in[19]; fa.bias[2] = (const float*)d_in[20];
  fa.g[3] = (const float*)d_in[21]; fa.bb[3] = (const float*)d_in[22];
  fa.m[3] = (const float*)d_in[23]; fa.v[3] = (const float*)d_in[24];
  fa.W[3] = (const float*)d_in[25]; fa.bias[3] = (const float*)d_in[26];
  fa.pk[0] = W1pk; fa.pk[1] = W2pk; fa.pk[2] = U1pk; fa.pk[3] = U2pk;
  fa.bf[0] = b1f; fa.bf[1] = b2f; fa.bf[2] = bu1; fa.bf[3] = bu2;
  fa.din[0] = 128; fa.din[1] = 128; fa.din[2] = 256; fa.din[3] = 128;
  fa.S[0] = 4; fa.S[1] = 4; fa.S[2] = 8; fa.S[3] = 4;

  fold_hist_kernel<<<44 + PART_BLOCKS, 256, 0, stream>>>(fa, node_idx, part);
  merge_msg_kernel<<<40 + MSG64_BLOCKS, 256, 0, stream>>>(
      part, hist, x, W1pk, b1f, W2pk, b2f, M);
  scan_kernel<<<1, 256, 0, stream>>>(hist, row_start, N_NODES);
  scatter_kernel<<<PART_BLOCKS, 256, 0, stream>>>(node_idx, nbr_idx, ew, row_start, part, edge_s);
  spmm_kernel<<<N_NODES, 256, 0, stream>>>(row_start, edge_s, (const __half*)M, agg);
  update_mfma_kernel<<<UPD_BLOCKS, 128, 0, stream>>>(
      x, agg, U1pk, bu1, U2pk, bu2, (float*)d_out);
}

// Round 8
// 138.218 us; speedup vs baseline: 1.4259x; 1.1288x over previous
//
#include <hip/hip_runtime.h>
#include <hip/hip_bf16.h>
#include <hip/hip_fp16.h>
#include <math.h>

#define N_NODES 10000
#define DIM 128
#define N_EDGES 640000
#define BN_EPS 1e-3f

#define PART_BLOCKS 125       // 640000 / 5120
#define EDGES_PER_PART 5120   // 256 thr * 4 edges * 5 steps
#define MSG64_BLOCKS 157      // ceil(10000 / 64)
#define SU_BLOCKS 313         // ceil(10000 / 32)

typedef _Float16 half8 __attribute__((ext_vector_type(8)));
typedef float f32x4 __attribute__((ext_vector_type(4)));

__device__ __forceinline__ float gelu_exact(float x) {
  return 0.5f * x * (1.0f + erff(x * 0.70710678f));
}

// Swizzled per-wave LDS tile: [16 rows][128 cols] f16, row stride 256 B.
__device__ __forceinline__ int lds_swz(int row, int colbyte) {
  return ((row * 256 + colbyte) ^ ((row & 7) << 4));
}

struct FoldAll {
  const float* g[4];
  const float* bb[4];
  const float* m[4];
  const float* v[4];
  const float* W[4];
  const float* bias[4];
  _Float16* pk[4];
  float* bf[4];
  int din[4];
  int S[4];  // K/32
};

// K1: grid = 169 blocks x 256 thr.
// b in [0,40): pack W fragments (f16, B-frag layout, BN-scale folded).
// b in [40,44): folded bias: bf = bias + t @ W.
// b in [44,169): per-block LDS histogram -> u16 partial row (plain stores).
__global__ __launch_bounds__(256) void fold_hist_kernel(FoldAll fa,
                                                        const int* __restrict__ node_idx,
                                                        unsigned short* __restrict__ part) {
  __shared__ int lh[N_NODES];
  __shared__ float t_sh[256];
  __shared__ float bpart[128];
  int b = blockIdx.x, t = threadIdx.x;
  if (b >= 44) {
    int pb = b - 44;
    for (int i = t; i < N_NODES; i += 256) lh[i] = 0;
    __syncthreads();
    int base0 = pb * EDGES_PER_PART;
#pragma unroll
    for (int s = 0; s < 5; ++s) {
      int base = base0 + s * 1024 + t * 4;
      int4 vv = *reinterpret_cast<const int4*>(&node_idx[base]);
      atomicAdd(&lh[vv.x], 1);
      atomicAdd(&lh[vv.y], 1);
      atomicAdd(&lh[vv.z], 1);
      atomicAdd(&lh[vv.w], 1);
    }
    __syncthreads();
    unsigned short* prow = part + (size_t)pb * N_NODES;
    for (int i = t; i < N_NODES; i += 256) prow[i] = (unsigned short)lh[i];
    return;
  }
  if (b >= 40) {
    int p = b - 40;
    int din = fa.din[p];
    const float* W = fa.W[p];
    for (int k = t; k < din; k += 256) {
      float sc = fa.g[p][k] * rsqrtf(fa.v[p][k] + BN_EPS);
      t_sh[k] = fa.bb[p][k] - fa.m[p][k] * sc;
    }
    __syncthreads();
    int j = t & 127, kh = t >> 7;
    int half = din >> 1;
    float acc = 0.f;
    for (int k = kh * half; k < (kh + 1) * half; ++k)
      acc = fmaf(t_sh[k], W[k * 128 + j], acc);
    if (kh == 1) bpart[j] = acc;
    __syncthreads();
    if (kh == 0) fa.bf[p][j] = acc + bpart[j] + fa.bias[p][j];
    return;
  }
  int p, lf;
  if (b < 8)       { p = 0; lf = b * 256 + t; }
  else if (b < 16) { p = 1; lf = (b - 8) * 256 + t; }
  else if (b < 32) { p = 2; lf = (b - 16) * 256 + t; }
  else             { p = 3; lf = (b - 32) * 256 + t; }
  int S = fa.S[p];
  int l = lf & 63;
  int fs = lf >> 6;
  int f = fs & 7, s = fs >> 3;
  if (s >= S) return;
  const float* W = fa.W[p];
  const float* g = fa.g[p];
  const float* v = fa.v[p];
  int k0 = s * 32 + (l >> 4) * 8;
  int col = f * 16 + (l & 15);
  half8 h;
#pragma unroll
  for (int i = 0; i < 8; ++i) {
    int k = k0 + i;
    float sc = g[k] * rsqrtf(v[k] + BN_EPS);
    h[i] = (_Float16)(sc * W[k * 128 + col]);
  }
  *reinterpret_cast<half8*>(fa.pk[p] + (size_t)lf * 8) = h;
}

// K2: grid = 197 blocks x 256 thr.
// b in [0,40): merge — per bin, prefix over 125 u16 partials (chunked), total
//   -> hist[bin]; partials become per-block exclusive offsets in place.
// b in [40,197): per-node message via f16 MFMA, 4 waves x 16 rows.
__global__ __launch_bounds__(256) void merge_msg_kernel(
    unsigned short* __restrict__ part, int* __restrict__ hist,
    const float* __restrict__ x,
    const _Float16* __restrict__ W1pk, const float* __restrict__ b1f,
    const _Float16* __restrict__ W2pk, const float* __restrict__ b2f,
    _Float16* __restrict__ M) {
  __shared__ char lds_raw[4 * 4096];
  int b = blockIdx.x, t = threadIdx.x;
  if (b < 40) {
    int bin = b * 256 + t;
    if (bin >= N_NODES) return;
    int sum = 0;
#pragma unroll
    for (int c = 0; c < PART_BLOCKS; c += 25) {
      int vals[25];
#pragma unroll
      for (int i = 0; i < 25; ++i) vals[i] = part[(size_t)(c + i) * N_NODES + bin];
#pragma unroll
      for (int i = 0; i < 25; ++i) {
        part[(size_t)(c + i) * N_NODES + bin] = (unsigned short)sum;
        sum += vals[i];
      }
    }
    hist[bin] = sum;
    return;
  }
  int wid = t >> 6, lane = t & 63;
  int r = lane & 15, g = lane >> 4;
  int row0 = (b - 40) * 64 + wid * 16;
  char* lbase = lds_raw + wid * 4096;

  int arow = row0 + r;
  if (arow > N_NODES - 1) arow = N_NODES - 1;
  const float* xp = x + (size_t)arow * DIM;

  half8 a[4];
#pragma unroll
  for (int s = 0; s < 4; ++s) {
    float4 lo = *reinterpret_cast<const float4*>(xp + s * 32 + g * 8);
    float4 hi = *reinterpret_cast<const float4*>(xp + s * 32 + g * 8 + 4);
    half8 h;
    h[0] = (_Float16)lo.x; h[1] = (_Float16)lo.y; h[2] = (_Float16)lo.z; h[3] = (_Float16)lo.w;
    h[4] = (_Float16)hi.x; h[5] = (_Float16)hi.y; h[6] = (_Float16)hi.z; h[7] = (_Float16)hi.w;
    a[s] = h;
  }

  f32x4 zero = {0.f, 0.f, 0.f, 0.f};
  f32x4 acc[8];
#pragma unroll
  for (int f = 0; f < 8; ++f) acc[f] = zero;
#pragma unroll
  for (int f = 0; f < 8; ++f)
#pragma unroll
    for (int s = 0; s < 4; ++s) {
      half8 bfrag = *reinterpret_cast<const half8*>(W1pk + (size_t)((s * 8 + f) * 64 + lane) * 8);
      acc[f] = __builtin_amdgcn_mfma_f32_16x16x32_f16(a[s], bfrag, acc[f], 0, 0, 0);
    }

#pragma unroll
  for (int f = 0; f < 8; ++f) {
    int col = f * 16 + r;
    float bv = b1f[col];
#pragma unroll
    for (int j = 0; j < 4; ++j) {
      int rl = g * 4 + j;
      float gv = gelu_exact(acc[f][j] + bv);
      *reinterpret_cast<_Float16*>(lbase + lds_swz(rl, col * 2)) = (_Float16)gv;
    }
  }

  half8 a2[4];
#pragma unroll
  for (int s = 0; s < 4; ++s)
    a2[s] = *reinterpret_cast<const half8*>(lbase + lds_swz(r, (s * 32 + g * 8) * 2));

  f32x4 acc2[8];
#pragma unroll
  for (int f = 0; f < 8; ++f) acc2[f] = zero;
#pragma unroll
  for (int f = 0; f < 8; ++f)
#pragma unroll
    for (int s = 0; s < 4; ++s) {
      half8 bfrag = *reinterpret_cast<const half8*>(W2pk + (size_t)((s * 8 + f) * 64 + lane) * 8);
      acc2[f] = __builtin_amdgcn_mfma_f32_16x16x32_f16(a2[s], bfrag, acc2[f], 0, 0, 0);
    }

#pragma unroll
  for (int f = 0; f < 8; ++f) {
    int col = f * 16 + r;
    float bv = b2f[col];
#pragma unroll
    for (int j = 0; j < 4; ++j) {
      int grow = row0 + g * 4 + j;
      if (grow < N_NODES)
        M[(size_t)grow * DIM + col] = (_Float16)gelu_exact(acc2[f][j] + bv);
    }
  }
}

// One block, 256 threads, each owns 40 contiguous elements.
__global__ __launch_bounds__(256) void scan_kernel(const int* __restrict__ hist,
                                                   int* __restrict__ row_start, int n) {
  const int PER = 40;
  __shared__ int sums[256];
  int t = threadIdx.x;
  int i0 = t * PER;
  int total = 0;
  for (int i = 0; i < PER; ++i) {
    int idx = i0 + i;
    total += (idx < n) ? hist[idx] : 0;
  }
  sums[t] = total;
  __syncthreads();
  for (int off = 1; off < 256; off <<= 1) {
    int v = (t >= off) ? sums[t - off] : 0;
    __syncthreads();
    sums[t] += v;
    __syncthreads();
  }
  int running = sums[t] - total;
  for (int i = 0; i < PER; ++i) {
    int idx = i0 + i;
    if (idx < n) {
      row_start[idx] = running;
      running += hist[idx];
    }
  }
  if (t == 255) row_start[n] = sums[255];
}

// Scatter with LDS-only atomics: cursor[d] = row_start[d] + part[b][d] (u16).
__global__ __launch_bounds__(256) void scatter_kernel(
    const int* __restrict__ node_idx, const int* __restrict__ nbr_idx,
    const float* __restrict__ ew, const int* __restrict__ row_start,
    const unsigned short* __restrict__ part, uint2* __restrict__ edge_s) {
  __shared__ int cur[N_NODES];
  int b = blockIdx.x, t = threadIdx.x;
  const unsigned short* prow = part + (size_t)b * N_NODES;
  for (int i = t; i < N_NODES; i += 256) cur[i] = row_start[i] + (int)prow[i];
  __syncthreads();
  int base0 = b * EDGES_PER_PART;
#pragma unroll
  for (int s = 0; s < 5; ++s) {
    int base = base0 + s * 1024 + t * 4;
    int4 ni = *reinterpret_cast<const int4*>(&node_idx[base]);
    int4 nb = *reinterpret_cast<const int4*>(&nbr_idx[base]);
    float4 wv = *reinterpret_cast<const float4*>(&ew[base]);
    int p0 = atomicAdd(&cur[ni.x], 1);
    edge_s[p0] = make_uint2((unsigned)nb.x, __float_as_uint(wv.x));
    int p1 = atomicAdd(&cur[ni.y], 1);
    edge_s[p1] = make_uint2((unsigned)nb.y, __float_as_uint(wv.y));
    int p2 = atomicAdd(&cur[ni.z], 1);
    edge_s[p2] = make_uint2((unsigned)nb.z, __float_as_uint(wv.z));
    int p3 = atomicAdd(&cur[ni.w], 1);
    edge_s[p3] = make_uint2((unsigned)nb.w, __float_as_uint(wv.w));
  }
}

// K5: fused spmm + update. grid = 313 blocks x 256 thr, 32 rows/block.
// Phase 1 (all 256 thr): agg for 32 rows — 8 thr/row, 16 cols/thr, 4-edge
//   batches of independent gathers; result written as f16 into the update
//   waves' swizzled LDS tiles (no agg global roundtrip, no per-row reduce).
// Phase 2 (waves 0,1): out = gelu(gelu([x,agg]@U1+bu1)@U2+bu2) via f16 MFMA.
__global__ __launch_bounds__(256) void spmm_update_kernel(
    const int* __restrict__ row_start, const uint2* __restrict__ edge_s,
    const __half* __restrict__ M, const float* __restrict__ x,
    const _Float16* __restrict__ U1pk, const float* __restrict__ bu1,
    const _Float16* __restrict__ U2pk, const float* __restrict__ bu2,
    float* __restrict__ out) {
  __shared__ char lds_raw[2 * 4096];
  int t = threadIdx.x;
  int row0 = blockIdx.x * 32;

  {
    int r = t >> 3;       // 0..31 local row
    int sub = t & 7;      // col block: cols sub*16..sub*16+15
    int row = row0 + r;
    int s = 0, e_end = 0;
    if (row < N_NODES) {
      s = row_start[row];
      e_end = row_start[row + 1];
    }
    float acc[16];
#pragma unroll
    for (int c = 0; c < 16; ++c) acc[c] = 0.f;
    const __half* Mb = M + sub * 16;
    for (int base = s; base < e_end; base += 4) {
      uint2 pk[4];
#pragma unroll
      for (int k = 0; k < 4; ++k) {
        int e = base + k;
        pk[k] = edge_s[(e < e_end) ? e : s];
        if (e >= e_end) pk[k].y = 0u;
      }
      uint4 raw[8];
#pragma unroll
      for (int k = 0; k < 4; ++k) {
        const uint4* mp = reinterpret_cast<const uint4*>(Mb + (size_t)pk[k].x * DIM);
        raw[2 * k] = mp[0];
        raw[2 * k + 1] = mp[1];
      }
#pragma unroll
      for (int k = 0; k < 4; ++k) {
        float w = __uint_as_float(pk[k].y);
        const __half2* h2 = reinterpret_cast<const __half2*>(&raw[2 * k]);
#pragma unroll
        for (int q = 0; q < 8; ++q) {
          float2 f = __half22float2(h2[q]);
          acc[2 * q] = fmaf(w, f.x, acc[2 * q]);
          acc[2 * q + 1] = fmaf(w, f.y, acc[2 * q + 1]);
        }
      }
    }
    int cnt = e_end - s;
    float inv = 1.f / (float)(cnt > 0 ? cnt : 1);
    char* tile = lds_raw + (r >> 4) * 4096;
    int rl = r & 15;
    half8 hlo, hhi;
#pragma unroll
    for (int c = 0; c < 8; ++c) hlo[c] = (_Float16)(acc[c] * inv);
#pragma unroll
    for (int c = 0; c < 8; ++c) hhi[c] = (_Float16)(acc[8 + c] * inv);
    *reinterpret_cast<half8*>(tile + lds_swz(rl, sub * 32)) = hlo;
    *reinterpret_cast<half8*>(tile + lds_swz(rl, sub * 32 + 16)) = hhi;
  }
  __syncthreads();

  int wid = t >> 6, lane = t & 63;
  if (wid >= 2) return;
  int r = lane & 15, g = lane >> 4;
  char* tile = lds_raw + wid * 4096;
  int arow = row0 + wid * 16 + r;
  int arow_c = (arow > N_NODES - 1) ? N_NODES - 1 : arow;
  const float* xp = x + (size_t)arow_c * DIM;

  half8 a[8];
#pragma unroll
  for (int s = 0; s < 4; ++s) {
    float4 lo = *reinterpret_cast<const float4*>(xp + s * 32 + g * 8);
    float4 hi = *reinterpret_cast<const float4*>(xp + s * 32 + g * 8 + 4);
    half8 h;
    h[0] = (_Float16)lo.x; h[1] = (_Float16)lo.y; h[2] = (_Float16)lo.z; h[3] = (_Float16)lo.w;
    h[4] = (_Float16)hi.x; h[5] = (_Float16)hi.y; h[6] = (_Float16)hi.z; h[7] = (_Float16)hi.w;
    a[s] = h;
  }
#pragma unroll
  for (int s = 0; s < 4; ++s)
    a[4 + s] = *reinterpret_cast<const half8*>(tile + lds_swz(r, (s * 32 + g * 8) * 2));

  f32x4 zero = {0.f, 0.f, 0.f, 0.f};
  f32x4 acc[8];
#pragma unroll
  for (int f = 0; f < 8; ++f) acc[f] = zero;
#pragma unroll
  for (int f = 0; f < 8; ++f)
#pragma unroll
    for (int s = 0; s < 8; ++s) {
      half8 bfrag = *reinterpret_cast<const half8*>(U1pk + (size_t)((s * 8 + f) * 64 + lane) * 8);
      acc[f] = __builtin_amdgcn_mfma_f32_16x16x32_f16(a[s], bfrag, acc[f], 0, 0, 0);
    }

#pragma unroll
  for (int f = 0; f < 8; ++f) {
    int col = f * 16 + r;
    float bv = bu1[col];
#pragma unroll
    for (int j = 0; j < 4; ++j) {
      int rl = g * 4 + j;
      float gv = gelu_exact(acc[f][j] + bv);
      *reinterpret_cast<_Float16*>(tile + lds_swz(rl, col * 2)) = (_Float16)gv;
    }
  }

  half8 a2[4];
#pragma unroll
  for (int s = 0; s < 4; ++s)
    a2[s] = *reinterpret_cast<const half8*>(tile + lds_swz(r, (s * 32 + g * 8) * 2));

  f32x4 acc2[8];
#pragma unroll
  for (int f = 0; f < 8; ++f) acc2[f] = zero;
#pragma unroll
  for (int f = 0; f < 8; ++f)
#pragma unroll
    for (int s = 0; s < 4; ++s) {
      half8 bfrag = *reinterpret_cast<const half8*>(U2pk + (size_t)((s * 8 + f) * 64 + lane) * 8);
      acc2[f] = __builtin_amdgcn_mfma_f32_16x16x32_f16(a2[s], bfrag, acc2[f], 0, 0, 0);
    }

#pragma unroll
  for (int f = 0; f < 8; ++f) {
    int col = f * 16 + r;
    float bv = bu2[col];
#pragma unroll
    for (int j = 0; j < 4; ++j) {
      int grow = row0 + wid * 16 + g * 4 + j;
      if (grow < N_NODES)
        out[(size_t)grow * DIM + col] = gelu_exact(acc2[f][j] + bv);
    }
  }
}

extern "C" void kernel_launch(void* const* d_in, const int* in_sizes, int n_in,
                              void* d_out, int out_size, void* d_ws, size_t ws_size,
                              hipStream_t stream) {
  const float* x = (const float*)d_in[0];
  const int* edges = (const int*)d_in[1];
  const float* ew = (const float*)d_in[2];

  const int* node_idx = edges;            // edges[0, :]
  const int* nbr_idx = edges + N_EDGES;   // edges[1, :]

  char* wsp = (char*)d_ws;
  auto alloc = [&](size_t bytes) {
    char* p = wsp;
    wsp += (bytes + 255) & ~(size_t)255;
    return p;
  };
  _Float16* M = (_Float16*)alloc((size_t)N_NODES * DIM * 2);
  _Float16* W1pk = (_Float16*)alloc(128 * 128 * 2);
  _Float16* W2pk = (_Float16*)alloc(128 * 128 * 2);
  _Float16* U1pk = (_Float16*)alloc(256 * 128 * 2);
  _Float16* U2pk = (_Float16*)alloc(128 * 128 * 2);
  float* b1f = (float*)alloc(128 * 4);
  float* b2f = (float*)alloc(128 * 4);
  float* bu1 = (float*)alloc(128 * 4);
  float* bu2 = (float*)alloc(128 * 4);
  int* hist = (int*)alloc(N_NODES * 4);
  int* row_start = (int*)alloc((N_NODES + 1) * 4);
  unsigned short* part = (unsigned short*)alloc((size_t)PART_BLOCKS * N_NODES * 2);
  uint2* edge_s = (uint2*)alloc((size_t)N_EDGES * 8);

  FoldAll fa;
  fa.g[0] = (const float*)d_in[3];  fa.bb[0] = (const float*)d_in[4];
  fa.m[0] = (const float*)d_in[5];  fa.v[0] = (const float*)d_in[6];
  fa.W[0] = (const float*)d_in[7];  fa.bias[0] = (const float*)d_in[8];
  fa.g[1] = (const float*)d_in[9];  fa.bb[1] = (const float*)d_in[10];
  fa.m[1] = (const float*)d_in[11]; fa.v[1] = (const float*)d_in[12];
  fa.W[1] = (const float*)d_in[13]; fa.bias[1] = (const float*)d_in[14];
  fa.g[2] = (const float*)d_in[15]; fa.bb[2] = (const float*)d_in[16];
  fa.m[2] = (const float*)d_in[17]; fa.v[2] = (const float*)d_in[18];
  fa.W[2] = (const float*)d_in[19]; fa.bias[2] = (const float*)d_in[20];
  fa.g[3] = (const float*)d_in[21]; fa.bb[3] = (const float*)d_in[22];
  fa.m[3] = (const float*)d_in[23]; fa.v[3] = (const float*)d_in[24];
  fa.W[3] = (const float*)d_in[25]; fa.bias[3] = (const float*)d_in[26];
  fa.pk[0] = W1pk; fa.pk[1] = W2pk; fa.pk[2] = U1pk; fa.pk[3] = U2pk;
  fa.bf[0] = b1f; fa.bf[1] = b2f; fa.bf[2] = bu1; fa.bf[3] = bu2;
  fa.din[0] = 128; fa.din[1] = 128; fa.din[2] = 256; fa.din[3] = 128;
  fa.S[0] = 4; fa.S[1] = 4; fa.S[2] = 8; fa.S[3] = 4;

  fold_hist_kernel<<<44 + PART_BLOCKS, 256, 0, stream>>>(fa, node_idx, part);
  merge_msg_kernel<<<40 + MSG64_BLOCKS, 256, 0, stream>>>(
      part, hist, x, W1pk, b1f, W2pk, b2f, M);
  scan_kernel<<<1, 256, 0, stream>>>(hist, row_start, N_NODES);
  scatter_kernel<<<PART_BLOCKS, 256, 0, stream>>>(node_idx, nbr_idx, ew, row_start, part, edge_s);
  spmm_update_kernel<<<SU_BLOCKS, 256, 0, stream>>>(
      row_start, edge_s, (const __half*)M, x, U1pk, bu1, U2pk, bu2, (float*)d_out);
}

// Round 9
// 131.374 us; speedup vs baseline: 1.5001x; 1.0521x over previous
//
#include <hip/hip_runtime.h>
#include <hip/hip_bf16.h>
#include <hip/hip_fp16.h>
#include <math.h>

#define N_NODES 10000
#define DIM 128
#define N_EDGES 640000
#define BN_EPS 1e-3f

#define PART_BLOCKS 250       // 640000 / 2560
#define EDGES_PER_PART 2560
#define MSG64_BLOCKS 157      // ceil(10000 / 64)
#define SU_BLOCKS 625         // 10000 / 16

typedef _Float16 half8 __attribute__((ext_vector_type(8)));
typedef float f32x4 __attribute__((ext_vector_type(4)));

__device__ __forceinline__ float gelu_exact(float x) {
  return 0.5f * x * (1.0f + erff(x * 0.70710678f));
}

// Swizzled per-wave LDS tile: [16 rows][128 cols] f16, row stride 256 B.
__device__ __forceinline__ int lds_swz(int row, int colbyte) {
  return ((row * 256 + colbyte) ^ ((row & 7) << 4));
}

struct FoldAll {
  const float* g[4];
  const float* bb[4];
  const float* m[4];
  const float* v[4];
  const float* W[4];
  const float* bias[4];
  _Float16* pk[4];
  float* bf[4];
  int din[4];
  int S[4];  // K/32
};

// K1: grid = 44 + PART_BLOCKS blocks x 256 thr.
// b in [0,40): pack W fragments (f16, B-frag layout, BN-scale folded).
// b in [40,44): folded bias: bf = bias + t @ W.
// b >= 44: per-block LDS histogram of 2560 edges -> u16 partial row.
__global__ __launch_bounds__(256) void fold_hist_kernel(FoldAll fa,
                                                        const int* __restrict__ node_idx,
                                                        unsigned short* __restrict__ part) {
  __shared__ int lh[N_NODES];
  __shared__ float t_sh[256];
  __shared__ float bpart[128];
  int b = blockIdx.x, t = threadIdx.x;
  if (b >= 44) {
    int pb = b - 44;
    for (int i = t; i < N_NODES; i += 256) lh[i] = 0;
    __syncthreads();
    int base0 = pb * EDGES_PER_PART;
#pragma unroll
    for (int s = 0; s < 3; ++s) {
      int off = s * 1024 + t * 4;
      if (off < EDGES_PER_PART) {
        int4 vv = *reinterpret_cast<const int4*>(&node_idx[base0 + off]);
        atomicAdd(&lh[vv.x], 1);
        atomicAdd(&lh[vv.y], 1);
        atomicAdd(&lh[vv.z], 1);
        atomicAdd(&lh[vv.w], 1);
      }
    }
    __syncthreads();
    unsigned short* prow = part + (size_t)pb * N_NODES;
    for (int i = t; i < N_NODES; i += 256) prow[i] = (unsigned short)lh[i];
    return;
  }
  if (b >= 40) {
    int p = b - 40;
    int din = fa.din[p];
    const float* W = fa.W[p];
    for (int k = t; k < din; k += 256) {
      float sc = fa.g[p][k] * rsqrtf(fa.v[p][k] + BN_EPS);
      t_sh[k] = fa.bb[p][k] - fa.m[p][k] * sc;
    }
    __syncthreads();
    int j = t & 127, kh = t >> 7;
    int half = din >> 1;
    float acc = 0.f;
    for (int k = kh * half; k < (kh + 1) * half; ++k)
      acc = fmaf(t_sh[k], W[k * 128 + j], acc);
    if (kh == 1) bpart[j] = acc;
    __syncthreads();
    if (kh == 0) fa.bf[p][j] = acc + bpart[j] + fa.bias[p][j];
    return;
  }
  int p, lf;
  if (b < 8)       { p = 0; lf = b * 256 + t; }
  else if (b < 16) { p = 1; lf = (b - 8) * 256 + t; }
  else if (b < 32) { p = 2; lf = (b - 16) * 256 + t; }
  else             { p = 3; lf = (b - 32) * 256 + t; }
  int S = fa.S[p];
  int l = lf & 63;
  int fs = lf >> 6;
  int f = fs & 7, s = fs >> 3;
  if (s >= S) return;
  const float* W = fa.W[p];
  const float* g = fa.g[p];
  const float* v = fa.v[p];
  int k0 = s * 32 + (l >> 4) * 8;
  int col = f * 16 + (l & 15);
  half8 h;
#pragma unroll
  for (int i = 0; i < 8; ++i) {
    int k = k0 + i;
    float sc = g[k] * rsqrtf(v[k] + BN_EPS);
    h[i] = (_Float16)(sc * W[k * 128 + col]);
  }
  *reinterpret_cast<half8*>(fa.pk[p] + (size_t)lf * 8) = h;
}

// K2: grid = 40 + MSG64_BLOCKS blocks x 256 thr.
// b in [0,40): merge — per bin, prefix over 250 u16 partials (chunked), total
//   -> hist[bin]; partials become per-block exclusive offsets in place.
// b >= 40: per-node message via f16 MFMA, 4 waves x 16 rows.
__global__ __launch_bounds__(256) void merge_msg_kernel(
    unsigned short* __restrict__ part, int* __restrict__ hist,
    const float* __restrict__ x,
    const _Float16* __restrict__ W1pk, const float* __restrict__ b1f,
    const _Float16* __restrict__ W2pk, const float* __restrict__ b2f,
    _Float16* __restrict__ M) {
  __shared__ char lds_raw[4 * 4096];
  int b = blockIdx.x, t = threadIdx.x;
  if (b < 40) {
    int bin = b * 256 + t;
    if (bin >= N_NODES) return;
    int sum = 0;
#pragma unroll
    for (int c = 0; c < PART_BLOCKS; c += 25) {
      int vals[25];
#pragma unroll
      for (int i = 0; i < 25; ++i) vals[i] = part[(size_t)(c + i) * N_NODES + bin];
#pragma unroll
      for (int i = 0; i < 25; ++i) {
        part[(size_t)(c + i) * N_NODES + bin] = (unsigned short)sum;
        sum += vals[i];
      }
    }
    hist[bin] = sum;
    return;
  }
  int wid = t >> 6, lane = t & 63;
  int r = lane & 15, g = lane >> 4;
  int row0 = (b - 40) * 64 + wid * 16;
  char* lbase = lds_raw + wid * 4096;

  int arow = row0 + r;
  if (arow > N_NODES - 1) arow = N_NODES - 1;
  const float* xp = x + (size_t)arow * DIM;

  half8 a[4];
#pragma unroll
  for (int s = 0; s < 4; ++s) {
    float4 lo = *reinterpret_cast<const float4*>(xp + s * 32 + g * 8);
    float4 hi = *reinterpret_cast<const float4*>(xp + s * 32 + g * 8 + 4);
    half8 h;
    h[0] = (_Float16)lo.x; h[1] = (_Float16)lo.y; h[2] = (_Float16)lo.z; h[3] = (_Float16)lo.w;
    h[4] = (_Float16)hi.x; h[5] = (_Float16)hi.y; h[6] = (_Float16)hi.z; h[7] = (_Float16)hi.w;
    a[s] = h;
  }

  f32x4 zero = {0.f, 0.f, 0.f, 0.f};
  f32x4 acc[8];
#pragma unroll
  for (int f = 0; f < 8; ++f) acc[f] = zero;
#pragma unroll
  for (int f = 0; f < 8; ++f)
#pragma unroll
    for (int s = 0; s < 4; ++s) {
      half8 bfrag = *reinterpret_cast<const half8*>(W1pk + (size_t)((s * 8 + f) * 64 + lane) * 8);
      acc[f] = __builtin_amdgcn_mfma_f32_16x16x32_f16(a[s], bfrag, acc[f], 0, 0, 0);
    }

#pragma unroll
  for (int f = 0; f < 8; ++f) {
    int col = f * 16 + r;
    float bv = b1f[col];
#pragma unroll
    for (int j = 0; j < 4; ++j) {
      int rl = g * 4 + j;
      float gv = gelu_exact(acc[f][j] + bv);
      *reinterpret_cast<_Float16*>(lbase + lds_swz(rl, col * 2)) = (_Float16)gv;
    }
  }

  half8 a2[4];
#pragma unroll
  for (int s = 0; s < 4; ++s)
    a2[s] = *reinterpret_cast<const half8*>(lbase + lds_swz(r, (s * 32 + g * 8) * 2));

  f32x4 acc2[8];
#pragma unroll
  for (int f = 0; f < 8; ++f) acc2[f] = zero;
#pragma unroll
  for (int f = 0; f < 8; ++f)
#pragma unroll
    for (int s = 0; s < 4; ++s) {
      half8 bfrag = *reinterpret_cast<const half8*>(W2pk + (size_t)((s * 8 + f) * 64 + lane) * 8);
      acc2[f] = __builtin_amdgcn_mfma_f32_16x16x32_f16(a2[s], bfrag, acc2[f], 0, 0, 0);
    }

#pragma unroll
  for (int f = 0; f < 8; ++f) {
    int col = f * 16 + r;
    float bv = b2f[col];
#pragma unroll
    for (int j = 0; j < 4; ++j) {
      int grow = row0 + g * 4 + j;
      if (grow < N_NODES)
        M[(size_t)grow * DIM + col] = (_Float16)gelu_exact(acc2[f][j] + bv);
    }
  }
}

// One block, 256 threads, each owns 40 contiguous elements.
__global__ __launch_bounds__(256) void scan_kernel(const int* __restrict__ hist,
                                                   int* __restrict__ row_start, int n) {
  const int PER = 40;
  __shared__ int sums[256];
  int t = threadIdx.x;
  int i0 = t * PER;
  int total = 0;
  for (int i = 0; i < PER; ++i) {
    int idx = i0 + i;
    total += (idx < n) ? hist[idx] : 0;
  }
  sums[t] = total;
  __syncthreads();
  for (int off = 1; off < 256; off <<= 1) {
    int v = (t >= off) ? sums[t - off] : 0;
    __syncthreads();
    sums[t] += v;
    __syncthreads();
  }
  int running = sums[t] - total;
  for (int i = 0; i < PER; ++i) {
    int idx = i0 + i;
    if (idx < n) {
      row_start[idx] = running;
      running += hist[idx];
    }
  }
  if (t == 255) row_start[n] = sums[255];
}

// Scatter with LDS-only atomics: cursor[d] = row_start[d] + part[b][d] (u16).
__global__ __launch_bounds__(256) void scatter_kernel(
    const int* __restrict__ node_idx, const int* __restrict__ nbr_idx,
    const float* __restrict__ ew, const int* __restrict__ row_start,
    const unsigned short* __restrict__ part, uint2* __restrict__ edge_s) {
  __shared__ int cur[N_NODES];
  int b = blockIdx.x, t = threadIdx.x;
  const unsigned short* prow = part + (size_t)b * N_NODES;
  for (int i = t; i < N_NODES; i += 256) cur[i] = row_start[i] + (int)prow[i];
  __syncthreads();
  int base0 = b * EDGES_PER_PART;
#pragma unroll
  for (int s = 0; s < 3; ++s) {
    int off = s * 1024 + t * 4;
    if (off >= EDGES_PER_PART) break;
    int base = base0 + off;
    int4 ni = *reinterpret_cast<const int4*>(&node_idx[base]);
    int4 nb = *reinterpret_cast<const int4*>(&nbr_idx[base]);
    float4 wv = *reinterpret_cast<const float4*>(&ew[base]);
    int p0 = atomicAdd(&cur[ni.x], 1);
    edge_s[p0] = make_uint2((unsigned)nb.x, __float_as_uint(wv.x));
    int p1 = atomicAdd(&cur[ni.y], 1);
    edge_s[p1] = make_uint2((unsigned)nb.y, __float_as_uint(wv.y));
    int p2 = atomicAdd(&cur[ni.z], 1);
    edge_s[p2] = make_uint2((unsigned)nb.z, __float_as_uint(wv.z));
    int p3 = atomicAdd(&cur[ni.w], 1);
    edge_s[p3] = make_uint2((unsigned)nb.w, __float_as_uint(wv.w));
  }
}

// K5: fused spmm + update. grid = 625 blocks x 256 thr, 16 rows/block.
// Phase 1 (all 256 thr): agg for 16 rows — 16 thr/row, 8 cols/thr, 8-edge
//   batches of independent gathers; result written as f16 into the swizzled
//   LDS tile (no agg global roundtrip).
// Phase 2 (wave 0): out = gelu(gelu([x,agg]@U1+bu1)@U2+bu2) via f16 MFMA.
__global__ __launch_bounds__(256) void spmm_update_kernel(
    const int* __restrict__ row_start, const uint2* __restrict__ edge_s,
    const __half* __restrict__ M, const float* __restrict__ x,
    const _Float16* __restrict__ U1pk, const float* __restrict__ bu1,
    const _Float16* __restrict__ U2pk, const float* __restrict__ bu2,
    float* __restrict__ out) {
  __shared__ char tile[4096];
  int t = threadIdx.x;
  int row0 = blockIdx.x * 16;

  {
    int r = t >> 4;       // 0..15 local row
    int sub = t & 15;     // col block: cols sub*8..sub*8+7
    int row = row0 + r;
    int s = row_start[row];
    int e_end = row_start[row + 1];
    float acc[8];
#pragma unroll
    for (int c = 0; c < 8; ++c) acc[c] = 0.f;
    const __half* Mb = M + sub * 8;
    for (int base = s; base < e_end; base += 8) {
      uint2 pk[8];
#pragma unroll
      for (int k = 0; k < 8; ++k) {
        int e = base + k;
        pk[k] = edge_s[(e < e_end) ? e : s];
        if (e >= e_end) pk[k].y = 0u;
      }
      uint4 raw[8];
#pragma unroll
      for (int k = 0; k < 8; ++k)
        raw[k] = *reinterpret_cast<const uint4*>(Mb + (size_t)pk[k].x * DIM);
#pragma unroll
      for (int k = 0; k < 8; ++k) {
        float w = __uint_as_float(pk[k].y);
        const __half2* h2 = reinterpret_cast<const __half2*>(&raw[k]);
#pragma unroll
        for (int q = 0; q < 4; ++q) {
          float2 f = __half22float2(h2[q]);
          acc[2 * q] = fmaf(w, f.x, acc[2 * q]);
          acc[2 * q + 1] = fmaf(w, f.y, acc[2 * q + 1]);
        }
      }
    }
    int cnt = e_end - s;
    float inv = 1.f / (float)(cnt > 0 ? cnt : 1);
    half8 h;
#pragma unroll
    for (int c = 0; c < 8; ++c) h[c] = (_Float16)(acc[c] * inv);
    *reinterpret_cast<half8*>(tile + lds_swz(r, sub * 16)) = h;
  }
  __syncthreads();

  if (t >= 64) return;
  int lane = t;
  int r = lane & 15, g = lane >> 4;
  int arow = row0 + r;
  const float* xp = x + (size_t)arow * DIM;

  half8 a[8];
#pragma unroll
  for (int s = 0; s < 4; ++s) {
    float4 lo = *reinterpret_cast<const float4*>(xp + s * 32 + g * 8);
    float4 hi = *reinterpret_cast<const float4*>(xp + s * 32 + g * 8 + 4);
    half8 h;
    h[0] = (_Float16)lo.x; h[1] = (_Float16)lo.y; h[2] = (_Float16)lo.z; h[3] = (_Float16)lo.w;
    h[4] = (_Float16)hi.x; h[5] = (_Float16)hi.y; h[6] = (_Float16)hi.z; h[7] = (_Float16)hi.w;
    a[s] = h;
  }
#pragma unroll
  for (int s = 0; s < 4; ++s)
    a[4 + s] = *reinterpret_cast<const half8*>(tile + lds_swz(r, (s * 32 + g * 8) * 2));

  f32x4 zero = {0.f, 0.f, 0.f, 0.f};
  f32x4 acc[8];
#pragma unroll
  for (int f = 0; f < 8; ++f) acc[f] = zero;
#pragma unroll
  for (int f = 0; f < 8; ++f)
#pragma unroll
    for (int s = 0; s < 8; ++s) {
      half8 bfrag = *reinterpret_cast<const half8*>(U1pk + (size_t)((s * 8 + f) * 64 + lane) * 8);
      acc[f] = __builtin_amdgcn_mfma_f32_16x16x32_f16(a[s], bfrag, acc[f], 0, 0, 0);
    }

#pragma unroll
  for (int f = 0; f < 8; ++f) {
    int col = f * 16 + r;
    float bv = bu1[col];
#pragma unroll
    for (int j = 0; j < 4; ++j) {
      int rl = g * 4 + j;
      float gv = gelu_exact(acc[f][j] + bv);
      *reinterpret_cast<_Float16*>(tile + lds_swz(rl, col * 2)) = (_Float16)gv;
    }
  }

  half8 a2[4];
#pragma unroll
  for (int s = 0; s < 4; ++s)
    a2[s] = *reinterpret_cast<const half8*>(tile + lds_swz(r, (s * 32 + g * 8) * 2));

  f32x4 acc2[8];
#pragma unroll
  for (int f = 0; f < 8; ++f) acc2[f] = zero;
#pragma unroll
  for (int f = 0; f < 8; ++f)
#pragma unroll
    for (int s = 0; s < 4; ++s) {
      half8 bfrag = *reinterpret_cast<const half8*>(U2pk + (size_t)((s * 8 + f) * 64 + lane) * 8);
      acc2[f] = __builtin_amdgcn_mfma_f32_16x16x32_f16(a2[s], bfrag, acc2[f], 0, 0, 0);
    }

#pragma unroll
  for (int f = 0; f < 8; ++f) {
    int col = f * 16 + r;
    float bv = bu2[col];
#pragma unroll
    for (int j = 0; j < 4; ++j) {
      int grow = row0 + g * 4 + j;
      out[(size_t)grow * DIM + col] = gelu_exact(acc2[f][j] + bv);
    }
  }
}

extern "C" void kernel_launch(void* const* d_in, const int* in_sizes, int n_in,
                              void* d_out, int out_size, void* d_ws, size_t ws_size,
                              hipStream_t stream) {
  const float* x = (const float*)d_in[0];
  const int* edges = (const int*)d_in[1];
  const float* ew = (const float*)d_in[2];

  const int* node_idx = edges;            // edges[0, :]
  const int* nbr_idx = edges + N_EDGES;   // edges[1, :]

  char* wsp = (char*)d_ws;
  auto alloc = [&](size_t bytes) {
    char* p = wsp;
    wsp += (bytes + 255) & ~(size_t)255;
    return p;
  };
  _Float16* M = (_Float16*)alloc((size_t)N_NODES * DIM * 2);
  _Float16* W1pk = (_Float16*)alloc(128 * 128 * 2);
  _Float16* W2pk = (_Float16*)alloc(128 * 128 * 2);
  _Float16* U1pk = (_Float16*)alloc(256 * 128 * 2);
  _Float16* U2pk = (_Float16*)alloc(128 * 128 * 2);
  float* b1f = (float*)alloc(128 * 4);
  float* b2f = (float*)alloc(128 * 4);
  float* bu1 = (float*)alloc(128 * 4);
  float* bu2 = (float*)alloc(128 * 4);
  int* hist = (int*)alloc(N_NODES * 4);
  int* row_start = (int*)alloc((N_NODES + 1) * 4);
  unsigned short* part = (unsigned short*)alloc((size_t)PART_BLOCKS * N_NODES * 2);
  uint2* edge_s = (uint2*)alloc((size_t)N_EDGES * 8);

  FoldAll fa;
  fa.g[0] = (const float*)d_in[3];  fa.bb[0] = (const float*)d_in[4];
  fa.m[0] = (const float*)d_in[5];  fa.v[0] = (const float*)d_in[6];
  fa.W[0] = (const float*)d_in[7];  fa.bias[0] = (const float*)d_in[8];
  fa.g[1] = (const float*)d_in[9];  fa.bb[1] = (const float*)d_in[10];
  fa.m[1] = (const float*)d_in[11]; fa.v[1] = (const float*)d_in[12];
  fa.W[1] = (const float*)d_in[13]; fa.bias[1] = (const float*)d_in[14];
  fa.g[2] = (const float*)d_in[15]; fa.bb[2] = (const float*)d_in[16];
  fa.m[2] = (const float*)d_in[17]; fa.v[2] = (const float*)d_in[18];
  fa.W[2] = (const float*)d_in[19]; fa.bias[2] = (const float*)d_in[20];
  fa.g[3] = (const float*)d_in[21]; fa.bb[3] = (const float*)d_in[22];
  fa.m[3] = (const float*)d_in[23]; fa.v[3] = (const float*)d_in[24];
  fa.W[3] = (const float*)d_in[25]; fa.bias[3] = (const float*)d_in[26];
  fa.pk[0] = W1pk; fa.pk[1] = W2pk; fa.pk[2] = U1pk; fa.pk[3] = U2pk;
  fa.bf[0] = b1f; fa.bf[1] = b2f; fa.bf[2] = bu1; fa.bf[3] = bu2;
  fa.din[0] = 128; fa.din[1] = 128; fa.din[2] = 256; fa.din[3] = 128;
  fa.S[0] = 4; fa.S[1] = 4; fa.S[2] = 8; fa.S[3] = 4;

  fold_hist_kernel<<<44 + PART_BLOCKS, 256, 0, stream>>>(fa, node_idx, part);
  merge_msg_kernel<<<40 + MSG64_BLOCKS, 256, 0, stream>>>(
      part, hist, x, W1pk, b1f, W2pk, b2f, M);
  scan_kernel<<<1, 256, 0, stream>>>(hist, row_start, N_NODES);
  scatter_kernel<<<PART_BLOCKS, 256, 0, stream>>>(node_idx, nbr_idx, ew, row_start, part, edge_s);
  spmm_update_kernel<<<SU_BLOCKS, 256, 0, stream>>>(
      row_start, edge_s, (const __half*)M, x, U1pk, bu1, U2pk, bu2, (float*)d_out);
}

// Round 10
// 124.924 us; speedup vs baseline: 1.5776x; 1.0516x over previous
//
#include <hip/hip_runtime.h>
#include <hip/hip_bf16.h>
#include <hip/hip_fp16.h>
#include <math.h>

#define N_NODES 10000
#define DIM 128
#define N_EDGES 640000
#define BN_EPS 1e-3f

#define PART_BLOCKS 250       // 640000 / 2560
#define EDGES_PER_PART 2560
#define MSG64_BLOCKS 157      // ceil(10000 / 64)
#define SU_BLOCKS 625         // 10000 / 16

typedef _Float16 half8 __attribute__((ext_vector_type(8)));
typedef float f32x4 __attribute__((ext_vector_type(4)));

__device__ __forceinline__ float gelu_exact(float x) {
  return 0.5f * x * (1.0f + erff(x * 0.70710678f));
}

// Swizzled per-wave LDS tile: [16 rows][128 cols] f16, row stride 256 B.
__device__ __forceinline__ int lds_swz(int row, int colbyte) {
  return ((row * 256 + colbyte) ^ ((row & 7) << 4));
}

struct FoldAll {
  const float* g[4];
  const float* bb[4];
  const float* m[4];
  const float* v[4];
  const float* W[4];
  const float* bias[4];
  _Float16* pk[4];
  float* bf[4];
  int din[4];
  int S[4];  // K/32
};

// K1: grid = 44 + PART_BLOCKS blocks x 256 thr.
// b in [0,40): pack W fragments (f16, B-frag layout, BN-scale folded).
// b in [40,44): folded bias: bf = bias + t @ W.
// b >= 44: per-block LDS histogram of 2560 edges -> u16 partial row.
__global__ __launch_bounds__(256) void fold_hist_kernel(FoldAll fa,
                                                        const int* __restrict__ node_idx,
                                                        unsigned short* __restrict__ part) {
  __shared__ int lh[N_NODES];
  __shared__ float t_sh[256];
  __shared__ float bpart[128];
  int b = blockIdx.x, t = threadIdx.x;
  if (b >= 44) {
    int pb = b - 44;
    for (int i = t; i < N_NODES; i += 256) lh[i] = 0;
    __syncthreads();
    int base0 = pb * EDGES_PER_PART;
#pragma unroll
    for (int s = 0; s < 3; ++s) {
      int off = s * 1024 + t * 4;
      if (off < EDGES_PER_PART) {
        int4 vv = *reinterpret_cast<const int4*>(&node_idx[base0 + off]);
        atomicAdd(&lh[vv.x], 1);
        atomicAdd(&lh[vv.y], 1);
        atomicAdd(&lh[vv.z], 1);
        atomicAdd(&lh[vv.w], 1);
      }
    }
    __syncthreads();
    unsigned short* prow = part + (size_t)pb * N_NODES;
    for (int i = t; i < N_NODES; i += 256) prow[i] = (unsigned short)lh[i];
    return;
  }
  if (b >= 40) {
    int p = b - 40;
    int din = fa.din[p];
    const float* W = fa.W[p];
    for (int k = t; k < din; k += 256) {
      float sc = fa.g[p][k] * rsqrtf(fa.v[p][k] + BN_EPS);
      t_sh[k] = fa.bb[p][k] - fa.m[p][k] * sc;
    }
    __syncthreads();
    int j = t & 127, kh = t >> 7;
    int half = din >> 1;
    float acc = 0.f;
    for (int k = kh * half; k < (kh + 1) * half; ++k)
      acc = fmaf(t_sh[k], W[k * 128 + j], acc);
    if (kh == 1) bpart[j] = acc;
    __syncthreads();
    if (kh == 0) fa.bf[p][j] = acc + bpart[j] + fa.bias[p][j];
    return;
  }
  int p, lf;
  if (b < 8)       { p = 0; lf = b * 256 + t; }
  else if (b < 16) { p = 1; lf = (b - 8) * 256 + t; }
  else if (b < 32) { p = 2; lf = (b - 16) * 256 + t; }
  else             { p = 3; lf = (b - 32) * 256 + t; }
  int S = fa.S[p];
  int l = lf & 63;
  int fs = lf >> 6;
  int f = fs & 7, s = fs >> 3;
  if (s >= S) return;
  const float* W = fa.W[p];
  const float* g = fa.g[p];
  const float* v = fa.v[p];
  int k0 = s * 32 + (l >> 4) * 8;
  int col = f * 16 + (l & 15);
  half8 h;
#pragma unroll
  for (int i = 0; i < 8; ++i) {
    int k = k0 + i;
    float sc = g[k] * rsqrtf(v[k] + BN_EPS);
    h[i] = (_Float16)(sc * W[k * 128 + col]);
  }
  *reinterpret_cast<half8*>(fa.pk[p] + (size_t)lf * 8) = h;
}

// K2: grid = 40 + MSG64_BLOCKS blocks x 256 thr.
// b in [0,40): merge — per bin, prefix over 250 u16 partials (chunked), total
//   -> hist[bin]; partials become per-block exclusive offsets in place.
// b >= 40: per-node message via f16 MFMA, 4 waves x 16 rows.
__global__ __launch_bounds__(256) void merge_msg_kernel(
    unsigned short* __restrict__ part, int* __restrict__ hist,
    const float* __restrict__ x,
    const _Float16* __restrict__ W1pk, const float* __restrict__ b1f,
    const _Float16* __restrict__ W2pk, const float* __restrict__ b2f,
    _Float16* __restrict__ M) {
  __shared__ char lds_raw[4 * 4096];
  int b = blockIdx.x, t = threadIdx.x;
  if (b < 40) {
    int bin = b * 256 + t;
    if (bin >= N_NODES) return;
    int sum = 0;
#pragma unroll
    for (int c = 0; c < PART_BLOCKS; c += 25) {
      int vals[25];
#pragma unroll
      for (int i = 0; i < 25; ++i) vals[i] = part[(size_t)(c + i) * N_NODES + bin];
#pragma unroll
      for (int i = 0; i < 25; ++i) {
        part[(size_t)(c + i) * N_NODES + bin] = (unsigned short)sum;
        sum += vals[i];
      }
    }
    hist[bin] = sum;
    return;
  }
  int wid = t >> 6, lane = t & 63;
  int r = lane & 15, g = lane >> 4;
  int row0 = (b - 40) * 64 + wid * 16;
  char* lbase = lds_raw + wid * 4096;

  int arow = row0 + r;
  if (arow > N_NODES - 1) arow = N_NODES - 1;
  const float* xp = x + (size_t)arow * DIM;

  half8 a[4];
#pragma unroll
  for (int s = 0; s < 4; ++s) {
    float4 lo = *reinterpret_cast<const float4*>(xp + s * 32 + g * 8);
    float4 hi = *reinterpret_cast<const float4*>(xp + s * 32 + g * 8 + 4);
    half8 h;
    h[0] = (_Float16)lo.x; h[1] = (_Float16)lo.y; h[2] = (_Float16)lo.z; h[3] = (_Float16)lo.w;
    h[4] = (_Float16)hi.x; h[5] = (_Float16)hi.y; h[6] = (_Float16)hi.z; h[7] = (_Float16)hi.w;
    a[s] = h;
  }

  f32x4 zero = {0.f, 0.f, 0.f, 0.f};
  f32x4 acc[8];
#pragma unroll
  for (int f = 0; f < 8; ++f) acc[f] = zero;
#pragma unroll
  for (int f = 0; f < 8; ++f)
#pragma unroll
    for (int s = 0; s < 4; ++s) {
      half8 bfrag = *reinterpret_cast<const half8*>(W1pk + (size_t)((s * 8 + f) * 64 + lane) * 8);
      acc[f] = __builtin_amdgcn_mfma_f32_16x16x32_f16(a[s], bfrag, acc[f], 0, 0, 0);
    }

#pragma unroll
  for (int f = 0; f < 8; ++f) {
    int col = f * 16 + r;
    float bv = b1f[col];
#pragma unroll
    for (int j = 0; j < 4; ++j) {
      int rl = g * 4 + j;
      float gv = gelu_exact(acc[f][j] + bv);
      *reinterpret_cast<_Float16*>(lbase + lds_swz(rl, col * 2)) = (_Float16)gv;
    }
  }

  half8 a2[4];
#pragma unroll
  for (int s = 0; s < 4; ++s)
    a2[s] = *reinterpret_cast<const half8*>(lbase + lds_swz(r, (s * 32 + g * 8) * 2));

  f32x4 acc2[8];
#pragma unroll
  for (int f = 0; f < 8; ++f) acc2[f] = zero;
#pragma unroll
  for (int f = 0; f < 8; ++f)
#pragma unroll
    for (int s = 0; s < 4; ++s) {
      half8 bfrag = *reinterpret_cast<const half8*>(W2pk + (size_t)((s * 8 + f) * 64 + lane) * 8);
      acc2[f] = __builtin_amdgcn_mfma_f32_16x16x32_f16(a2[s], bfrag, acc2[f], 0, 0, 0);
    }

#pragma unroll
  for (int f = 0; f < 8; ++f) {
    int col = f * 16 + r;
    float bv = b2f[col];
#pragma unroll
    for (int j = 0; j < 4; ++j) {
      int grow = row0 + g * 4 + j;
      if (grow < N_NODES)
        M[(size_t)grow * DIM + col] = (_Float16)gelu_exact(acc2[f][j] + bv);
    }
  }
}

// One block, 256 threads, each owns 40 contiguous elements.
__global__ __launch_bounds__(256) void scan_kernel(const int* __restrict__ hist,
                                                   int* __restrict__ row_start, int n) {
  const int PER = 40;
  __shared__ int sums[256];
  int t = threadIdx.x;
  int i0 = t * PER;
  int total = 0;
  for (int i = 0; i < PER; ++i) {
    int idx = i0 + i;
    total += (idx < n) ? hist[idx] : 0;
  }
  sums[t] = total;
  __syncthreads();
  for (int off = 1; off < 256; off <<= 1) {
    int v = (t >= off) ? sums[t - off] : 0;
    __syncthreads();
    sums[t] += v;
    __syncthreads();
  }
  int running = sums[t] - total;
  for (int i = 0; i < PER; ++i) {
    int idx = i0 + i;
    if (idx < n) {
      row_start[idx] = running;
      running += hist[idx];
    }
  }
  if (t == 255) row_start[n] = sums[255];
}

// Scatter with LDS-only atomics: cursor[d] = row_start[d] + part[b][d] (u16).
__global__ __launch_bounds__(256) void scatter_kernel(
    const int* __restrict__ node_idx, const int* __restrict__ nbr_idx,
    const float* __restrict__ ew, const int* __restrict__ row_start,
    const unsigned short* __restrict__ part, uint2* __restrict__ edge_s) {
  __shared__ int cur[N_NODES];
  int b = blockIdx.x, t = threadIdx.x;
  const unsigned short* prow = part + (size_t)b * N_NODES;
  for (int i = t; i < N_NODES; i += 256) cur[i] = row_start[i] + (int)prow[i];
  __syncthreads();
  int base0 = b * EDGES_PER_PART;
#pragma unroll
  for (int s = 0; s < 3; ++s) {
    int off = s * 1024 + t * 4;
    if (off >= EDGES_PER_PART) break;
    int base = base0 + off;
    int4 ni = *reinterpret_cast<const int4*>(&node_idx[base]);
    int4 nb = *reinterpret_cast<const int4*>(&nbr_idx[base]);
    float4 wv = *reinterpret_cast<const float4*>(&ew[base]);
    int p0 = atomicAdd(&cur[ni.x], 1);
    edge_s[p0] = make_uint2((unsigned)nb.x, __float_as_uint(wv.x));
    int p1 = atomicAdd(&cur[ni.y], 1);
    edge_s[p1] = make_uint2((unsigned)nb.y, __float_as_uint(wv.y));
    int p2 = atomicAdd(&cur[ni.z], 1);
    edge_s[p2] = make_uint2((unsigned)nb.z, __float_as_uint(wv.z));
    int p3 = atomicAdd(&cur[ni.w], 1);
    edge_s[p3] = make_uint2((unsigned)nb.w, __float_as_uint(wv.w));
  }
}

// K5: fused spmm + update. grid = 625 blocks x 512 thr, 16 rows/block.
// Phase 1 (512 thr): agg for 16 rows — 32 thr/row = 2 edge-slices x 16
//   col-threads; slice partials reduced via f32 LDS scratch; result written
//   as f16 into the swizzled LDS tile (no agg global roundtrip).
// Phase 2 (waves 0,1): out = gelu(gelu([x,agg]@U1+bu1)@U2+bu2) via f16 MFMA,
//   output fragments split across the two waves. All 512 threads hit barriers.
__global__ __launch_bounds__(512) void spmm_update_kernel(
    const int* __restrict__ row_start, const uint2* __restrict__ edge_s,
    const __half* __restrict__ M, const float* __restrict__ x,
    const _Float16* __restrict__ U1pk, const float* __restrict__ bu1,
    const _Float16* __restrict__ U2pk, const float* __restrict__ bu2,
    float* __restrict__ out) {
  __shared__ float scratch[16][128];
  __shared__ char tile[4096];
  int t = threadIdx.x;
  int row0 = blockIdx.x * 16;

  {
    int r = t >> 5;       // 0..15 local row
    int q = t & 31;
    int slice = q >> 4;   // 0/1: even/odd 8-edge batch
    int sub = q & 15;     // col block: cols sub*8..sub*8+7
    int row = row0 + r;
    int s = row_start[row];
    int e_end = row_start[row + 1];
    float acc[8];
#pragma unroll
    for (int c = 0; c < 8; ++c) acc[c] = 0.f;
    const __half* Mb = M + sub * 8;
    for (int base = s + slice * 8; base < e_end; base += 16) {
      uint2 pk[8];
#pragma unroll
      for (int k = 0; k < 8; ++k) {
        int e = base + k;
        pk[k] = edge_s[(e < e_end) ? e : s];
        if (e >= e_end) pk[k].y = 0u;
      }
      uint4 raw[8];
#pragma unroll
      for (int k = 0; k < 8; ++k)
        raw[k] = *reinterpret_cast<const uint4*>(Mb + (size_t)pk[k].x * DIM);
#pragma unroll
      for (int k = 0; k < 8; ++k) {
        float w = __uint_as_float(pk[k].y);
        const __half2* h2 = reinterpret_cast<const __half2*>(&raw[k]);
#pragma unroll
        for (int qq = 0; qq < 4; ++qq) {
          float2 f = __half22float2(h2[qq]);
          acc[2 * qq] = fmaf(w, f.x, acc[2 * qq]);
          acc[2 * qq + 1] = fmaf(w, f.y, acc[2 * qq + 1]);
        }
      }
    }
    if (slice == 1) {
      *reinterpret_cast<float4*>(&scratch[r][sub * 8]) =
          make_float4(acc[0], acc[1], acc[2], acc[3]);
      *reinterpret_cast<float4*>(&scratch[r][sub * 8 + 4]) =
          make_float4(acc[4], acc[5], acc[6], acc[7]);
    }
    __syncthreads();
    if (slice == 0) {
      float4 o0 = *reinterpret_cast<const float4*>(&scratch[r][sub * 8]);
      float4 o1 = *reinterpret_cast<const float4*>(&scratch[r][sub * 8 + 4]);
      acc[0] += o0.x; acc[1] += o0.y; acc[2] += o0.z; acc[3] += o0.w;
      acc[4] += o1.x; acc[5] += o1.y; acc[6] += o1.z; acc[7] += o1.w;
      int cnt = e_end - s;
      float inv = 1.f / (float)(cnt > 0 ? cnt : 1);
      half8 h;
#pragma unroll
      for (int c = 0; c < 8; ++c) h[c] = (_Float16)(acc[c] * inv);
      *reinterpret_cast<half8*>(tile + lds_swz(r, sub * 16)) = h;
    }
  }
  __syncthreads();

  int wid = t >> 6, lane = t & 63;
  bool act = wid < 2;
  int r = lane & 15, g = lane >> 4;
  half8 a[8];
  if (act) {
    int arow = row0 + r;
    const float* xp = x + (size_t)arow * DIM;
#pragma unroll
    for (int s = 0; s < 4; ++s) {
      float4 lo = *reinterpret_cast<const float4*>(xp + s * 32 + g * 8);
      float4 hi = *reinterpret_cast<const float4*>(xp + s * 32 + g * 8 + 4);
      half8 h;
      h[0] = (_Float16)lo.x; h[1] = (_Float16)lo.y; h[2] = (_Float16)lo.z; h[3] = (_Float16)lo.w;
      h[4] = (_Float16)hi.x; h[5] = (_Float16)hi.y; h[6] = (_Float16)hi.z; h[7] = (_Float16)hi.w;
      a[s] = h;
    }
#pragma unroll
    for (int s = 0; s < 4; ++s)
      a[4 + s] = *reinterpret_cast<const half8*>(tile + lds_swz(r, (s * 32 + g * 8) * 2));
  }
  __syncthreads();  // all agg-frag reads done before layer-1 writes into tile

  f32x4 zero = {0.f, 0.f, 0.f, 0.f};
  if (act) {
    f32x4 acc1[4];
#pragma unroll
    for (int fi = 0; fi < 4; ++fi) acc1[fi] = zero;
#pragma unroll
    for (int fi = 0; fi < 4; ++fi) {
      int f = wid * 4 + fi;
#pragma unroll
      for (int s = 0; s < 8; ++s) {
        half8 bfrag = *reinterpret_cast<const half8*>(U1pk + (size_t)((s * 8 + f) * 64 + lane) * 8);
        acc1[fi] = __builtin_amdgcn_mfma_f32_16x16x32_f16(a[s], bfrag, acc1[fi], 0, 0, 0);
      }
    }
#pragma unroll
    for (int fi = 0; fi < 4; ++fi) {
      int f = wid * 4 + fi;
      int col = f * 16 + r;
      float bv = bu1[col];
#pragma unroll
      for (int j = 0; j < 4; ++j) {
        int rl = g * 4 + j;
        float gv = gelu_exact(acc1[fi][j] + bv);
        *reinterpret_cast<_Float16*>(tile + lds_swz(rl, col * 2)) = (_Float16)gv;
      }
    }
  }
  __syncthreads();  // layer-1 tile complete before layer-2 reads

  if (act) {
    half8 a2[4];
#pragma unroll
    for (int s = 0; s < 4; ++s)
      a2[s] = *reinterpret_cast<const half8*>(tile + lds_swz(r, (s * 32 + g * 8) * 2));

    f32x4 acc2[4];
#pragma unroll
    for (int fi = 0; fi < 4; ++fi) acc2[fi] = zero;
#pragma unroll
    for (int fi = 0; fi < 4; ++fi) {
      int f = wid * 4 + fi;
#pragma unroll
      for (int s = 0; s < 4; ++s) {
        half8 bfrag = *reinterpret_cast<const half8*>(U2pk + (size_t)((s * 8 + f) * 64 + lane) * 8);
        acc2[fi] = __builtin_amdgcn_mfma_f32_16x16x32_f16(a2[s], bfrag, acc2[fi], 0, 0, 0);
      }
    }
#pragma unroll
    for (int fi = 0; fi < 4; ++fi) {
      int f = wid * 4 + fi;
      int col = f * 16 + r;
      float bv = bu2[col];
#pragma unroll
      for (int j = 0; j < 4; ++j) {
        int grow = row0 + g * 4 + j;
        out[(size_t)grow * DIM + col] = gelu_exact(acc2[fi][j] + bv);
      }
    }
  }
}

extern "C" void kernel_launch(void* const* d_in, const int* in_sizes, int n_in,
                              void* d_out, int out_size, void* d_ws, size_t ws_size,
                              hipStream_t stream) {
  const float* x = (const float*)d_in[0];
  const int* edges = (const int*)d_in[1];
  const float* ew = (const float*)d_in[2];

  const int* node_idx = edges;            // edges[0, :]
  const int* nbr_idx = edges + N_EDGES;   // edges[1, :]

  char* wsp = (char*)d_ws;
  auto alloc = [&](size_t bytes) {
    char* p = wsp;
    wsp += (bytes + 255) & ~(size_t)255;
    return p;
  };
  _Float16* M = (_Float16*)alloc((size_t)N_NODES * DIM * 2);
  _Float16* W1pk = (_Float16*)alloc(128 * 128 * 2);
  _Float16* W2pk = (_Float16*)alloc(128 * 128 * 2);
  _Float16* U1pk = (_Float16*)alloc(256 * 128 * 2);
  _Float16* U2pk = (_Float16*)alloc(128 * 128 * 2);
  float* b1f = (float*)alloc(128 * 4);
  float* b2f = (float*)alloc(128 * 4);
  float* bu1 = (float*)alloc(128 * 4);
  float* bu2 = (float*)alloc(128 * 4);
  int* hist = (int*)alloc(N_NODES * 4);
  int* row_start = (int*)alloc((N_NODES + 1) * 4);
  unsigned short* part = (unsigned short*)alloc((size_t)PART_BLOCKS * N_NODES * 2);
  uint2* edge_s = (uint2*)alloc((size_t)N_EDGES * 8);

  FoldAll fa;
  fa.g[0] = (const float*)d_in[3];  fa.bb[0] = (const float*)d_in[4];
  fa.m[0] = (const float*)d_in[5];  fa.v[0] = (const float*)d_in[6];
  fa.W[0] = (const float*)d_in[7];  fa.bias[0] = (const float*)d_in[8];
  fa.g[1] = (const float*)d_in[9];  fa.bb[1] = (const float*)d_in[10];
  fa.m[1] = (const float*)d_in[11]; fa.v[1] = (const float*)d_in[12];
  fa.W[1] = (const float*)d_in[13]; fa.bias[1] = (const float*)d_in[14];
  fa.g[2] = (const float*)d_in[15]; fa.bb[2] = (const float*)d_in[16];
  fa.m[2] = (const float*)d_in[17]; fa.v[2] = (const float*)d_in[18];
  fa.W[2] = (const float*)d_in[19]; fa.bias[2] = (const float*)d_in[20];
  fa.g[3] = (const float*)d_in[21]; fa.bb[3] = (const float*)d_in[22];
  fa.m[3] = (const float*)d_in[23]; fa.v[3] = (const float*)d_in[24];
  fa.W[3] = (const float*)d_in[25]; fa.bias[3] = (const float*)d_in[26];
  fa.pk[0] = W1pk; fa.pk[1] = W2pk; fa.pk[2] = U1pk; fa.pk[3] = U2pk;
  fa.bf[0] = b1f; fa.bf[1] = b2f; fa.bf[2] = bu1; fa.bf[3] = bu2;
  fa.din[0] = 128; fa.din[1] = 128; fa.din[2] = 256; fa.din[3] = 128;
  fa.S[0] = 4; fa.S[1] = 4; fa.S[2] = 8; fa.S[3] = 4;

  fold_hist_kernel<<<44 + PART_BLOCKS, 256, 0, stream>>>(fa, node_idx, part);
  merge_msg_kernel<<<40 + MSG64_BLOCKS, 256, 0, stream>>>(
      part, hist, x, W1pk, b1f, W2pk, b2f, M);
  scan_kernel<<<1, 256, 0, stream>>>(hist, row_start, N_NODES);
  scatter_kernel<<<PART_BLOCKS, 256, 0, stream>>>(node_idx, nbr_idx, ew, row_start, part, edge_s);
  spmm_update_kernel<<<SU_BLOCKS, 512, 0, stream>>>(
      row_start, edge_s, (const __half*)M, x, U1pk, bu1, U2pk, bu2, (float*)d_out);
}

// Round 11
// 117.192 us; speedup vs baseline: 1.6817x; 1.0660x over previous
//
#include <hip/hip_runtime.h>
#include <hip/hip_bf16.h>
#include <hip/hip_fp16.h>
#include <math.h>

#define N_NODES 10000
#define DIM 128
#define N_EDGES 640000
#define BN_EPS 1e-3f

#define PART_BLOCKS 250       // 640000 / 2560
#define EDGES_PER_PART 2560
#define MSG64_BLOCKS 157      // ceil(10000 / 64)
#define SU_BLOCKS 1250        // 10000 / 8

typedef _Float16 half8 __attribute__((ext_vector_type(8)));
typedef float f32x4 __attribute__((ext_vector_type(4)));

__device__ __forceinline__ float gelu_exact(float x) {
  return 0.5f * x * (1.0f + erff(x * 0.70710678f));
}

// Swizzled LDS tile: [16 rows][128 cols] f16, row stride 256 B.
__device__ __forceinline__ int lds_swz(int row, int colbyte) {
  return ((row * 256 + colbyte) ^ ((row & 7) << 4));
}

struct FoldAll {
  const float* g[4];
  const float* bb[4];
  const float* m[4];
  const float* v[4];
  const float* W[4];
  const float* bias[4];
  _Float16* pk[4];
  float* bf[4];
  int din[4];
  int S[4];  // K/32
};

// K1: grid = 44 + PART_BLOCKS blocks x 256 thr.
// b in [0,40): pack W fragments (f16, B-frag layout, BN-scale folded).
// b in [40,44): folded bias: bf = bias + t @ W.
// b >= 44: per-block LDS histogram of 2560 edges -> u16 partial row.
__global__ __launch_bounds__(256) void fold_hist_kernel(FoldAll fa,
                                                        const int* __restrict__ node_idx,
                                                        unsigned short* __restrict__ part) {
  __shared__ int lh[N_NODES];
  __shared__ float t_sh[256];
  __shared__ float bpart[128];
  int b = blockIdx.x, t = threadIdx.x;
  if (b >= 44) {
    int pb = b - 44;
    for (int i = t; i < N_NODES; i += 256) lh[i] = 0;
    __syncthreads();
    int base0 = pb * EDGES_PER_PART;
#pragma unroll
    for (int s = 0; s < 3; ++s) {
      int off = s * 1024 + t * 4;
      if (off < EDGES_PER_PART) {
        int4 vv = *reinterpret_cast<const int4*>(&node_idx[base0 + off]);
        atomicAdd(&lh[vv.x], 1);
        atomicAdd(&lh[vv.y], 1);
        atomicAdd(&lh[vv.z], 1);
        atomicAdd(&lh[vv.w], 1);
      }
    }
    __syncthreads();
    unsigned short* prow = part + (size_t)pb * N_NODES;
    for (int i = t; i < N_NODES; i += 256) prow[i] = (unsigned short)lh[i];
    return;
  }
  if (b >= 40) {
    int p = b - 40;
    int din = fa.din[p];
    const float* W = fa.W[p];
    for (int k = t; k < din; k += 256) {
      float sc = fa.g[p][k] * rsqrtf(fa.v[p][k] + BN_EPS);
      t_sh[k] = fa.bb[p][k] - fa.m[p][k] * sc;
    }
    __syncthreads();
    int j = t & 127, kh = t >> 7;
    int half = din >> 1;
    float acc = 0.f;
    for (int k = kh * half; k < (kh + 1) * half; ++k)
      acc = fmaf(t_sh[k], W[k * 128 + j], acc);
    if (kh == 1) bpart[j] = acc;
    __syncthreads();
    if (kh == 0) fa.bf[p][j] = acc + bpart[j] + fa.bias[p][j];
    return;
  }
  int p, lf;
  if (b < 8)       { p = 0; lf = b * 256 + t; }
  else if (b < 16) { p = 1; lf = (b - 8) * 256 + t; }
  else if (b < 32) { p = 2; lf = (b - 16) * 256 + t; }
  else             { p = 3; lf = (b - 32) * 256 + t; }
  int S = fa.S[p];
  int l = lf & 63;
  int fs = lf >> 6;
  int f = fs & 7, s = fs >> 3;
  if (s >= S) return;
  const float* W = fa.W[p];
  const float* g = fa.g[p];
  const float* v = fa.v[p];
  int k0 = s * 32 + (l >> 4) * 8;
  int col = f * 16 + (l & 15);
  half8 h;
#pragma unroll
  for (int i = 0; i < 8; ++i) {
    int k = k0 + i;
    float sc = g[k] * rsqrtf(v[k] + BN_EPS);
    h[i] = (_Float16)(sc * W[k * 128 + col]);
  }
  *reinterpret_cast<half8*>(fa.pk[p] + (size_t)lf * 8) = h;
}

// K2: grid = 40 + MSG64_BLOCKS blocks x 256 thr.
// b in [0,40): merge — per bin, prefix over 250 u16 partials (chunked), total
//   -> hist[bin]; partials become per-block exclusive offsets in place.
// b >= 40: per-node message via f16 MFMA, 4 waves x 16 rows.
__global__ __launch_bounds__(256) void merge_msg_kernel(
    unsigned short* __restrict__ part, int* __restrict__ hist,
    const float* __restrict__ x,
    const _Float16* __restrict__ W1pk, const float* __restrict__ b1f,
    const _Float16* __restrict__ W2pk, const float* __restrict__ b2f,
    _Float16* __restrict__ M) {
  __shared__ char lds_raw[4 * 4096];
  int b = blockIdx.x, t = threadIdx.x;
  if (b < 40) {
    int bin = b * 256 + t;
    if (bin >= N_NODES) return;
    int sum = 0;
#pragma unroll
    for (int c = 0; c < PART_BLOCKS; c += 25) {
      int vals[25];
#pragma unroll
      for (int i = 0; i < 25; ++i) vals[i] = part[(size_t)(c + i) * N_NODES + bin];
#pragma unroll
      for (int i = 0; i < 25; ++i) {
        part[(size_t)(c + i) * N_NODES + bin] = (unsigned short)sum;
        sum += vals[i];
      }
    }
    hist[bin] = sum;
    return;
  }
  int wid = t >> 6, lane = t & 63;
  int r = lane & 15, g = lane >> 4;
  int row0 = (b - 40) * 64 + wid * 16;
  char* lbase = lds_raw + wid * 4096;

  int arow = row0 + r;
  if (arow > N_NODES - 1) arow = N_NODES - 1;
  const float* xp = x + (size_t)arow * DIM;

  half8 a[4];
#pragma unroll
  for (int s = 0; s < 4; ++s) {
    float4 lo = *reinterpret_cast<const float4*>(xp + s * 32 + g * 8);
    float4 hi = *reinterpret_cast<const float4*>(xp + s * 32 + g * 8 + 4);
    half8 h;
    h[0] = (_Float16)lo.x; h[1] = (_Float16)lo.y; h[2] = (_Float16)lo.z; h[3] = (_Float16)lo.w;
    h[4] = (_Float16)hi.x; h[5] = (_Float16)hi.y; h[6] = (_Float16)hi.z; h[7] = (_Float16)hi.w;
    a[s] = h;
  }

  f32x4 zero = {0.f, 0.f, 0.f, 0.f};
  f32x4 acc[8];
#pragma unroll
  for (int f = 0; f < 8; ++f) acc[f] = zero;
#pragma unroll
  for (int f = 0; f < 8; ++f)
#pragma unroll
    for (int s = 0; s < 4; ++s) {
      half8 bfrag = *reinterpret_cast<const half8*>(W1pk + (size_t)((s * 8 + f) * 64 + lane) * 8);
      acc[f] = __builtin_amdgcn_mfma_f32_16x16x32_f16(a[s], bfrag, acc[f], 0, 0, 0);
    }

#pragma unroll
  for (int f = 0; f < 8; ++f) {
    int col = f * 16 + r;
    float bv = b1f[col];
#pragma unroll
    for (int j = 0; j < 4; ++j) {
      int rl = g * 4 + j;
      float gv = gelu_exact(acc[f][j] + bv);
      *reinterpret_cast<_Float16*>(lbase + lds_swz(rl, col * 2)) = (_Float16)gv;
    }
  }

  half8 a2[4];
#pragma unroll
  for (int s = 0; s < 4; ++s)
    a2[s] = *reinterpret_cast<const half8*>(lbase + lds_swz(r, (s * 32 + g * 8) * 2));

  f32x4 acc2[8];
#pragma unroll
  for (int f = 0; f < 8; ++f) acc2[f] = zero;
#pragma unroll
  for (int f = 0; f < 8; ++f)
#pragma unroll
    for (int s = 0; s < 4; ++s) {
      half8 bfrag = *reinterpret_cast<const half8*>(W2pk + (size_t)((s * 8 + f) * 64 + lane) * 8);
      acc2[f] = __builtin_amdgcn_mfma_f32_16x16x32_f16(a2[s], bfrag, acc2[f], 0, 0, 0);
    }

#pragma unroll
  for (int f = 0; f < 8; ++f) {
    int col = f * 16 + r;
    float bv = b2f[col];
#pragma unroll
    for (int j = 0; j < 4; ++j) {
      int grow = row0 + g * 4 + j;
      if (grow < N_NODES)
        M[(size_t)grow * DIM + col] = (_Float16)gelu_exact(acc2[f][j] + bv);
    }
  }
}

// K3: scatter with in-block global scan (removes the scan dispatch).
// Each block: chunked scan of hist -> global row_start prefix (block 0 also
// stores row_start to global for K4), cursor = prefix + part[b] (u16), then
// LDS-atomic scatter of this block's 2560 edges.
__global__ __launch_bounds__(256) void scatter_kernel(
    const int* __restrict__ node_idx, const int* __restrict__ nbr_idx,
    const float* __restrict__ ew, const int* __restrict__ hist,
    const unsigned short* __restrict__ part, uint2* __restrict__ edge_s,
    int* __restrict__ row_start) {
  __shared__ int cur[N_NODES];
  __shared__ int sums[256];
  int b = blockIdx.x, t = threadIdx.x;
  const int PER = 40;  // 256 * 40 >= 10000
  int i0 = t * PER;
  int lh[PER];
  int total = 0;
#pragma unroll
  for (int i = 0; i < PER; ++i) {
    int idx = i0 + i;
    lh[i] = (idx < N_NODES) ? hist[idx] : 0;
    total += lh[i];
  }
  sums[t] = total;
  __syncthreads();
  for (int off = 1; off < 256; off <<= 1) {
    int v = (t >= off) ? sums[t - off] : 0;
    __syncthreads();
    sums[t] += v;
    __syncthreads();
  }
  int running = sums[t] - total;  // global exclusive prefix of this chunk
  const unsigned short* prow = part + (size_t)b * N_NODES;
  bool w0 = (b == 0);
#pragma unroll
  for (int i = 0; i < PER; ++i) {
    int idx = i0 + i;
    if (idx < N_NODES) {
      cur[idx] = running + (int)prow[idx];
      if (w0) row_start[idx] = running;
      running += lh[i];
    }
  }
  if (w0 && t == 255) row_start[N_NODES] = running;
  __syncthreads();

  int base0 = b * EDGES_PER_PART;
#pragma unroll
  for (int s = 0; s < 3; ++s) {
    int off = s * 1024 + t * 4;
    if (off >= EDGES_PER_PART) break;
    int base = base0 + off;
    int4 ni = *reinterpret_cast<const int4*>(&node_idx[base]);
    int4 nb = *reinterpret_cast<const int4*>(&nbr_idx[base]);
    float4 wv = *reinterpret_cast<const float4*>(&ew[base]);
    int p0 = atomicAdd(&cur[ni.x], 1);
    edge_s[p0] = make_uint2((unsigned)nb.x, __float_as_uint(wv.x));
    int p1 = atomicAdd(&cur[ni.y], 1);
    edge_s[p1] = make_uint2((unsigned)nb.y, __float_as_uint(wv.y));
    int p2 = atomicAdd(&cur[ni.z], 1);
    edge_s[p2] = make_uint2((unsigned)nb.z, __float_as_uint(wv.z));
    int p3 = atomicAdd(&cur[ni.w], 1);
    edge_s[p3] = make_uint2((unsigned)nb.w, __float_as_uint(wv.w));
  }
}

// K4: fused spmm + update. grid = 1250 blocks x 512 thr, 8 rows/block.
// Phase 1: one WAVE per row — 4 edge-slices x 16 col-threads, 8-edge batches
//   (avg 2 iterations/wave); slice partials reduced via f32 LDS scratch; agg
//   written f16 into swizzled tile rows 0..7.
// Phase 2 (waves 0-3): MFMA on a 16-row tile with rows 8-15 zero-padded
//   (unstored); U1/U2 output fragments split 2-per-wave.
// 16.4 KB LDS, 512 thr -> 4 blocks/CU co-resident.
__global__ __launch_bounds__(512) void spmm_update_kernel(
    const int* __restrict__ row_start, const uint2* __restrict__ edge_s,
    const __half* __restrict__ M, const float* __restrict__ x,
    const _Float16* __restrict__ U1pk, const float* __restrict__ bu1,
    const _Float16* __restrict__ U2pk, const float* __restrict__ bu2,
    float* __restrict__ out) {
  __shared__ float scratch[3][8][128];
  __shared__ char tile[4096];
  int t = threadIdx.x;
  int row0 = blockIdx.x * 8;

  {
    int r = t >> 6;       // 0..7 local row (= wave id)
    int q = t & 63;
    int slice = q >> 4;   // 0..3
    int sub = q & 15;     // cols sub*8 .. sub*8+7
    int row = row0 + r;
    int s = row_start[row];
    int e_end = row_start[row + 1];
    float acc[8];
#pragma unroll
    for (int c = 0; c < 8; ++c) acc[c] = 0.f;
    const __half* Mb = M + sub * 8;
    for (int base = s + slice * 8; base < e_end; base += 32) {
      uint2 pk[8];
#pragma unroll
      for (int k = 0; k < 8; ++k) {
        int e = base + k;
        pk[k] = edge_s[(e < e_end) ? e : s];
        if (e >= e_end) pk[k].y = 0u;
      }
      uint4 raw[8];
#pragma unroll
      for (int k = 0; k < 8; ++k)
        raw[k] = *reinterpret_cast<const uint4*>(Mb + (size_t)pk[k].x * DIM);
#pragma unroll
      for (int k = 0; k < 8; ++k) {
        float w = __uint_as_float(pk[k].y);
        const __half2* h2 = reinterpret_cast<const __half2*>(&raw[k]);
#pragma unroll
        for (int qq = 0; qq < 4; ++qq) {
          float2 f = __half22float2(h2[qq]);
          acc[2 * qq] = fmaf(w, f.x, acc[2 * qq]);
          acc[2 * qq + 1] = fmaf(w, f.y, acc[2 * qq + 1]);
        }
      }
    }
    if (slice >= 1) {
      *reinterpret_cast<float4*>(&scratch[slice - 1][r][sub * 8]) =
          make_float4(acc[0], acc[1], acc[2], acc[3]);
      *reinterpret_cast<float4*>(&scratch[slice - 1][r][sub * 8 + 4]) =
          make_float4(acc[4], acc[5], acc[6], acc[7]);
    }
    __syncthreads();
    if (slice == 0) {
#pragma unroll
      for (int sl = 0; sl < 3; ++sl) {
        float4 o0 = *reinterpret_cast<const float4*>(&scratch[sl][r][sub * 8]);
        float4 o1 = *reinterpret_cast<const float4*>(&scratch[sl][r][sub * 8 + 4]);
        acc[0] += o0.x; acc[1] += o0.y; acc[2] += o0.z; acc[3] += o0.w;
        acc[4] += o1.x; acc[5] += o1.y; acc[6] += o1.z; acc[7] += o1.w;
      }
      int cnt = e_end - s;
      float inv = 1.f / (float)(cnt > 0 ? cnt : 1);
      half8 h;
#pragma unroll
      for (int c = 0; c < 8; ++c) h[c] = (_Float16)(acc[c] * inv);
      *reinterpret_cast<half8*>(tile + lds_swz(r, sub * 16)) = h;
    }
  }
  __syncthreads();

  int wid = t >> 6, lane = t & 63;
  bool act = wid < 4;
  int r = lane & 15, g = lane >> 4;
  half8 hzero;
#pragma unroll
  for (int i = 0; i < 8; ++i) hzero[i] = (_Float16)0.f;

  half8 a[8];
#pragma unroll
  for (int s = 0; s < 8; ++s) a[s] = hzero;
  if (act && r < 8) {
    const float* xp = x + (size_t)(row0 + r) * DIM;
#pragma unroll
    for (int s = 0; s < 4; ++s) {
      float4 lo = *reinterpret_cast<const float4*>(xp + s * 32 + g * 8);
      float4 hi = *reinterpret_cast<const float4*>(xp + s * 32 + g * 8 + 4);
      half8 h;
      h[0] = (_Float16)lo.x; h[1] = (_Float16)lo.y; h[2] = (_Float16)lo.z; h[3] = (_Float16)lo.w;
      h[4] = (_Float16)hi.x; h[5] = (_Float16)hi.y; h[6] = (_Float16)hi.z; h[7] = (_Float16)hi.w;
      a[s] = h;
    }
#pragma unroll
    for (int s = 0; s < 4; ++s)
      a[4 + s] = *reinterpret_cast<const half8*>(tile + lds_swz(r, (s * 32 + g * 8) * 2));
  }
  __syncthreads();  // agg-tile reads done before layer-1 overwrites tile

  f32x4 zero = {0.f, 0.f, 0.f, 0.f};
  if (act) {
    f32x4 acc1[2];
    acc1[0] = zero; acc1[1] = zero;
#pragma unroll
    for (int fi = 0; fi < 2; ++fi) {
      int f = wid * 2 + fi;
#pragma unroll
      for (int s = 0; s < 8; ++s) {
        half8 bfrag = *reinterpret_cast<const half8*>(U1pk + (size_t)((s * 8 + f) * 64 + lane) * 8);
        acc1[fi] = __builtin_amdgcn_mfma_f32_16x16x32_f16(a[s], bfrag, acc1[fi], 0, 0, 0);
      }
    }
#pragma unroll
    for (int fi = 0; fi < 2; ++fi) {
      int f = wid * 2 + fi;
      int col = f * 16 + r;
      float bv = bu1[col];
#pragma unroll
      for (int j = 0; j < 4; ++j) {
        int rl = g * 4 + j;
        float gv = gelu_exact(acc1[fi][j] + bv);
        *reinterpret_cast<_Float16*>(tile + lds_swz(rl, col * 2)) = (_Float16)gv;
      }
    }
  }
  __syncthreads();  // layer-1 tile complete before layer-2 reads

  if (act) {
    half8 a2[4];
#pragma unroll
    for (int s = 0; s < 4; ++s) a2[s] = hzero;
    if (r < 8) {
#pragma unroll
      for (int s = 0; s < 4; ++s)
        a2[s] = *reinterpret_cast<const half8*>(tile + lds_swz(r, (s * 32 + g * 8) * 2));
    }
    f32x4 acc2[2];
    acc2[0] = zero; acc2[1] = zero;
#pragma unroll
    for (int fi = 0; fi < 2; ++fi) {
      int f = wid * 2 + fi;
#pragma unroll
      for (int s = 0; s < 4; ++s) {
        half8 bfrag = *reinterpret_cast<const half8*>(U2pk + (size_t)((s * 8 + f) * 64 + lane) * 8);
        acc2[fi] = __builtin_amdgcn_mfma_f32_16x16x32_f16(a2[s], bfrag, acc2[fi], 0, 0, 0);
      }
    }
#pragma unroll
    for (int fi = 0; fi < 2; ++fi) {
      int f = wid * 2 + fi;
      int col = f * 16 + r;
      float bv = bu2[col];
#pragma unroll
      for (int j = 0; j < 4; ++j) {
        int rloc = g * 4 + j;
        if (rloc < 8)
          out[(size_t)(row0 + rloc) * DIM + col] = gelu_exact(acc2[fi][j] + bv);
      }
    }
  }
}

extern "C" void kernel_launch(void* const* d_in, const int* in_sizes, int n_in,
                              void* d_out, int out_size, void* d_ws, size_t ws_size,
                              hipStream_t stream) {
  const float* x = (const float*)d_in[0];
  const int* edges = (const int*)d_in[1];
  const float* ew = (const float*)d_in[2];

  const int* node_idx = edges;            // edges[0, :]
  const int* nbr_idx = edges + N_EDGES;   // edges[1, :]

  char* wsp = (char*)d_ws;
  auto alloc = [&](size_t bytes) {
    char* p = wsp;
    wsp += (bytes + 255) & ~(size_t)255;
    return p;
  };
  _Float16* M = (_Float16*)alloc((size_t)N_NODES * DIM * 2);
  _Float16* W1pk = (_Float16*)alloc(128 * 128 * 2);
  _Float16* W2pk = (_Float16*)alloc(128 * 128 * 2);
  _Float16* U1pk = (_Float16*)alloc(256 * 128 * 2);
  _Float16* U2pk = (_Float16*)alloc(128 * 128 * 2);
  float* b1f = (float*)alloc(128 * 4);
  float* b2f = (float*)alloc(128 * 4);
  float* bu1 = (float*)alloc(128 * 4);
  float* bu2 = (float*)alloc(128 * 4);
  int* hist = (int*)alloc(N_NODES * 4);
  int* row_start = (int*)alloc((N_NODES + 1) * 4);
  unsigned short* part = (unsigned short*)alloc((size_t)PART_BLOCKS * N_NODES * 2);
  uint2* edge_s = (uint2*)alloc((size_t)N_EDGES * 8);

  FoldAll fa;
  fa.g[0] = (const float*)d_in[3];  fa.bb[0] = (const float*)d_in[4];
  fa.m[0] = (const float*)d_in[5];  fa.v[0] = (const float*)d_in[6];
  fa.W[0] = (const float*)d_in[7];  fa.bias[0] = (const float*)d_in[8];
  fa.g[1] = (const float*)d_in[9];  fa.bb[1] = (const float*)d_in[10];
  fa.m[1] = (const float*)d_in[11]; fa.v[1] = (const float*)d_in[12];
  fa.W[1] = (const float*)d_in[13]; fa.bias[1] = (const float*)d_in[14];
  fa.g[2] = (const float*)d_in[15]; fa.bb[2] = (const float*)d_in[16];
  fa.m[2] = (const float*)d_in[17]; fa.v[2] = (const float*)d_in[18];
  fa.W[2] = (const float*)d_in[19]; fa.bias[2] = (const float*)d_in[20];
  fa.g[3] = (const float*)d_in[21]; fa.bb[3] = (const float*)d_in[22];
  fa.m[3] = (const float*)d_in[23]; fa.v[3] = (const float*)d_in[24];
  fa.W[3] = (const float*)d_in[25]; fa.bias[3] = (const float*)d_in[26];
  fa.pk[0] = W1pk; fa.pk[1] = W2pk; fa.pk[2] = U1pk; fa.pk[3] = U2pk;
  fa.bf[0] = b1f; fa.bf[1] = b2f; fa.bf[2] = bu1; fa.bf[3] = bu2;
  fa.din[0] = 128; fa.din[1] = 128; fa.din[2] = 256; fa.din[3] = 128;
  fa.S[0] = 4; fa.S[1] = 4; fa.S[2] = 8; fa.S[3] = 4;

  fold_hist_kernel<<<44 + PART_BLOCKS, 256, 0, stream>>>(fa, node_idx, part);
  merge_msg_kernel<<<40 + MSG64_BLOCKS, 256, 0, stream>>>(
      part, hist, x, W1pk, b1f, W2pk, b2f, M);
  scatter_kernel<<<PART_BLOCKS, 256, 0, stream>>>(
      node_idx, nbr_idx, ew, hist, part, edge_s, row_start);
  spmm_update_kernel<<<SU_BLOCKS, 512, 0, stream>>>(
      row_start, edge_s, (const __half*)M, x, U1pk, bu1, U2pk, bu2, (float*)d_out);
}

// Round 12
// 114.567 us; speedup vs baseline: 1.7202x; 1.0229x over previous
//
#include <hip/hip_runtime.h>
#include <hip/hip_bf16.h>
#include <hip/hip_fp16.h>
#include <math.h>

#define N_NODES 10000
#define DIM 128
#define N_EDGES 640000
#define BN_EPS 1e-3f

#define QUARTER 2500
#define PART_BLOCKS 250       // edge chunks: 640000 / 2560
#define EDGES_PER_PART 2560
#define HIST_GRID 1000        // 250 chunks x 4 quarters
#define MSG64_BLOCKS 157      // ceil(10000 / 64)
#define SU_BLOCKS 1250        // 10000 / 8
#define HIST_PAD 10240

typedef _Float16 half8 __attribute__((ext_vector_type(8)));
typedef float f32x4 __attribute__((ext_vector_type(4)));

__device__ __forceinline__ float gelu_exact(float x) {
  return 0.5f * x * (1.0f + erff(x * 0.70710678f));
}

// Swizzled LDS tile: [16 rows][128 cols] f16, row stride 256 B.
__device__ __forceinline__ int lds_swz(int row, int colbyte) {
  return ((row * 256 + colbyte) ^ ((row & 7) << 4));
}

struct FoldAll {
  const float* g[4];
  const float* bb[4];
  const float* m[4];
  const float* v[4];
  const float* W[4];
  const float* bias[4];
  _Float16* pk[4];
  float* bf[4];
  int din[4];
  int S[4];  // K/32
};

// K1: grid = 44 + HIST_GRID blocks x 256 thr.
// b in [0,40): pack W fragments (f16, B-frag layout, BN-scale folded).
// b in [40,44): folded bias: bf = bias + t @ W.
// b >= 44: quarter-partitioned histogram — block (eb, q) counts chunk eb's
//   edges with dst in quarter q into a 10 KB LDS array -> u8 partial row.
__global__ __launch_bounds__(256) void fold_hist_kernel(FoldAll fa,
                                                        const int* __restrict__ node_idx,
                                                        unsigned char* __restrict__ part) {
  __shared__ int lh[QUARTER];
  __shared__ float t_sh[256];
  __shared__ float bpart[128];
  int b = blockIdx.x, t = threadIdx.x;
  if (b >= 44) {
    int pb = b - 44;
    int eb = pb >> 2;
    int q = pb & 3;
    int qbase = q * QUARTER;
    for (int i = t; i < QUARTER; i += 256) lh[i] = 0;
    __syncthreads();
    int base0 = eb * EDGES_PER_PART;
#pragma unroll
    for (int s = 0; s < 3; ++s) {
      int off = s * 1024 + t * 4;
      if (off < EDGES_PER_PART) {
        int4 vv = *reinterpret_cast<const int4*>(&node_idx[base0 + off]);
        unsigned d0 = (unsigned)(vv.x - qbase);
        unsigned d1 = (unsigned)(vv.y - qbase);
        unsigned d2 = (unsigned)(vv.z - qbase);
        unsigned d3 = (unsigned)(vv.w - qbase);
        if (d0 < QUARTER) atomicAdd(&lh[d0], 1);
        if (d1 < QUARTER) atomicAdd(&lh[d1], 1);
        if (d2 < QUARTER) atomicAdd(&lh[d2], 1);
        if (d3 < QUARTER) atomicAdd(&lh[d3], 1);
      }
    }
    __syncthreads();
    unsigned char* prow = part + (size_t)(q * PART_BLOCKS + eb) * QUARTER;
    for (int i = t; i < QUARTER; i += 256) prow[i] = (unsigned char)lh[i];
    return;
  }
  if (b >= 40) {
    int p = b - 40;
    int din = fa.din[p];
    const float* W = fa.W[p];
    for (int k = t; k < din; k += 256) {
      float sc = fa.g[p][k] * rsqrtf(fa.v[p][k] + BN_EPS);
      t_sh[k] = fa.bb[p][k] - fa.m[p][k] * sc;
    }
    __syncthreads();
    int j = t & 127, kh = t >> 7;
    int half = din >> 1;
    float acc = 0.f;
    for (int k = kh * half; k < (kh + 1) * half; ++k)
      acc = fmaf(t_sh[k], W[k * 128 + j], acc);
    if (kh == 1) bpart[j] = acc;
    __syncthreads();
    if (kh == 0) fa.bf[p][j] = acc + bpart[j] + fa.bias[p][j];
    return;
  }
  int p, lf;
  if (b < 8)       { p = 0; lf = b * 256 + t; }
  else if (b < 16) { p = 1; lf = (b - 8) * 256 + t; }
  else if (b < 32) { p = 2; lf = (b - 16) * 256 + t; }
  else             { p = 3; lf = (b - 32) * 256 + t; }
  int S = fa.S[p];
  int l = lf & 63;
  int fs = lf >> 6;
  int f = fs & 7, s = fs >> 3;
  if (s >= S) return;
  const float* W = fa.W[p];
  const float* g = fa.g[p];
  const float* v = fa.v[p];
  int k0 = s * 32 + (l >> 4) * 8;
  int col = f * 16 + (l & 15);
  half8 h;
#pragma unroll
  for (int i = 0; i < 8; ++i) {
    int k = k0 + i;
    float sc = g[k] * rsqrtf(v[k] + BN_EPS);
    h[i] = (_Float16)(sc * W[k * 128 + col]);
  }
  *reinterpret_cast<half8*>(fa.pk[p] + (size_t)lf * 8) = h;
}

// K2: grid = 40 + MSG64_BLOCKS blocks x 256 thr.
// b in [0,40): merge — per bin, prefix over 250 u8 partials (chunked), total
//   -> hist[bin]; partials become per-block exclusive offsets in place.
//   Bins [10000,10240) get hist=0 (pad for unguarded int4 scans downstream).
// b >= 40: per-node message via f16 MFMA, 4 waves x 16 rows.
__global__ __launch_bounds__(256) void merge_msg_kernel(
    unsigned char* __restrict__ part, int* __restrict__ hist,
    const float* __restrict__ x,
    const _Float16* __restrict__ W1pk, const float* __restrict__ b1f,
    const _Float16* __restrict__ W2pk, const float* __restrict__ b2f,
    _Float16* __restrict__ M) {
  __shared__ char lds_raw[4 * 4096];
  int b = blockIdx.x, t = threadIdx.x;
  if (b < 40) {
    int bin = b * 256 + t;
    if (bin < N_NODES) {
      int q = bin / QUARTER;
      int bp = bin - q * QUARTER;
      unsigned char* col = part + (size_t)q * PART_BLOCKS * QUARTER + bp;
      int sum = 0;
#pragma unroll
      for (int c = 0; c < PART_BLOCKS; c += 25) {
        int vals[25];
#pragma unroll
        for (int i = 0; i < 25; ++i) vals[i] = col[(size_t)(c + i) * QUARTER];
#pragma unroll
        for (int i = 0; i < 25; ++i) {
          col[(size_t)(c + i) * QUARTER] = (unsigned char)sum;
          sum += vals[i];
        }
      }
      hist[bin] = sum;
    } else if (bin < HIST_PAD) {
      hist[bin] = 0;
    }
    return;
  }
  int wid = t >> 6, lane = t & 63;
  int r = lane & 15, g = lane >> 4;
  int row0 = (b - 40) * 64 + wid * 16;
  char* lbase = lds_raw + wid * 4096;

  int arow = row0 + r;
  if (arow > N_NODES - 1) arow = N_NODES - 1;
  const float* xp = x + (size_t)arow * DIM;

  half8 a[4];
#pragma unroll
  for (int s = 0; s < 4; ++s) {
    float4 lo = *reinterpret_cast<const float4*>(xp + s * 32 + g * 8);
    float4 hi = *reinterpret_cast<const float4*>(xp + s * 32 + g * 8 + 4);
    half8 h;
    h[0] = (_Float16)lo.x; h[1] = (_Float16)lo.y; h[2] = (_Float16)lo.z; h[3] = (_Float16)lo.w;
    h[4] = (_Float16)hi.x; h[5] = (_Float16)hi.y; h[6] = (_Float16)hi.z; h[7] = (_Float16)hi.w;
    a[s] = h;
  }

  f32x4 zero = {0.f, 0.f, 0.f, 0.f};
  f32x4 acc[8];
#pragma unroll
  for (int f = 0; f < 8; ++f) acc[f] = zero;
#pragma unroll
  for (int f = 0; f < 8; ++f)
#pragma unroll
    for (int s = 0; s < 4; ++s) {
      half8 bfrag = *reinterpret_cast<const half8*>(W1pk + (size_t)((s * 8 + f) * 64 + lane) * 8);
      acc[f] = __builtin_amdgcn_mfma_f32_16x16x32_f16(a[s], bfrag, acc[f], 0, 0, 0);
    }

#pragma unroll
  for (int f = 0; f < 8; ++f) {
    int col = f * 16 + r;
    float bv = b1f[col];
#pragma unroll
    for (int j = 0; j < 4; ++j) {
      int rl = g * 4 + j;
      float gv = gelu_exact(acc[f][j] + bv);
      *reinterpret_cast<_Float16*>(lbase + lds_swz(rl, col * 2)) = (_Float16)gv;
    }
  }

  half8 a2[4];
#pragma unroll
  for (int s = 0; s < 4; ++s)
    a2[s] = *reinterpret_cast<const half8*>(lbase + lds_swz(r, (s * 32 + g * 8) * 2));

  f32x4 acc2[8];
#pragma unroll
  for (int f = 0; f < 8; ++f) acc2[f] = zero;
#pragma unroll
  for (int f = 0; f < 8; ++f)
#pragma unroll
    for (int s = 0; s < 4; ++s) {
      half8 bfrag = *reinterpret_cast<const half8*>(W2pk + (size_t)((s * 8 + f) * 64 + lane) * 8);
      acc2[f] = __builtin_amdgcn_mfma_f32_16x16x32_f16(a2[s], bfrag, acc2[f], 0, 0, 0);
    }

#pragma unroll
  for (int f = 0; f < 8; ++f) {
    int col = f * 16 + r;
    float bv = b2f[col];
#pragma unroll
    for (int j = 0; j < 4; ++j) {
      int grow = row0 + g * 4 + j;
      if (grow < N_NODES)
        M[(size_t)grow * DIM + col] = (_Float16)gelu_exact(acc2[f][j] + bv);
    }
  }
}

// K3: quarter-partitioned scatter, grid = 1000 blocks x 256 thr.
// Block (eb, q): chunked int4 scan of padded hist -> global prefix; keeps
// LDS cursor only for its quarter (10 KB); block 0 writes row_start; then
// scatters chunk eb's edges with dst in quarter q via LDS atomics.
__global__ __launch_bounds__(256) void scatter_kernel(
    const int* __restrict__ node_idx, const int* __restrict__ nbr_idx,
    const float* __restrict__ ew, const int* __restrict__ hist,
    const unsigned char* __restrict__ part, uint2* __restrict__ edge_s,
    int* __restrict__ row_start) {
  __shared__ int cur[QUARTER];
  __shared__ int sums[256];
  int bk = blockIdx.x, t = threadIdx.x;
  int eb = bk >> 2;
  int q = bk & 3;
  int qbase = q * QUARTER;
  const int PER = 40;
  int i0 = t * PER;
  int lh[PER];
  int total = 0;
#pragma unroll
  for (int i = 0; i < PER; i += 4) {
    int4 h4 = *reinterpret_cast<const int4*>(&hist[i0 + i]);
    lh[i] = h4.x; lh[i + 1] = h4.y; lh[i + 2] = h4.z; lh[i + 3] = h4.w;
    total += h4.x + h4.y + h4.z + h4.w;
  }
  sums[t] = total;
  __syncthreads();
  for (int off = 1; off < 256; off <<= 1) {
    int v = (t >= off) ? sums[t - off] : 0;
    __syncthreads();
    sums[t] += v;
    __syncthreads();
  }
  int running = sums[t] - total;  // global exclusive prefix of this chunk
  const unsigned char* prow = part + (size_t)(q * PART_BLOCKS + eb) * QUARTER;
  bool wrs = (bk == 0);
#pragma unroll
  for (int i = 0; i < PER; ++i) {
    int idx = i0 + i;
    if (idx < N_NODES) {
      unsigned d = (unsigned)(idx - qbase);
      if (d < QUARTER) cur[d] = running + (int)prow[d];
      if (wrs) row_start[idx] = running;
      running += lh[i];
    }
  }
  if (wrs && t == 255) row_start[N_NODES] = running;
  __syncthreads();

  int base0 = eb * EDGES_PER_PART;
#pragma unroll
  for (int s = 0; s < 3; ++s) {
    int off = s * 1024 + t * 4;
    if (off >= EDGES_PER_PART) break;
    int base = base0 + off;
    int4 ni = *reinterpret_cast<const int4*>(&node_idx[base]);
    int4 nb = *reinterpret_cast<const int4*>(&nbr_idx[base]);
    float4 wv = *reinterpret_cast<const float4*>(&ew[base]);
    unsigned d0 = (unsigned)(ni.x - qbase);
    unsigned d1 = (unsigned)(ni.y - qbase);
    unsigned d2 = (unsigned)(ni.z - qbase);
    unsigned d3 = (unsigned)(ni.w - qbase);
    if (d0 < QUARTER) {
      int p0 = atomicAdd(&cur[d0], 1);
      edge_s[p0] = make_uint2((unsigned)nb.x, __float_as_uint(wv.x));
    }
    if (d1 < QUARTER) {
      int p1 = atomicAdd(&cur[d1], 1);
      edge_s[p1] = make_uint2((unsigned)nb.y, __float_as_uint(wv.y));
    }
    if (d2 < QUARTER) {
      int p2 = atomicAdd(&cur[d2], 1);
      edge_s[p2] = make_uint2((unsigned)nb.z, __float_as_uint(wv.z));
    }
    if (d3 < QUARTER) {
      int p3 = atomicAdd(&cur[d3], 1);
      edge_s[p3] = make_uint2((unsigned)nb.w, __float_as_uint(wv.w));
    }
  }
}

// K4: fused spmm + update. grid = 1250 blocks x 512 thr, 8 rows/block.
// Phase 1: one WAVE per row — 4 edge-slices x 16 col-threads, 8-edge batches;
//   slice partials reduced via f32 LDS scratch; agg written f16 into swizzled
//   tile rows 0..7.
// Phase 2 (waves 0-3): MFMA on a 16-row tile with rows 8-15 zero-padded;
//   U1/U2 output fragments split 2-per-wave.
__global__ __launch_bounds__(512) void spmm_update_kernel(
    const int* __restrict__ row_start, const uint2* __restrict__ edge_s,
    const __half* __restrict__ M, const float* __restrict__ x,
    const _Float16* __restrict__ U1pk, const float* __restrict__ bu1,
    const _Float16* __restrict__ U2pk, const float* __restrict__ bu2,
    float* __restrict__ out) {
  __shared__ float scratch[3][8][128];
  __shared__ char tile[4096];
  int t = threadIdx.x;
  int row0 = blockIdx.x * 8;

  {
    int r = t >> 6;       // 0..7 local row (= wave id)
    int q = t & 63;
    int slice = q >> 4;   // 0..3
    int sub = q & 15;     // cols sub*8 .. sub*8+7
    int row = row0 + r;
    int s = row_start[row];
    int e_end = row_start[row + 1];
    float acc[8];
#pragma unroll
    for (int c = 0; c < 8; ++c) acc[c] = 0.f;
    const __half* Mb = M + sub * 8;
    for (int base = s + slice * 8; base < e_end; base += 32) {
      uint2 pk[8];
#pragma unroll
      for (int k = 0; k < 8; ++k) {
        int e = base + k;
        pk[k] = edge_s[(e < e_end) ? e : s];
        if (e >= e_end) pk[k].y = 0u;
      }
      uint4 raw[8];
#pragma unroll
      for (int k = 0; k < 8; ++k)
        raw[k] = *reinterpret_cast<const uint4*>(Mb + (size_t)pk[k].x * DIM);
#pragma unroll
      for (int k = 0; k < 8; ++k) {
        float w = __uint_as_float(pk[k].y);
        const __half2* h2 = reinterpret_cast<const __half2*>(&raw[k]);
#pragma unroll
        for (int qq = 0; qq < 4; ++qq) {
          float2 f = __half22float2(h2[qq]);
          acc[2 * qq] = fmaf(w, f.x, acc[2 * qq]);
          acc[2 * qq + 1] = fmaf(w, f.y, acc[2 * qq + 1]);
        }
      }
    }
    if (slice >= 1) {
      *reinterpret_cast<float4*>(&scratch[slice - 1][r][sub * 8]) =
          make_float4(acc[0], acc[1], acc[2], acc[3]);
      *reinterpret_cast<float4*>(&scratch[slice - 1][r][sub * 8 + 4]) =
          make_float4(acc[4], acc[5], acc[6], acc[7]);
    }
    __syncthreads();
    if (slice == 0) {
#pragma unroll
      for (int sl = 0; sl < 3; ++sl) {
        float4 o0 = *reinterpret_cast<const float4*>(&scratch[sl][r][sub * 8]);
        float4 o1 = *reinterpret_cast<const float4*>(&scratch[sl][r][sub * 8 + 4]);
        acc[0] += o0.x; acc[1] += o0.y; acc[2] += o0.z; acc[3] += o0.w;
        acc[4] += o1.x; acc[5] += o1.y; acc[6] += o1.z; acc[7] += o1.w;
      }
      int cnt = e_end - s;
      float inv = 1.f / (float)(cnt > 0 ? cnt : 1);
      half8 h;
#pragma unroll
      for (int c = 0; c < 8; ++c) h[c] = (_Float16)(acc[c] * inv);
      *reinterpret_cast<half8*>(tile + lds_swz(r, sub * 16)) = h;
    }
  }
  __syncthreads();

  int wid = t >> 6, lane = t & 63;
  bool act = wid < 4;
  int r = lane & 15, g = lane >> 4;
  half8 hzero;
#pragma unroll
  for (int i = 0; i < 8; ++i) hzero[i] = (_Float16)0.f;

  half8 a[8];
#pragma unroll
  for (int s = 0; s < 8; ++s) a[s] = hzero;
  if (act && r < 8) {
    const float* xp = x + (size_t)(row0 + r) * DIM;
#pragma unroll
    for (int s = 0; s < 4; ++s) {
      float4 lo = *reinterpret_cast<const float4*>(xp + s * 32 + g * 8);
      float4 hi = *reinterpret_cast<const float4*>(xp + s * 32 + g * 8 + 4);
      half8 h;
      h[0] = (_Float16)lo.x; h[1] = (_Float16)lo.y; h[2] = (_Float16)lo.z; h[3] = (_Float16)lo.w;
      h[4] = (_Float16)hi.x; h[5] = (_Float16)hi.y; h[6] = (_Float16)hi.z; h[7] = (_Float16)hi.w;
      a[s] = h;
    }
#pragma unroll
    for (int s = 0; s < 4; ++s)
      a[4 + s] = *reinterpret_cast<const half8*>(tile + lds_swz(r, (s * 32 + g * 8) * 2));
  }
  __syncthreads();  // agg-tile reads done before layer-1 overwrites tile

  f32x4 zero = {0.f, 0.f, 0.f, 0.f};
  if (act) {
    f32x4 acc1[2];
    acc1[0] = zero; acc1[1] = zero;
#pragma unroll
    for (int fi = 0; fi < 2; ++fi) {
      int f = wid * 2 + fi;
#pragma unroll
      for (int s = 0; s < 8; ++s) {
        half8 bfrag = *reinterpret_cast<const half8*>(U1pk + (size_t)((s * 8 + f) * 64 + lane) * 8);
        acc1[fi] = __builtin_amdgcn_mfma_f32_16x16x32_f16(a[s], bfrag, acc1[fi], 0, 0, 0);
      }
    }
#pragma unroll
    for (int fi = 0; fi < 2; ++fi) {
      int f = wid * 2 + fi;
      int col = f * 16 + r;
      float bv = bu1[col];
#pragma unroll
      for (int j = 0; j < 4; ++j) {
        int rl = g * 4 + j;
        float gv = gelu_exact(acc1[fi][j] + bv);
        *reinterpret_cast<_Float16*>(tile + lds_swz(rl, col * 2)) = (_Float16)gv;
      }
    }
  }
  __syncthreads();  // layer-1 tile complete before layer-2 reads

  if (act) {
    half8 a2[4];
#pragma unroll
    for (int s = 0; s < 4; ++s) a2[s] = hzero;
    if (r < 8) {
#pragma unroll
      for (int s = 0; s < 4; ++s)
        a2[s] = *reinterpret_cast<const half8*>(tile + lds_swz(r, (s * 32 + g * 8) * 2));
    }
    f32x4 acc2[2];
    acc2[0] = zero; acc2[1] = zero;
#pragma unroll
    for (int fi = 0; fi < 2; ++fi) {
      int f = wid * 2 + fi;
#pragma unroll
      for (int s = 0; s < 4; ++s) {
        half8 bfrag = *reinterpret_cast<const half8*>(U2pk + (size_t)((s * 8 + f) * 64 + lane) * 8);
        acc2[fi] = __builtin_amdgcn_mfma_f32_16x16x32_f16(a2[s], bfrag, acc2[fi], 0, 0, 0);
      }
    }
#pragma unroll
    for (int fi = 0; fi < 2; ++fi) {
      int f = wid * 2 + fi;
      int col = f * 16 + r;
      float bv = bu2[col];
#pragma unroll
      for (int j = 0; j < 4; ++j) {
        int rloc = g * 4 + j;
        if (rloc < 8)
          out[(size_t)(row0 + rloc) * DIM + col] = gelu_exact(acc2[fi][j] + bv);
      }
    }
  }
}

extern "C" void kernel_launch(void* const* d_in, const int* in_sizes, int n_in,
                              void* d_out, int out_size, void* d_ws, size_t ws_size,
                              hipStream_t stream) {
  const float* x = (const float*)d_in[0];
  const int* edges = (const int*)d_in[1];
  const float* ew = (const float*)d_in[2];

  const int* node_idx = edges;            // edges[0, :]
  const int* nbr_idx = edges + N_EDGES;   // edges[1, :]

  char* wsp = (char*)d_ws;
  auto alloc = [&](size_t bytes) {
    char* p = wsp;
    wsp += (bytes + 255) & ~(size_t)255;
    return p;
  };
  _Float16* M = (_Float16*)alloc((size_t)N_NODES * DIM * 2);
  _Float16* W1pk = (_Float16*)alloc(128 * 128 * 2);
  _Float16* W2pk = (_Float16*)alloc(128 * 128 * 2);
  _Float16* U1pk = (_Float16*)alloc(256 * 128 * 2);
  _Float16* U2pk = (_Float16*)alloc(128 * 128 * 2);
  float* b1f = (float*)alloc(128 * 4);
  float* b2f = (float*)alloc(128 * 4);
  float* bu1 = (float*)alloc(128 * 4);
  float* bu2 = (float*)alloc(128 * 4);
  int* hist = (int*)alloc(HIST_PAD * 4);
  int* row_start = (int*)alloc((N_NODES + 1) * 4);
  unsigned char* part = (unsigned char*)alloc((size_t)PART_BLOCKS * N_NODES);
  uint2* edge_s = (uint2*)alloc((size_t)N_EDGES * 8);

  FoldAll fa;
  fa.g[0] = (const float*)d_in[3];  fa.bb[0] = (const float*)d_in[4];
  fa.m[0] = (const float*)d_in[5];  fa.v[0] = (const float*)d_in[6];
  fa.W[0] = (const float*)d_in[7];  fa.bias[0] = (const float*)d_in[8];
  fa.g[1] = (const float*)d_in[9];  fa.bb[1] = (const float*)d_in[10];
  fa.m[1] = (const float*)d_in[11]; fa.v[1] = (const float*)d_in[12];
  fa.W[1] = (const float*)d_in[13]; fa.bias[1] = (const float*)d_in[14];
  fa.g[2] = (const float*)d_in[15]; fa.bb[2] = (const float*)d_in[16];
  fa.m[2] = (const float*)d_in[17]; fa.v[2] = (const float*)d_in[18];
  fa.W[2] = (const float*)d_in[19]; fa.bias[2] = (const float*)d_in[20];
  fa.g[3] = (const float*)d_in[21]; fa.bb[3] = (const float*)d_in[22];
  fa.m[3] = (const float*)d_in[23]; fa.v[3] = (const float*)d_in[24];
  fa.W[3] = (const float*)d_in[25]; fa.bias[3] = (const float*)d_in[26];
  fa.pk[0] = W1pk; fa.pk[1] = W2pk; fa.pk[2] = U1pk; fa.pk[3] = U2pk;
  fa.bf[0] = b1f; fa.bf[1] = b2f; fa.bf[2] = bu1; fa.bf[3] = bu2;
  fa.din[0] = 128; fa.din[1] = 128; fa.din[2] = 256; fa.din[3] = 128;
  fa.S[0] = 4; fa.S[1] = 4; fa.S[2] = 8; fa.S[3] = 4;

  fold_hist_kernel<<<44 + HIST_GRID, 256, 0, stream>>>(fa, node_idx, part);
  merge_msg_kernel<<<40 + MSG64_BLOCKS, 256, 0, stream>>>(
      part, hist, x, W1pk, b1f, W2pk, b2f, M);
  scatter_kernel<<<HIST_GRID, 256, 0, stream>>>(
      node_idx, nbr_idx, ew, hist, part, edge_s, row_start);
  spmm_update_kernel<<<SU_BLOCKS, 512, 0, stream>>>(
      row_start, edge_s, (const __half*)M, x, U1pk, bu1, U2pk, bu2, (float*)d_out);
}

// Round 13
// 108.070 us; speedup vs baseline: 1.8236x; 1.0601x over previous
//
#include <hip/hip_runtime.h>
#include <hip/hip_bf16.h>
#include <hip/hip_fp16.h>
#include <math.h>

#define N_NODES 10000
#define DIM 128
#define N_EDGES 640000
#define BN_EPS 1e-3f

#define QUARTER 2500
#define PART_BLOCKS 250       // edge chunks: 640000 / 2560
#define EDGES_PER_PART 2560
#define SCAT_GRID 1000        // 250 chunks x 4 quarters
#define MSG64_BLOCKS 157      // ceil(10000 / 64)
#define SU_BLOCKS 1250        // 10000 / 8
#define HIST_PAD 10240

typedef _Float16 half8 __attribute__((ext_vector_type(8)));
typedef float f32x4 __attribute__((ext_vector_type(4)));

__device__ __forceinline__ float gelu_exact(float x) {
  return 0.5f * x * (1.0f + erff(x * 0.70710678f));
}

// Swizzled LDS tile: [16 rows][128 cols] f16, row stride 256 B.
__device__ __forceinline__ int lds_swz(int row, int colbyte) {
  return ((row * 256 + colbyte) ^ ((row & 7) << 4));
}

struct FoldAll {
  const float* g[4];
  const float* bb[4];
  const float* m[4];
  const float* v[4];
  const float* W[4];
  const float* bias[4];
  _Float16* pk[4];
  float* bf[4];
  int din[4];
  int S[4];  // K/32
};

// K1: grid = 44 + PART_BLOCKS blocks x 256 thr.
// b in [0,40): pack W fragments (f16, B-frag layout, BN-scale folded).
// b in [40,44): folded bias: bf = bias + t @ W.
// b >= 44: single-pass full-LDS histogram of chunk eb (40 KB) -> u8 partial
//   rows in quarter-major layout part[(q*250+eb)*2500 + bp].
__global__ __launch_bounds__(256) void fold_hist_kernel(FoldAll fa,
                                                        const int* __restrict__ node_idx,
                                                        unsigned char* __restrict__ part) {
  __shared__ int lh[N_NODES];
  __shared__ float t_sh[256];
  __shared__ float bpart[128];
  int b = blockIdx.x, t = threadIdx.x;
  if (b >= 44) {
    int eb = b - 44;
    for (int i = t; i < N_NODES; i += 256) lh[i] = 0;
    __syncthreads();
    int base0 = eb * EDGES_PER_PART;
#pragma unroll
    for (int s = 0; s < 3; ++s) {
      int off = s * 1024 + t * 4;
      if (off < EDGES_PER_PART) {
        int4 vv = *reinterpret_cast<const int4*>(&node_idx[base0 + off]);
        atomicAdd(&lh[vv.x], 1);
        atomicAdd(&lh[vv.y], 1);
        atomicAdd(&lh[vv.z], 1);
        atomicAdd(&lh[vv.w], 1);
      }
    }
    __syncthreads();
    for (int i = t; i < N_NODES; i += 256) {
      int q = i / QUARTER;
      int bp = i - q * QUARTER;
      part[(size_t)(q * PART_BLOCKS + eb) * QUARTER + bp] = (unsigned char)lh[i];
    }
    return;
  }
  if (b >= 40) {
    int p = b - 40;
    int din = fa.din[p];
    const float* W = fa.W[p];
    for (int k = t; k < din; k += 256) {
      float sc = fa.g[p][k] * rsqrtf(fa.v[p][k] + BN_EPS);
      t_sh[k] = fa.bb[p][k] - fa.m[p][k] * sc;
    }
    __syncthreads();
    int j = t & 127, kh = t >> 7;
    int half = din >> 1;
    float acc = 0.f;
    for (int k = kh * half; k < (kh + 1) * half; ++k)
      acc = fmaf(t_sh[k], W[k * 128 + j], acc);
    if (kh == 1) bpart[j] = acc;
    __syncthreads();
    if (kh == 0) fa.bf[p][j] = acc + bpart[j] + fa.bias[p][j];
    return;
  }
  int p, lf;
  if (b < 8)       { p = 0; lf = b * 256 + t; }
  else if (b < 16) { p = 1; lf = (b - 8) * 256 + t; }
  else if (b < 32) { p = 2; lf = (b - 16) * 256 + t; }
  else             { p = 3; lf = (b - 32) * 256 + t; }
  int S = fa.S[p];
  int l = lf & 63;
  int fs = lf >> 6;
  int f = fs & 7, s = fs >> 3;
  if (s >= S) return;
  const float* W = fa.W[p];
  const float* g = fa.g[p];
  const float* v = fa.v[p];
  int k0 = s * 32 + (l >> 4) * 8;
  int col = f * 16 + (l & 15);
  half8 h;
#pragma unroll
  for (int i = 0; i < 8; ++i) {
    int k = k0 + i;
    float sc = g[k] * rsqrtf(v[k] + BN_EPS);
    h[i] = (_Float16)(sc * W[k * 128 + col]);
  }
  *reinterpret_cast<half8*>(fa.pk[p] + (size_t)lf * 8) = h;
}

// K2: grid = 40 + MSG64_BLOCKS blocks x 256 thr.
// b in [0,40): merge — per bin, prefix over 250 u8 partials (chunked), total
//   -> hist[bin]; partials become per-block exclusive offsets in place.
//   Bins [10000,10240) get hist=0 (pad for unguarded int4 scans downstream).
// b >= 40: per-node message via f16 MFMA, 4 waves x 16 rows.
__global__ __launch_bounds__(256) void merge_msg_kernel(
    unsigned char* __restrict__ part, int* __restrict__ hist,
    const float* __restrict__ x,
    const _Float16* __restrict__ W1pk, const float* __restrict__ b1f,
    const _Float16* __restrict__ W2pk, const float* __restrict__ b2f,
    _Float16* __restrict__ M) {
  __shared__ char lds_raw[4 * 4096];
  int b = blockIdx.x, t = threadIdx.x;
  if (b < 40) {
    int bin = b * 256 + t;
    if (bin < N_NODES) {
      int q = bin / QUARTER;
      int bp = bin - q * QUARTER;
      unsigned char* col = part + (size_t)q * PART_BLOCKS * QUARTER + bp;
      int sum = 0;
#pragma unroll
      for (int c = 0; c < PART_BLOCKS; c += 25) {
        int vals[25];
#pragma unroll
        for (int i = 0; i < 25; ++i) vals[i] = col[(size_t)(c + i) * QUARTER];
#pragma unroll
        for (int i = 0; i < 25; ++i) {
          col[(size_t)(c + i) * QUARTER] = (unsigned char)sum;
          sum += vals[i];
        }
      }
      hist[bin] = sum;
    } else if (bin < HIST_PAD) {
      hist[bin] = 0;
    }
    return;
  }
  int wid = t >> 6, lane = t & 63;
  int r = lane & 15, g = lane >> 4;
  int row0 = (b - 40) * 64 + wid * 16;
  char* lbase = lds_raw + wid * 4096;

  int arow = row0 + r;
  if (arow > N_NODES - 1) arow = N_NODES - 1;
  const float* xp = x + (size_t)arow * DIM;

  half8 a[4];
#pragma unroll
  for (int s = 0; s < 4; ++s) {
    float4 lo = *reinterpret_cast<const float4*>(xp + s * 32 + g * 8);
    float4 hi = *reinterpret_cast<const float4*>(xp + s * 32 + g * 8 + 4);
    half8 h;
    h[0] = (_Float16)lo.x; h[1] = (_Float16)lo.y; h[2] = (_Float16)lo.z; h[3] = (_Float16)lo.w;
    h[4] = (_Float16)hi.x; h[5] = (_Float16)hi.y; h[6] = (_Float16)hi.z; h[7] = (_Float16)hi.w;
    a[s] = h;
  }

  f32x4 zero = {0.f, 0.f, 0.f, 0.f};
  f32x4 acc[8];
#pragma unroll
  for (int f = 0; f < 8; ++f) acc[f] = zero;
#pragma unroll
  for (int f = 0; f < 8; ++f)
#pragma unroll
    for (int s = 0; s < 4; ++s) {
      half8 bfrag = *reinterpret_cast<const half8*>(W1pk + (size_t)((s * 8 + f) * 64 + lane) * 8);
      acc[f] = __builtin_amdgcn_mfma_f32_16x16x32_f16(a[s], bfrag, acc[f], 0, 0, 0);
    }

#pragma unroll
  for (int f = 0; f < 8; ++f) {
    int col = f * 16 + r;
    float bv = b1f[col];
#pragma unroll
    for (int j = 0; j < 4; ++j) {
      int rl = g * 4 + j;
      float gv = gelu_exact(acc[f][j] + bv);
      *reinterpret_cast<_Float16*>(lbase + lds_swz(rl, col * 2)) = (_Float16)gv;
    }
  }

  half8 a2[4];
#pragma unroll
  for (int s = 0; s < 4; ++s)
    a2[s] = *reinterpret_cast<const half8*>(lbase + lds_swz(r, (s * 32 + g * 8) * 2));

  f32x4 acc2[8];
#pragma unroll
  for (int f = 0; f < 8; ++f) acc2[f] = zero;
#pragma unroll
  for (int f = 0; f < 8; ++f)
#pragma unroll
    for (int s = 0; s < 4; ++s) {
      half8 bfrag = *reinterpret_cast<const half8*>(W2pk + (size_t)((s * 8 + f) * 64 + lane) * 8);
      acc2[f] = __builtin_amdgcn_mfma_f32_16x16x32_f16(a2[s], bfrag, acc2[f], 0, 0, 0);
    }

#pragma unroll
  for (int f = 0; f < 8; ++f) {
    int col = f * 16 + r;
    float bv = b2f[col];
#pragma unroll
    for (int j = 0; j < 4; ++j) {
      int grow = row0 + g * 4 + j;
      if (grow < N_NODES)
        M[(size_t)grow * DIM + col] = (_Float16)gelu_exact(acc2[f][j] + bv);
    }
  }
}

// K3: quarter-partitioned scatter, grid = 1000 blocks x 256 thr.
// Block (eb, q): chunked int4 scan of padded hist -> global prefix; keeps
// LDS cursor only for its quarter (10 KB); block 0 writes row_start; then
// scatters chunk eb's edges with dst in quarter q via LDS atomics.
__global__ __launch_bounds__(256) void scatter_kernel(
    const int* __restrict__ node_idx, const int* __restrict__ nbr_idx,
    const float* __restrict__ ew, const int* __restrict__ hist,
    const unsigned char* __restrict__ part, uint2* __restrict__ edge_s,
    int* __restrict__ row_start) {
  __shared__ int cur[QUARTER];
  __shared__ int sums[256];
  int bk = blockIdx.x, t = threadIdx.x;
  int eb = bk >> 2;
  int q = bk & 3;
  int qbase = q * QUARTER;
  const int PER = 40;
  int i0 = t * PER;
  int lh[PER];
  int total = 0;
#pragma unroll
  for (int i = 0; i < PER; i += 4) {
    int4 h4 = *reinterpret_cast<const int4*>(&hist[i0 + i]);
    lh[i] = h4.x; lh[i + 1] = h4.y; lh[i + 2] = h4.z; lh[i + 3] = h4.w;
    total += h4.x + h4.y + h4.z + h4.w;
  }
  sums[t] = total;
  __syncthreads();
  for (int off = 1; off < 256; off <<= 1) {
    int v = (t >= off) ? sums[t - off] : 0;
    __syncthreads();
    sums[t] += v;
    __syncthreads();
  }
  int running = sums[t] - total;  // global exclusive prefix of this chunk
  const unsigned char* prow = part + (size_t)(q * PART_BLOCKS + eb) * QUARTER;
  bool wrs = (bk == 0);
#pragma unroll
  for (int i = 0; i < PER; ++i) {
    int idx = i0 + i;
    if (idx < N_NODES) {
      unsigned d = (unsigned)(idx - qbase);
      if (d < QUARTER) cur[d] = running + (int)prow[d];
      if (wrs) row_start[idx] = running;
      running += lh[i];
    }
  }
  if (wrs && t == 255) row_start[N_NODES] = running;
  __syncthreads();

  int base0 = eb * EDGES_PER_PART;
#pragma unroll
  for (int s = 0; s < 3; ++s) {
    int off = s * 1024 + t * 4;
    if (off >= EDGES_PER_PART) break;
    int base = base0 + off;
    int4 ni = *reinterpret_cast<const int4*>(&node_idx[base]);
    int4 nb = *reinterpret_cast<const int4*>(&nbr_idx[base]);
    float4 wv = *reinterpret_cast<const float4*>(&ew[base]);
    unsigned d0 = (unsigned)(ni.x - qbase);
    unsigned d1 = (unsigned)(ni.y - qbase);
    unsigned d2 = (unsigned)(ni.z - qbase);
    unsigned d3 = (unsigned)(ni.w - qbase);
    if (d0 < QUARTER) {
      int p0 = atomicAdd(&cur[d0], 1);
      edge_s[p0] = make_uint2((unsigned)nb.x, __float_as_uint(wv.x));
    }
    if (d1 < QUARTER) {
      int p1 = atomicAdd(&cur[d1], 1);
      edge_s[p1] = make_uint2((unsigned)nb.y, __float_as_uint(wv.y));
    }
    if (d2 < QUARTER) {
      int p2 = atomicAdd(&cur[d2], 1);
      edge_s[p2] = make_uint2((unsigned)nb.z, __float_as_uint(wv.z));
    }
    if (d3 < QUARTER) {
      int p3 = atomicAdd(&cur[d3], 1);
      edge_s[p3] = make_uint2((unsigned)nb.w, __float_as_uint(wv.w));
    }
  }
}

// K4: fused spmm + update. grid = 1250 blocks x 256 thr, 8 rows/block.
// Phase 1: 32 thr/row = 4 edge-slices x 8 col-subs, 32 B gathers (16 cols),
//   4-edge batches; slice partials reduced via f32 LDS scratch (12 KB); agg
//   written f16 into swizzled tile rows 0..7.
// Phase 2 (4 waves): MFMA on a 16-row tile with rows 8-15 zero-padded;
//   U1/U2 output fragments split 2-per-wave.
__global__ __launch_bounds__(256) void spmm_update_kernel(
    const int* __restrict__ row_start, const uint2* __restrict__ edge_s,
    const __half* __restrict__ M, const float* __restrict__ x,
    const _Float16* __restrict__ U1pk, const float* __restrict__ bu1,
    const _Float16* __restrict__ U2pk, const float* __restrict__ bu2,
    float* __restrict__ out) {
  __shared__ float scratch[3][8][128];
  __shared__ char tile[4096];
  int t = threadIdx.x;
  int row0 = blockIdx.x * 8;

  {
    int r = t >> 5;       // 0..7 local row
    int q = t & 31;
    int slice = q >> 3;   // 0..3
    int sub = q & 7;      // cols sub*16 .. sub*16+15
    int row = row0 + r;
    int s = row_start[row];
    int e_end = row_start[row + 1];
    float acc[16];
#pragma unroll
    for (int c = 0; c < 16; ++c) acc[c] = 0.f;
    const __half* Mb = M + sub * 16;
    for (int base = s + slice * 4; base < e_end; base += 16) {
      uint2 pk[4];
#pragma unroll
      for (int k = 0; k < 4; ++k) {
        int e = base + k;
        pk[k] = edge_s[(e < e_end) ? e : s];
        if (e >= e_end) pk[k].y = 0u;
      }
      uint4 raw[8];
#pragma unroll
      for (int k = 0; k < 4; ++k) {
        const uint4* mp = reinterpret_cast<const uint4*>(Mb + (size_t)pk[k].x * DIM);
        raw[2 * k] = mp[0];
        raw[2 * k + 1] = mp[1];
      }
#pragma unroll
      for (int k = 0; k < 4; ++k) {
        float w = __uint_as_float(pk[k].y);
        const __half2* h2 = reinterpret_cast<const __half2*>(&raw[2 * k]);
#pragma unroll
        for (int qq = 0; qq < 8; ++qq) {
          float2 f = __half22float2(h2[qq]);
          acc[2 * qq] = fmaf(w, f.x, acc[2 * qq]);
          acc[2 * qq + 1] = fmaf(w, f.y, acc[2 * qq + 1]);
        }
      }
    }
    if (slice >= 1) {
      float* dst = &scratch[slice - 1][r][sub * 16];
      *reinterpret_cast<float4*>(dst) = make_float4(acc[0], acc[1], acc[2], acc[3]);
      *reinterpret_cast<float4*>(dst + 4) = make_float4(acc[4], acc[5], acc[6], acc[7]);
      *reinterpret_cast<float4*>(dst + 8) = make_float4(acc[8], acc[9], acc[10], acc[11]);
      *reinterpret_cast<float4*>(dst + 12) = make_float4(acc[12], acc[13], acc[14], acc[15]);
    }
    __syncthreads();
    if (slice == 0) {
#pragma unroll
      for (int sl = 0; sl < 3; ++sl) {
        const float* src = &scratch[sl][r][sub * 16];
#pragma unroll
        for (int c = 0; c < 16; c += 4) {
          float4 o = *reinterpret_cast<const float4*>(src + c);
          acc[c] += o.x; acc[c + 1] += o.y; acc[c + 2] += o.z; acc[c + 3] += o.w;
        }
      }
      int cnt = e_end - s;
      float inv = 1.f / (float)(cnt > 0 ? cnt : 1);
      half8 hlo, hhi;
#pragma unroll
      for (int c = 0; c < 8; ++c) hlo[c] = (_Float16)(acc[c] * inv);
#pragma unroll
      for (int c = 0; c < 8; ++c) hhi[c] = (_Float16)(acc[8 + c] * inv);
      *reinterpret_cast<half8*>(tile + lds_swz(r, sub * 32)) = hlo;
      *reinterpret_cast<half8*>(tile + lds_swz(r, sub * 32 + 16)) = hhi;
    }
  }
  __syncthreads();

  int wid = t >> 6, lane = t & 63;
  int r = lane & 15, g = lane >> 4;
  half8 hzero;
#pragma unroll
  for (int i = 0; i < 8; ++i) hzero[i] = (_Float16)0.f;

  half8 a[8];
#pragma unroll
  for (int s = 0; s < 8; ++s) a[s] = hzero;
  if (r < 8) {
    const float* xp = x + (size_t)(row0 + r) * DIM;
#pragma unroll
    for (int s = 0; s < 4; ++s) {
      float4 lo = *reinterpret_cast<const float4*>(xp + s * 32 + g * 8);
      float4 hi = *reinterpret_cast<const float4*>(xp + s * 32 + g * 8 + 4);
      half8 h;
      h[0] = (_Float16)lo.x; h[1] = (_Float16)lo.y; h[2] = (_Float16)lo.z; h[3] = (_Float16)lo.w;
      h[4] = (_Float16)hi.x; h[5] = (_Float16)hi.y; h[6] = (_Float16)hi.z; h[7] = (_Float16)hi.w;
      a[s] = h;
    }
#pragma unroll
    for (int s = 0; s < 4; ++s)
      a[4 + s] = *reinterpret_cast<const half8*>(tile + lds_swz(r, (s * 32 + g * 8) * 2));
  }
  __syncthreads();  // agg-tile reads done before layer-1 overwrites tile

  f32x4 zero = {0.f, 0.f, 0.f, 0.f};
  {
    f32x4 acc1[2];
    acc1[0] = zero; acc1[1] = zero;
#pragma unroll
    for (int fi = 0; fi < 2; ++fi) {
      int f = wid * 2 + fi;
#pragma unroll
      for (int s = 0; s < 8; ++s) {
        half8 bfrag = *reinterpret_cast<const half8*>(U1pk + (size_t)((s * 8 + f) * 64 + lane) * 8);
        acc1[fi] = __builtin_amdgcn_mfma_f32_16x16x32_f16(a[s], bfrag, acc1[fi], 0, 0, 0);
      }
    }
#pragma unroll
    for (int fi = 0; fi < 2; ++fi) {
      int f = wid * 2 + fi;
      int col = f * 16 + r;
      float bv = bu1[col];
#pragma unroll
      for (int j = 0; j < 4; ++j) {
        int rl = g * 4 + j;
        float gv = gelu_exact(acc1[fi][j] + bv);
        *reinterpret_cast<_Float16*>(tile + lds_swz(rl, col * 2)) = (_Float16)gv;
      }
    }
  }
  __syncthreads();  // layer-1 tile complete before layer-2 reads

  {
    half8 a2[4];
#pragma unroll
    for (int s = 0; s < 4; ++s) a2[s] = hzero;
    if (r < 8) {
#pragma unroll
      for (int s = 0; s < 4; ++s)
        a2[s] = *reinterpret_cast<const half8*>(tile + lds_swz(r, (s * 32 + g * 8) * 2));
    }
    f32x4 acc2[2];
    acc2[0] = zero; acc2[1] = zero;
#pragma unroll
    for (int fi = 0; fi < 2; ++fi) {
      int f = wid * 2 + fi;
#pragma unroll
      for (int s = 0; s < 4; ++s) {
        half8 bfrag = *reinterpret_cast<const half8*>(U2pk + (size_t)((s * 8 + f) * 64 + lane) * 8);
        acc2[fi] = __builtin_amdgcn_mfma_f32_16x16x32_f16(a2[s], bfrag, acc2[fi], 0, 0, 0);
      }
    }
#pragma unroll
    for (int fi = 0; fi < 2; ++fi) {
      int f = wid * 2 + fi;
      int col = f * 16 + r;
      float bv = bu2[col];
#pragma unroll
      for (int j = 0; j < 4; ++j) {
        int rloc = g * 4 + j;
        if (rloc < 8)
          out[(size_t)(row0 + rloc) * DIM + col] = gelu_exact(acc2[fi][j] + bv);
      }
    }
  }
}

extern "C" void kernel_launch(void* const* d_in, const int* in_sizes, int n_in,
                              void* d_out, int out_size, void* d_ws, size_t ws_size,
                              hipStream_t stream) {
  const float* x = (const float*)d_in[0];
  const int* edges = (const int*)d_in[1];
  const float* ew = (const float*)d_in[2];

  const int* node_idx = edges;            // edges[0, :]
  const int* nbr_idx = edges + N_EDGES;   // edges[1, :]

  char* wsp = (char*)d_ws;
  auto alloc = [&](size_t bytes) {
    char* p = wsp;
    wsp += (bytes + 255) & ~(size_t)255;
    return p;
  };
  _Float16* M = (_Float16*)alloc((size_t)N_NODES * DIM * 2);
  _Float16* W1pk = (_Float16*)alloc(128 * 128 * 2);
  _Float16* W2pk = (_Float16*)alloc(128 * 128 * 2);
  _Float16* U1pk = (_Float16*)alloc(256 * 128 * 2);
  _Float16* U2pk = (_Float16*)alloc(128 * 128 * 2);
  float* b1f = (float*)alloc(128 * 4);
  float* b2f = (float*)alloc(128 * 4);
  float* bu1 = (float*)alloc(128 * 4);
  float* bu2 = (float*)alloc(128 * 4);
  int* hist = (int*)alloc(HIST_PAD * 4);
  int* row_start = (int*)alloc((N_NODES + 1) * 4);
  unsigned char* part = (unsigned char*)alloc((size_t)PART_BLOCKS * N_NODES);
  uint2* edge_s = (uint2*)alloc((size_t)N_EDGES * 8);

  FoldAll fa;
  fa.g[0] = (const float*)d_in[3];  fa.bb[0] = (const float*)d_in[4];
  fa.m[0] = (const float*)d_in[5];  fa.v[0] = (const float*)d_in[6];
  fa.W[0] = (const float*)d_in[7];  fa.bias[0] = (const float*)d_in[8];
  fa.g[1] = (const float*)d_in[9];  fa.bb[1] = (const float*)d_in[10];
  fa.m[1] = (const float*)d_in[11]; fa.v[1] = (const float*)d_in[12];
  fa.W[1] = (const float*)d_in[13]; fa.bias[1] = (const float*)d_in[14];
  fa.g[2] = (const float*)d_in[15]; fa.bb[2] = (const float*)d_in[16];
  fa.m[2] = (const float*)d_in[17]; fa.v[2] = (const float*)d_in[18];
  fa.W[2] = (const float*)d_in[19]; fa.bias[2] = (const float*)d_in[20];
  fa.g[3] = (const float*)d_in[21]; fa.bb[3] = (const float*)d_in[22];
  fa.m[3] = (const float*)d_in[23]; fa.v[3] = (const float*)d_in[24];
  fa.W[3] = (const float*)d_in[25]; fa.bias[3] = (const float*)d_in[26];
  fa.pk[0] = W1pk; fa.pk[1] = W2pk; fa.pk[2] = U1pk; fa.pk[3] = U2pk;
  fa.bf[0] = b1f; fa.bf[1] = b2f; fa.bf[2] = bu1; fa.bf[3] = bu2;
  fa.din[0] = 128; fa.din[1] = 128; fa.din[2] = 256; fa.din[3] = 128;
  fa.S[0] = 4; fa.S[1] = 4; fa.S[2] = 8; fa.S[3] = 4;

  fold_hist_kernel<<<44 + PART_BLOCKS, 256, 0, stream>>>(fa, node_idx, part);
  merge_msg_kernel<<<40 + MSG64_BLOCKS, 256, 0, stream>>>(
      part, hist, x, W1pk, b1f, W2pk, b2f, M);
  scatter_kernel<<<SCAT_GRID, 256, 0, stream>>>(
      node_idx, nbr_idx, ew, hist, part, edge_s, row_start);
  spmm_update_kernel<<<SU_BLOCKS, 256, 0, stream>>>(
      row_start, edge_s, (const __half*)M, x, U1pk, bu1, U2pk, bu2, (float*)d_out);
}

// Round 14
// 105.253 us; speedup vs baseline: 1.8724x; 1.0268x over previous
//
#include <hip/hip_runtime.h>
#include <hip/hip_bf16.h>
#include <hip/hip_fp16.h>
#include <math.h>

#define N_NODES 10000
#define DIM 128
#define N_EDGES 640000
#define BN_EPS 1e-3f

#define QUARTER 2500
#define QPAD 3072             // padded quarter stride (multiple of 256*12/…)
#define PART_BLOCKS 250       // edge chunks: 640000 / 2560
#define EDGES_PER_PART 2560
#define SCAT_GRID 1000        // 250 chunks x 4 quarters
#define MSG64_BLOCKS 157      // ceil(10000 / 64)
#define SU_BLOCKS 1250        // 10000 / 8

typedef _Float16 half8 __attribute__((ext_vector_type(8)));
typedef float f32x4 __attribute__((ext_vector_type(4)));

__device__ __forceinline__ float gelu_exact(float x) {
  return 0.5f * x * (1.0f + erff(x * 0.70710678f));
}

// Swizzled LDS tile: [16 rows][128 cols] f16, row stride 256 B.
__device__ __forceinline__ int lds_swz(int row, int colbyte) {
  return ((row * 256 + colbyte) ^ ((row & 7) << 4));
}

struct FoldAll {
  const float* g[4];
  const float* bb[4];
  const float* m[4];
  const float* v[4];
  const float* W[4];
  const float* bias[4];
  _Float16* pk[4];
  float* bf[4];
  int din[4];
  int S[4];  // K/32
};

// K1: grid = 44 + PART_BLOCKS blocks x 256 thr.
// b in [0,40): pack W fragments (f16, B-frag layout, BN-scale folded).
// b in [40,44): folded bias; block 40+p also zeroes qtot (p==0) and the
//   padded tail of histq quarter p.
// b >= 44: single-pass full-LDS histogram of chunk eb (40 KB) -> u8 partial
//   rows in quarter-major layout part[(q*250+eb)*2500 + bp].
__global__ __launch_bounds__(256) void fold_hist_kernel(FoldAll fa,
                                                        const int* __restrict__ node_idx,
                                                        unsigned char* __restrict__ part,
                                                        int* __restrict__ histq,
                                                        int* __restrict__ qtot) {
  __shared__ int lh[N_NODES];
  __shared__ float t_sh[256];
  __shared__ float bpart[128];
  int b = blockIdx.x, t = threadIdx.x;
  if (b >= 44) {
    int eb = b - 44;
    for (int i = t; i < N_NODES; i += 256) lh[i] = 0;
    __syncthreads();
    int base0 = eb * EDGES_PER_PART;
#pragma unroll
    for (int s = 0; s < 3; ++s) {
      int off = s * 1024 + t * 4;
      if (off < EDGES_PER_PART) {
        int4 vv = *reinterpret_cast<const int4*>(&node_idx[base0 + off]);
        atomicAdd(&lh[vv.x], 1);
        atomicAdd(&lh[vv.y], 1);
        atomicAdd(&lh[vv.z], 1);
        atomicAdd(&lh[vv.w], 1);
      }
    }
    __syncthreads();
    for (int i = t; i < N_NODES; i += 256) {
      int q = i / QUARTER;
      int bp = i - q * QUARTER;
      part[(size_t)(q * PART_BLOCKS + eb) * QUARTER + bp] = (unsigned char)lh[i];
    }
    return;
  }
  if (b >= 40) {
    int p = b - 40;
    if (p == 0 && t < 4) qtot[t] = 0;
    for (int i = t; i < QPAD - QUARTER; i += 256) histq[p * QPAD + QUARTER + i] = 0;
    int din = fa.din[p];
    const float* W = fa.W[p];
    for (int k = t; k < din; k += 256) {
      float sc = fa.g[p][k] * rsqrtf(fa.v[p][k] + BN_EPS);
      t_sh[k] = fa.bb[p][k] - fa.m[p][k] * sc;
    }
    __syncthreads();
    int j = t & 127, kh = t >> 7;
    int half = din >> 1;
    float acc = 0.f;
    for (int k = kh * half; k < (kh + 1) * half; ++k)
      acc = fmaf(t_sh[k], W[k * 128 + j], acc);
    if (kh == 1) bpart[j] = acc;
    __syncthreads();
    if (kh == 0) fa.bf[p][j] = acc + bpart[j] + fa.bias[p][j];
    return;
  }
  int p, lf;
  if (b < 8)       { p = 0; lf = b * 256 + t; }
  else if (b < 16) { p = 1; lf = (b - 8) * 256 + t; }
  else if (b < 32) { p = 2; lf = (b - 16) * 256 + t; }
  else             { p = 3; lf = (b - 32) * 256 + t; }
  int S = fa.S[p];
  int l = lf & 63;
  int fs = lf >> 6;
  int f = fs & 7, s = fs >> 3;
  if (s >= S) return;
  const float* W = fa.W[p];
  const float* g = fa.g[p];
  const float* v = fa.v[p];
  int k0 = s * 32 + (l >> 4) * 8;
  int col = f * 16 + (l & 15);
  half8 h;
#pragma unroll
  for (int i = 0; i < 8; ++i) {
    int k = k0 + i;
    float sc = g[k] * rsqrtf(v[k] + BN_EPS);
    h[i] = (_Float16)(sc * W[k * 128 + col]);
  }
  *reinterpret_cast<half8*>(fa.pk[p] + (size_t)lf * 8) = h;
}

// K2: grid = 40 + MSG64_BLOCKS blocks x 256 thr.
// b in [0,40): merge — per bin, prefix over 250 u8 partials; total ->
//   histq[q*QPAD + bp]; per-quarter totals accumulated into qtot via one
//   LDS reduction + <=4 global atomics per block.
// b >= 40: per-node message via f16 MFMA, 4 waves x 16 rows.
__global__ __launch_bounds__(256) void merge_msg_kernel(
    unsigned char* __restrict__ part, int* __restrict__ histq,
    int* __restrict__ qtot,
    const float* __restrict__ x,
    const _Float16* __restrict__ W1pk, const float* __restrict__ b1f,
    const _Float16* __restrict__ W2pk, const float* __restrict__ b2f,
    _Float16* __restrict__ M) {
  __shared__ char lds_raw[4 * 4096];
  __shared__ int qsum[4];
  int b = blockIdx.x, t = threadIdx.x;
  if (b < 40) {
    int bin = b * 256 + t;
    int sum = 0;
    int q = 0;
    if (bin < N_NODES) {
      q = bin / QUARTER;
      int bp = bin - q * QUARTER;
      unsigned char* col = part + (size_t)q * PART_BLOCKS * QUARTER + bp;
#pragma unroll
      for (int c = 0; c < PART_BLOCKS; c += 25) {
        int vals[25];
#pragma unroll
        for (int i = 0; i < 25; ++i) vals[i] = col[(size_t)(c + i) * QUARTER];
#pragma unroll
        for (int i = 0; i < 25; ++i) {
          col[(size_t)(c + i) * QUARTER] = (unsigned char)sum;
          sum += vals[i];
        }
      }
      histq[q * QPAD + bp] = sum;
    }
    if (t < 4) qsum[t] = 0;
    __syncthreads();
    if (bin < N_NODES) atomicAdd(&qsum[q], sum);
    __syncthreads();
    if (t < 4) atomicAdd(&qtot[t], qsum[t]);
    return;
  }
  int wid = t >> 6, lane = t & 63;
  int r = lane & 15, g = lane >> 4;
  int row0 = (b - 40) * 64 + wid * 16;
  char* lbase = lds_raw + wid * 4096;

  int arow = row0 + r;
  if (arow > N_NODES - 1) arow = N_NODES - 1;
  const float* xp = x + (size_t)arow * DIM;

  half8 a[4];
#pragma unroll
  for (int s = 0; s < 4; ++s) {
    float4 lo = *reinterpret_cast<const float4*>(xp + s * 32 + g * 8);
    float4 hi = *reinterpret_cast<const float4*>(xp + s * 32 + g * 8 + 4);
    half8 h;
    h[0] = (_Float16)lo.x; h[1] = (_Float16)lo.y; h[2] = (_Float16)lo.z; h[3] = (_Float16)lo.w;
    h[4] = (_Float16)hi.x; h[5] = (_Float16)hi.y; h[6] = (_Float16)hi.z; h[7] = (_Float16)hi.w;
    a[s] = h;
  }

  f32x4 zero = {0.f, 0.f, 0.f, 0.f};
  f32x4 acc[8];
#pragma unroll
  for (int f = 0; f < 8; ++f) acc[f] = zero;
#pragma unroll
  for (int f = 0; f < 8; ++f)
#pragma unroll
    for (int s = 0; s < 4; ++s) {
      half8 bfrag = *reinterpret_cast<const half8*>(W1pk + (size_t)((s * 8 + f) * 64 + lane) * 8);
      acc[f] = __builtin_amdgcn_mfma_f32_16x16x32_f16(a[s], bfrag, acc[f], 0, 0, 0);
    }

#pragma unroll
  for (int f = 0; f < 8; ++f) {
    int col = f * 16 + r;
    float bv = b1f[col];
#pragma unroll
    for (int j = 0; j < 4; ++j) {
      int rl = g * 4 + j;
      float gv = gelu_exact(acc[f][j] + bv);
      *reinterpret_cast<_Float16*>(lbase + lds_swz(rl, col * 2)) = (_Float16)gv;
    }
  }

  half8 a2[4];
#pragma unroll
  for (int s = 0; s < 4; ++s)
    a2[s] = *reinterpret_cast<const half8*>(lbase + lds_swz(r, (s * 32 + g * 8) * 2));

  f32x4 acc2[8];
#pragma unroll
  for (int f = 0; f < 8; ++f) acc2[f] = zero;
#pragma unroll
  for (int f = 0; f < 8; ++f)
#pragma unroll
    for (int s = 0; s < 4; ++s) {
      half8 bfrag = *reinterpret_cast<const half8*>(W2pk + (size_t)((s * 8 + f) * 64 + lane) * 8);
      acc2[f] = __builtin_amdgcn_mfma_f32_16x16x32_f16(a2[s], bfrag, acc2[f], 0, 0, 0);
    }

#pragma unroll
  for (int f = 0; f < 8; ++f) {
    int col = f * 16 + r;
    float bv = b2f[col];
#pragma unroll
    for (int j = 0; j < 4; ++j) {
      int grow = row0 + g * 4 + j;
      if (grow < N_NODES)
        M[(size_t)grow * DIM + col] = (_Float16)gelu_exact(acc2[f][j] + bv);
    }
  }
}

// K3: quarter-partitioned scatter, grid = 1000 blocks x 256 thr.
// Block (eb, q): scans ONLY its quarter (3072 padded bins, 3 int4/thread),
// offsets by qpre from qtot; eb==0 blocks write row_start for their quarter;
// then scatters chunk eb's edges with dst in quarter q via LDS atomics.
__global__ __launch_bounds__(256) void scatter_kernel(
    const int* __restrict__ node_idx, const int* __restrict__ nbr_idx,
    const float* __restrict__ ew, const int* __restrict__ histq,
    const int* __restrict__ qtot,
    const unsigned char* __restrict__ part, uint2* __restrict__ edge_s,
    int* __restrict__ row_start) {
  __shared__ int cur[QUARTER];
  __shared__ int sums[256];
  int bk = blockIdx.x, t = threadIdx.x;
  int eb = bk >> 2;
  int q = bk & 3;
  int qbase = q * QUARTER;
  const int PER = 12;  // 256 * 12 = 3072 = QPAD
  int i0 = t * PER;
  const int* hq = histq + q * QPAD;
  int lh[PER];
  int total = 0;
#pragma unroll
  for (int i = 0; i < PER; i += 4) {
    int4 h4 = *reinterpret_cast<const int4*>(&hq[i0 + i]);
    lh[i] = h4.x; lh[i + 1] = h4.y; lh[i + 2] = h4.z; lh[i + 3] = h4.w;
    total += h4.x + h4.y + h4.z + h4.w;
  }
  sums[t] = total;
  __syncthreads();
  for (int off = 1; off < 256; off <<= 1) {
    int v = (t >= off) ? sums[t - off] : 0;
    __syncthreads();
    sums[t] += v;
    __syncthreads();
  }
  int q0 = qtot[0], q1 = qtot[1], q2 = qtot[2];
  int qpre = (q >= 1 ? q0 : 0) + (q >= 2 ? q1 : 0) + (q >= 3 ? q2 : 0);
  int running = qpre + sums[t] - total;  // global exclusive prefix at bin i0
  const unsigned char* prow = part + (size_t)(q * PART_BLOCKS + eb) * QUARTER;
  bool wrs = (eb == 0);
#pragma unroll
  for (int i = 0; i < PER; ++i) {
    int idx = i0 + i;
    if (idx < QUARTER) {
      cur[idx] = running + (int)prow[idx];
      if (wrs) row_start[qbase + idx] = running;
      running += lh[i];
    }
  }
  if (bk == 0 && t == 0) row_start[N_NODES] = N_EDGES;
  __syncthreads();

  int base0 = eb * EDGES_PER_PART;
#pragma unroll
  for (int s = 0; s < 3; ++s) {
    int off = s * 1024 + t * 4;
    if (off >= EDGES_PER_PART) break;
    int base = base0 + off;
    int4 ni = *reinterpret_cast<const int4*>(&node_idx[base]);
    int4 nb = *reinterpret_cast<const int4*>(&nbr_idx[base]);
    float4 wv = *reinterpret_cast<const float4*>(&ew[base]);
    unsigned d0 = (unsigned)(ni.x - qbase);
    unsigned d1 = (unsigned)(ni.y - qbase);
    unsigned d2 = (unsigned)(ni.z - qbase);
    unsigned d3 = (unsigned)(ni.w - qbase);
    if (d0 < QUARTER) {
      int p0 = atomicAdd(&cur[d0], 1);
      edge_s[p0] = make_uint2((unsigned)nb.x, __float_as_uint(wv.x));
    }
    if (d1 < QUARTER) {
      int p1 = atomicAdd(&cur[d1], 1);
      edge_s[p1] = make_uint2((unsigned)nb.y, __float_as_uint(wv.y));
    }
    if (d2 < QUARTER) {
      int p2 = atomicAdd(&cur[d2], 1);
      edge_s[p2] = make_uint2((unsigned)nb.z, __float_as_uint(wv.z));
    }
    if (d3 < QUARTER) {
      int p3 = atomicAdd(&cur[d3], 1);
      edge_s[p3] = make_uint2((unsigned)nb.w, __float_as_uint(wv.w));
    }
  }
}

// K4: fused spmm + update. grid = 1250 blocks x 256 thr, 8 rows/block.
// Phase 1: 32 thr/row = 4 edge-slices x 8 col-subs, 32 B gathers, 4-edge
//   batches with NEXT-BATCH EDGE PREFETCH (unconditional clamped loads) so
//   the edge-load round trip hides under gather+FMA; slice partials reduced
//   via f32 LDS scratch; agg written f16 into swizzled tile rows 0..7.
// Phase 2 (4 waves): MFMA on a 16-row tile with rows 8-15 zero-padded;
//   U1/U2 output fragments split 2-per-wave.
__global__ __launch_bounds__(256) void spmm_update_kernel(
    const int* __restrict__ row_start, const uint2* __restrict__ edge_s,
    const __half* __restrict__ M, const float* __restrict__ x,
    const _Float16* __restrict__ U1pk, const float* __restrict__ bu1,
    const _Float16* __restrict__ U2pk, const float* __restrict__ bu2,
    float* __restrict__ out) {
  __shared__ float scratch[3][8][128];
  __shared__ char tile[4096];
  int t = threadIdx.x;
  int row0 = blockIdx.x * 8;

  {
    int r = t >> 5;       // 0..7 local row
    int q = t & 31;
    int slice = q >> 3;   // 0..3
    int sub = q & 7;      // cols sub*16 .. sub*16+15
    int row = row0 + r;
    int s = row_start[row];
    int e_end = row_start[row + 1];
    float acc[16];
#pragma unroll
    for (int c = 0; c < 16; ++c) acc[c] = 0.f;
    const __half* Mb = M + sub * 16;
    int base = s + slice * 4;
    uint2 pk[4];
#pragma unroll
    for (int k = 0; k < 4; ++k) {
      int e = base + k;
      pk[k] = edge_s[(e < e_end) ? e : s];
      if (e >= e_end) pk[k].y = 0u;
    }
    for (; base < e_end; base += 16) {
      uint2 pkn[4];
      int nb = base + 16;
#pragma unroll
      for (int k = 0; k < 4; ++k) {
        int e = nb + k;
        pkn[k] = edge_s[(e < e_end) ? e : s];
        if (e >= e_end) pkn[k].y = 0u;
      }
      uint4 raw[8];
#pragma unroll
      for (int k = 0; k < 4; ++k) {
        const uint4* mp = reinterpret_cast<const uint4*>(Mb + (size_t)pk[k].x * DIM);
        raw[2 * k] = mp[0];
        raw[2 * k + 1] = mp[1];
      }
#pragma unroll
      for (int k = 0; k < 4; ++k) {
        float w = __uint_as_float(pk[k].y);
        const __half2* h2 = reinterpret_cast<const __half2*>(&raw[2 * k]);
#pragma unroll
        for (int qq = 0; qq < 8; ++qq) {
          float2 f = __half22float2(h2[qq]);
          acc[2 * qq] = fmaf(w, f.x, acc[2 * qq]);
          acc[2 * qq + 1] = fmaf(w, f.y, acc[2 * qq + 1]);
        }
      }
#pragma unroll
      for (int k = 0; k < 4; ++k) pk[k] = pkn[k];
    }
    if (slice >= 1) {
      float* dst = &scratch[slice - 1][r][sub * 16];
      *reinterpret_cast<float4*>(dst) = make_float4(acc[0], acc[1], acc[2], acc[3]);
      *reinterpret_cast<float4*>(dst + 4) = make_float4(acc[4], acc[5], acc[6], acc[7]);
      *reinterpret_cast<float4*>(dst + 8) = make_float4(acc[8], acc[9], acc[10], acc[11]);
      *reinterpret_cast<float4*>(dst + 12) = make_float4(acc[12], acc[13], acc[14], acc[15]);
    }
    __syncthreads();
    if (slice == 0) {
#pragma unroll
      for (int sl = 0; sl < 3; ++sl) {
        const float* src = &scratch[sl][r][sub * 16];
#pragma unroll
        for (int c = 0; c < 16; c += 4) {
          float4 o = *reinterpret_cast<const float4*>(src + c);
          acc[c] += o.x; acc[c + 1] += o.y; acc[c + 2] += o.z; acc[c + 3] += o.w;
        }
      }
      int cnt = e_end - s;
      float inv = 1.f / (float)(cnt > 0 ? cnt : 1);
      half8 hlo, hhi;
#pragma unroll
      for (int c = 0; c < 8; ++c) hlo[c] = (_Float16)(acc[c] * inv);
#pragma unroll
      for (int c = 0; c < 8; ++c) hhi[c] = (_Float16)(acc[8 + c] * inv);
      *reinterpret_cast<half8*>(tile + lds_swz(r, sub * 32)) = hlo;
      *reinterpret_cast<half8*>(tile + lds_swz(r, sub * 32 + 16)) = hhi;
    }
  }
  __syncthreads();

  int wid = t >> 6, lane = t & 63;
  int r = lane & 15, g = lane >> 4;
  half8 hzero;
#pragma unroll
  for (int i = 0; i < 8; ++i) hzero[i] = (_Float16)0.f;

  half8 a[8];
#pragma unroll
  for (int s = 0; s < 8; ++s) a[s] = hzero;
  if (r < 8) {
    const float* xp = x + (size_t)(row0 + r) * DIM;
#pragma unroll
    for (int s = 0; s < 4; ++s) {
      float4 lo = *reinterpret_cast<const float4*>(xp + s * 32 + g * 8);
      float4 hi = *reinterpret_cast<const float4*>(xp + s * 32 + g * 8 + 4);
      half8 h;
      h[0] = (_Float16)lo.x; h[1] = (_Float16)lo.y; h[2] = (_Float16)lo.z; h[3] = (_Float16)lo.w;
      h[4] = (_Float16)hi.x; h[5] = (_Float16)hi.y; h[6] = (_Float16)hi.z; h[7] = (_Float16)hi.w;
      a[s] = h;
    }
#pragma unroll
    for (int s = 0; s < 4; ++s)
      a[4 + s] = *reinterpret_cast<const half8*>(tile + lds_swz(r, (s * 32 + g * 8) * 2));
  }
  __syncthreads();  // agg-tile reads done before layer-1 overwrites tile

  f32x4 zero = {0.f, 0.f, 0.f, 0.f};
  {
    f32x4 acc1[2];
    acc1[0] = zero; acc1[1] = zero;
#pragma unroll
    for (int fi = 0; fi < 2; ++fi) {
      int f = wid * 2 + fi;
#pragma unroll
      for (int s = 0; s < 8; ++s) {
        half8 bfrag = *reinterpret_cast<const half8*>(U1pk + (size_t)((s * 8 + f) * 64 + lane) * 8);
        acc1[fi] = __builtin_amdgcn_mfma_f32_16x16x32_f16(a[s], bfrag, acc1[fi], 0, 0, 0);
      }
    }
#pragma unroll
    for (int fi = 0; fi < 2; ++fi) {
      int f = wid * 2 + fi;
      int col = f * 16 + r;
      float bv = bu1[col];
#pragma unroll
      for (int j = 0; j < 4; ++j) {
        int rl = g * 4 + j;
        float gv = gelu_exact(acc1[fi][j] + bv);
        *reinterpret_cast<_Float16*>(tile + lds_swz(rl, col * 2)) = (_Float16)gv;
      }
    }
  }
  __syncthreads();  // layer-1 tile complete before layer-2 reads

  {
    half8 a2[4];
#pragma unroll
    for (int s = 0; s < 4; ++s) a2[s] = hzero;
    if (r < 8) {
#pragma unroll
      for (int s = 0; s < 4; ++s)
        a2[s] = *reinterpret_cast<const half8*>(tile + lds_swz(r, (s * 32 + g * 8) * 2));
    }
    f32x4 acc2[2];
    acc2[0] = zero; acc2[1] = zero;
#pragma unroll
    for (int fi = 0; fi < 2; ++fi) {
      int f = wid * 2 + fi;
#pragma unroll
      for (int s = 0; s < 4; ++s) {
        half8 bfrag = *reinterpret_cast<const half8*>(U2pk + (size_t)((s * 8 + f) * 64 + lane) * 8);
        acc2[fi] = __builtin_amdgcn_mfma_f32_16x16x32_f16(a2[s], bfrag, acc2[fi], 0, 0, 0);
      }
    }
#pragma unroll
    for (int fi = 0; fi < 2; ++fi) {
      int f = wid * 2 + fi;
      int col = f * 16 + r;
      float bv = bu2[col];
#pragma unroll
      for (int j = 0; j < 4; ++j) {
        int rloc = g * 4 + j;
        if (rloc < 8)
          out[(size_t)(row0 + rloc) * DIM + col] = gelu_exact(acc2[fi][j] + bv);
      }
    }
  }
}

extern "C" void kernel_launch(void* const* d_in, const int* in_sizes, int n_in,
                              void* d_out, int out_size, void* d_ws, size_t ws_size,
                              hipStream_t stream) {
  const float* x = (const float*)d_in[0];
  const int* edges = (const int*)d_in[1];
  const float* ew = (const float*)d_in[2];

  const int* node_idx = edges;            // edges[0, :]
  const int* nbr_idx = edges + N_EDGES;   // edges[1, :]

  char* wsp = (char*)d_ws;
  auto alloc = [&](size_t bytes) {
    char* p = wsp;
    wsp += (bytes + 255) & ~(size_t)255;
    return p;
  };
  _Float16* M = (_Float16*)alloc((size_t)N_NODES * DIM * 2);
  _Float16* W1pk = (_Float16*)alloc(128 * 128 * 2);
  _Float16* W2pk = (_Float16*)alloc(128 * 128 * 2);
  _Float16* U1pk = (_Float16*)alloc(256 * 128 * 2);
  _Float16* U2pk = (_Float16*)alloc(128 * 128 * 2);
  float* b1f = (float*)alloc(128 * 4);
  float* b2f = (float*)alloc(128 * 4);
  float* bu1 = (float*)alloc(128 * 4);
  float* bu2 = (float*)alloc(128 * 4);
  int* histq = (int*)alloc(4 * QPAD * 4);
  int* qtot = (int*)alloc(4 * 4);
  int* row_start = (int*)alloc((N_NODES + 1) * 4);
  unsigned char* part = (unsigned char*)alloc((size_t)PART_BLOCKS * N_NODES);
  uint2* edge_s = (uint2*)alloc((size_t)N_EDGES * 8);

  FoldAll fa;
  fa.g[0] = (const float*)d_in[3];  fa.bb[0] = (const float*)d_in[4];
  fa.m[0] = (const float*)d_in[5];  fa.v[0] = (const float*)d_in[6];
  fa.W[0] = (const float*)d_in[7];  fa.bias[0] = (const float*)d_in[8];
  fa.g[1] = (const float*)d_in[9];  fa.bb[1] = (const float*)d_in[10];
  fa.m[1] = (const float*)d_in[11]; fa.v[1] = (const float*)d_in[12];
  fa.W[1] = (const float*)d_in[13]; fa.bias[1] = (const float*)d_in[14];
  fa.g[2] = (const float*)d_in[15]; fa.bb[2] = (const float*)d_in[16];
  fa.m[2] = (const float*)d_in[17]; fa.v[2] = (const float*)d_in[18];
  fa.W[2] = (const float*)d_in[19]; fa.bias[2] = (const float*)d_in[20];
  fa.g[3] = (const float*)d_in[21]; fa.bb[3] = (const float*)d_in[22];
  fa.m[3] = (const float*)d_in[23]; fa.v[3] = (const float*)d_in[24];
  fa.W[3] = (const float*)d_in[25]; fa.bias[3] = (const float*)d_in[26];
  fa.pk[0] = W1pk; fa.pk[1] = W2pk; fa.pk[2] = U1pk; fa.pk[3] = U2pk;
  fa.bf[0] = b1f; fa.bf[1] = b2f; fa.bf[2] = bu1; fa.bf[3] = bu2;
  fa.din[0] = 128; fa.din[1] = 128; fa.din[2] = 256; fa.din[3] = 128;
  fa.S[0] = 4; fa.S[1] = 4; fa.S[2] = 8; fa.S[3] = 4;

  fold_hist_kernel<<<44 + PART_BLOCKS, 256, 0, stream>>>(fa, node_idx, part, histq, qtot);
  merge_msg_kernel<<<40 + MSG64_BLOCKS, 256, 0, stream>>>(
      part, histq, qtot, x, W1pk, b1f, W2pk, b2f, M);
  scatter_kernel<<<SCAT_GRID, 256, 0, stream>>>(
      node_idx, nbr_idx, ew, histq, qtot, part, edge_s, row_start);
  spmm_update_kernel<<<SU_BLOCKS, 256, 0, stream>>>(
      row_start, edge_s, (const __half*)M, x, U1pk, bu1, U2pk, bu2, (float*)d_out);
}

// Round 15
// 95.771 us; speedup vs baseline: 2.0578x; 1.0990x over previous
//
#include <hip/hip_runtime.h>
#include <hip/hip_bf16.h>
#include <hip/hip_fp16.h>
#include <math.h>

#define N_NODES 10000
#define DIM 128
#define N_EDGES 640000
#define BN_EPS 1e-3f

#define QUARTER 2500
#define QPAD 3072             // padded quarter stride
#define PART_BLOCKS 250       // edge chunks: 640000 / 2560
#define EDGES_PER_PART 2560
#define SCAT_GRID 1000        // 250 chunks x 4 quarters
#define MSG64_BLOCKS 157      // ceil(10000 / 64)
#define SU_BLOCKS 1250        // 10000 / 8

typedef _Float16 half8 __attribute__((ext_vector_type(8)));
typedef float f32x4 __attribute__((ext_vector_type(4)));

__device__ __forceinline__ float gelu_exact(float x) {
  return 0.5f * x * (1.0f + erff(x * 0.70710678f));
}

// Swizzled LDS tile: [16 rows][128 cols] f16, row stride 256 B.
__device__ __forceinline__ int lds_swz(int row, int colbyte) {
  return ((row * 256 + colbyte) ^ ((row & 7) << 4));
}

// f32 -> fp8 e4m3 (OCP on gfx950), single value via HW pack instruction.
__device__ __forceinline__ unsigned char f32_to_fp8(float v) {
  unsigned pk = __builtin_amdgcn_cvt_pk_fp8_f32(v, v, 0, false);
  return (unsigned char)(pk & 0xffu);
}

struct FoldAll {
  const float* g[4];
  const float* bb[4];
  const float* m[4];
  const float* v[4];
  const float* W[4];
  const float* bias[4];
  _Float16* pk[4];
  float* bf[4];
  int din[4];
  int S[4];  // K/32
};

// K1: grid = 44 + PART_BLOCKS blocks x 256 thr.
// b in [0,40): pack W fragments (f16, B-frag layout, BN-scale folded).
// b in [40,44): folded bias; block 40+p also zeroes qtot (p==0) and the
//   padded tail of histq quarter p.
// b >= 44: single-pass full-LDS histogram of chunk eb (40 KB) -> u8 partial
//   rows in quarter-major layout part[(q*250+eb)*2500 + bp].
__global__ __launch_bounds__(256) void fold_hist_kernel(FoldAll fa,
                                                        const int* __restrict__ node_idx,
                                                        unsigned char* __restrict__ part,
                                                        int* __restrict__ histq,
                                                        int* __restrict__ qtot) {
  __shared__ int lh[N_NODES];
  __shared__ float t_sh[256];
  __shared__ float bpart[128];
  int b = blockIdx.x, t = threadIdx.x;
  if (b >= 44) {
    int eb = b - 44;
    for (int i = t; i < N_NODES; i += 256) lh[i] = 0;
    __syncthreads();
    int base0 = eb * EDGES_PER_PART;
#pragma unroll
    for (int s = 0; s < 3; ++s) {
      int off = s * 1024 + t * 4;
      if (off < EDGES_PER_PART) {
        int4 vv = *reinterpret_cast<const int4*>(&node_idx[base0 + off]);
        atomicAdd(&lh[vv.x], 1);
        atomicAdd(&lh[vv.y], 1);
        atomicAdd(&lh[vv.z], 1);
        atomicAdd(&lh[vv.w], 1);
      }
    }
    __syncthreads();
    for (int i = t; i < N_NODES; i += 256) {
      int q = i / QUARTER;
      int bp = i - q * QUARTER;
      part[(size_t)(q * PART_BLOCKS + eb) * QUARTER + bp] = (unsigned char)lh[i];
    }
    return;
  }
  if (b >= 40) {
    int p = b - 40;
    if (p == 0 && t < 4) qtot[t] = 0;
    for (int i = t; i < QPAD - QUARTER; i += 256) histq[p * QPAD + QUARTER + i] = 0;
    int din = fa.din[p];
    const float* W = fa.W[p];
    for (int k = t; k < din; k += 256) {
      float sc = fa.g[p][k] * rsqrtf(fa.v[p][k] + BN_EPS);
      t_sh[k] = fa.bb[p][k] - fa.m[p][k] * sc;
    }
    __syncthreads();
    int j = t & 127, kh = t >> 7;
    int half = din >> 1;
    float acc = 0.f;
    for (int k = kh * half; k < (kh + 1) * half; ++k)
      acc = fmaf(t_sh[k], W[k * 128 + j], acc);
    if (kh == 1) bpart[j] = acc;
    __syncthreads();
    if (kh == 0) fa.bf[p][j] = acc + bpart[j] + fa.bias[p][j];
    return;
  }
  int p, lf;
  if (b < 8)       { p = 0; lf = b * 256 + t; }
  else if (b < 16) { p = 1; lf = (b - 8) * 256 + t; }
  else if (b < 32) { p = 2; lf = (b - 16) * 256 + t; }
  else             { p = 3; lf = (b - 32) * 256 + t; }
  int S = fa.S[p];
  int l = lf & 63;
  int fs = lf >> 6;
  int f = fs & 7, s = fs >> 3;
  if (s >= S) return;
  const float* W = fa.W[p];
  const float* g = fa.g[p];
  const float* v = fa.v[p];
  int k0 = s * 32 + (l >> 4) * 8;
  int col = f * 16 + (l & 15);
  half8 h;
#pragma unroll
  for (int i = 0; i < 8; ++i) {
    int k = k0 + i;
    float sc = g[k] * rsqrtf(v[k] + BN_EPS);
    h[i] = (_Float16)(sc * W[k * 128 + col]);
  }
  *reinterpret_cast<half8*>(fa.pk[p] + (size_t)lf * 8) = h;
}

// K2: grid = 40 + MSG64_BLOCKS blocks x 256 thr.
// b in [0,40): merge — per bin, prefix over 250 u8 partials; total ->
//   histq[q*QPAD + bp]; per-quarter totals into qtot (LDS reduce + atomics).
// b >= 40: per-node message via f16 MFMA, 4 waves x 16 rows; M stored fp8.
__global__ __launch_bounds__(256) void merge_msg_kernel(
    unsigned char* __restrict__ part, int* __restrict__ histq,
    int* __restrict__ qtot,
    const float* __restrict__ x,
    const _Float16* __restrict__ W1pk, const float* __restrict__ b1f,
    const _Float16* __restrict__ W2pk, const float* __restrict__ b2f,
    unsigned char* __restrict__ M8) {
  __shared__ char lds_raw[4 * 4096];
  __shared__ int qsum[4];
  int b = blockIdx.x, t = threadIdx.x;
  if (b < 40) {
    int bin = b * 256 + t;
    int sum = 0;
    int q = 0;
    if (bin < N_NODES) {
      q = bin / QUARTER;
      int bp = bin - q * QUARTER;
      unsigned char* col = part + (size_t)q * PART_BLOCKS * QUARTER + bp;
#pragma unroll
      for (int c = 0; c < PART_BLOCKS; c += 25) {
        int vals[25];
#pragma unroll
        for (int i = 0; i < 25; ++i) vals[i] = col[(size_t)(c + i) * QUARTER];
#pragma unroll
        for (int i = 0; i < 25; ++i) {
          col[(size_t)(c + i) * QUARTER] = (unsigned char)sum;
          sum += vals[i];
        }
      }
      histq[q * QPAD + bp] = sum;
    }
    if (t < 4) qsum[t] = 0;
    __syncthreads();
    if (bin < N_NODES) atomicAdd(&qsum[q], sum);
    __syncthreads();
    if (t < 4) atomicAdd(&qtot[t], qsum[t]);
    return;
  }
  int wid = t >> 6, lane = t & 63;
  int r = lane & 15, g = lane >> 4;
  int row0 = (b - 40) * 64 + wid * 16;
  char* lbase = lds_raw + wid * 4096;

  int arow = row0 + r;
  if (arow > N_NODES - 1) arow = N_NODES - 1;
  const float* xp = x + (size_t)arow * DIM;

  half8 a[4];
#pragma unroll
  for (int s = 0; s < 4; ++s) {
    float4 lo = *reinterpret_cast<const float4*>(xp + s * 32 + g * 8);
    float4 hi = *reinterpret_cast<const float4*>(xp + s * 32 + g * 8 + 4);
    half8 h;
    h[0] = (_Float16)lo.x; h[1] = (_Float16)lo.y; h[2] = (_Float16)lo.z; h[3] = (_Float16)lo.w;
    h[4] = (_Float16)hi.x; h[5] = (_Float16)hi.y; h[6] = (_Float16)hi.z; h[7] = (_Float16)hi.w;
    a[s] = h;
  }

  f32x4 zero = {0.f, 0.f, 0.f, 0.f};
  f32x4 acc[8];
#pragma unroll
  for (int f = 0; f < 8; ++f) acc[f] = zero;
#pragma unroll
  for (int f = 0; f < 8; ++f)
#pragma unroll
    for (int s = 0; s < 4; ++s) {
      half8 bfrag = *reinterpret_cast<const half8*>(W1pk + (size_t)((s * 8 + f) * 64 + lane) * 8);
      acc[f] = __builtin_amdgcn_mfma_f32_16x16x32_f16(a[s], bfrag, acc[f], 0, 0, 0);
    }

#pragma unroll
  for (int f = 0; f < 8; ++f) {
    int col = f * 16 + r;
    float bv = b1f[col];
#pragma unroll
    for (int j = 0; j < 4; ++j) {
      int rl = g * 4 + j;
      float gv = gelu_exact(acc[f][j] + bv);
      *reinterpret_cast<_Float16*>(lbase + lds_swz(rl, col * 2)) = (_Float16)gv;
    }
  }

  half8 a2[4];
#pragma unroll
  for (int s = 0; s < 4; ++s)
    a2[s] = *reinterpret_cast<const half8*>(lbase + lds_swz(r, (s * 32 + g * 8) * 2));

  f32x4 acc2[8];
#pragma unroll
  for (int f = 0; f < 8; ++f) acc2[f] = zero;
#pragma unroll
  for (int f = 0; f < 8; ++f)
#pragma unroll
    for (int s = 0; s < 4; ++s) {
      half8 bfrag = *reinterpret_cast<const half8*>(W2pk + (size_t)((s * 8 + f) * 64 + lane) * 8);
      acc2[f] = __builtin_amdgcn_mfma_f32_16x16x32_f16(a2[s], bfrag, acc2[f], 0, 0, 0);
    }

#pragma unroll
  for (int f = 0; f < 8; ++f) {
    int col = f * 16 + r;
    float bv = b2f[col];
#pragma unroll
    for (int j = 0; j < 4; ++j) {
      int grow = row0 + g * 4 + j;
      if (grow < N_NODES)
        M8[(size_t)grow * DIM + col] = f32_to_fp8(gelu_exact(acc2[f][j] + bv));
    }
  }
}

// K3: quarter-partitioned scatter, grid = 1000 blocks x 256 thr.
// Block (eb, q): scans ONLY its quarter (3072 padded bins, 3 int4/thread),
// offsets by qpre from qtot; eb==0 blocks write row_start for their quarter;
// then scatters chunk eb's edges with dst in quarter q via LDS atomics.
__global__ __launch_bounds__(256) void scatter_kernel(
    const int* __restrict__ node_idx, const int* __restrict__ nbr_idx,
    const float* __restrict__ ew, const int* __restrict__ histq,
    const int* __restrict__ qtot,
    const unsigned char* __restrict__ part, uint2* __restrict__ edge_s,
    int* __restrict__ row_start) {
  __shared__ int cur[QUARTER];
  __shared__ int sums[256];
  int bk = blockIdx.x, t = threadIdx.x;
  int eb = bk >> 2;
  int q = bk & 3;
  int qbase = q * QUARTER;
  const int PER = 12;  // 256 * 12 = 3072 = QPAD
  int i0 = t * PER;
  const int* hq = histq + q * QPAD;
  int lh[PER];
  int total = 0;
#pragma unroll
  for (int i = 0; i < PER; i += 4) {
    int4 h4 = *reinterpret_cast<const int4*>(&hq[i0 + i]);
    lh[i] = h4.x; lh[i + 1] = h4.y; lh[i + 2] = h4.z; lh[i + 3] = h4.w;
    total += h4.x + h4.y + h4.z + h4.w;
  }
  sums[t] = total;
  __syncthreads();
  for (int off = 1; off < 256; off <<= 1) {
    int v = (t >= off) ? sums[t - off] : 0;
    __syncthreads();
    sums[t] += v;
    __syncthreads();
  }
  int q0 = qtot[0], q1 = qtot[1], q2 = qtot[2];
  int qpre = (q >= 1 ? q0 : 0) + (q >= 2 ? q1 : 0) + (q >= 3 ? q2 : 0);
  int running = qpre + sums[t] - total;  // global exclusive prefix at bin i0
  const unsigned char* prow = part + (size_t)(q * PART_BLOCKS + eb) * QUARTER;
  bool wrs = (eb == 0);
#pragma unroll
  for (int i = 0; i < PER; ++i) {
    int idx = i0 + i;
    if (idx < QUARTER) {
      cur[idx] = running + (int)prow[idx];
      if (wrs) row_start[qbase + idx] = running;
      running += lh[i];
    }
  }
  if (bk == 0 && t == 0) row_start[N_NODES] = N_EDGES;
  __syncthreads();

  int base0 = eb * EDGES_PER_PART;
#pragma unroll
  for (int s = 0; s < 3; ++s) {
    int off = s * 1024 + t * 4;
    if (off >= EDGES_PER_PART) break;
    int base = base0 + off;
    int4 ni = *reinterpret_cast<const int4*>(&node_idx[base]);
    int4 nb = *reinterpret_cast<const int4*>(&nbr_idx[base]);
    float4 wv = *reinterpret_cast<const float4*>(&ew[base]);
    unsigned d0 = (unsigned)(ni.x - qbase);
    unsigned d1 = (unsigned)(ni.y - qbase);
    unsigned d2 = (unsigned)(ni.z - qbase);
    unsigned d3 = (unsigned)(ni.w - qbase);
    if (d0 < QUARTER) {
      int p0 = atomicAdd(&cur[d0], 1);
      edge_s[p0] = make_uint2((unsigned)nb.x, __float_as_uint(wv.x));
    }
    if (d1 < QUARTER) {
      int p1 = atomicAdd(&cur[d1], 1);
      edge_s[p1] = make_uint2((unsigned)nb.y, __float_as_uint(wv.y));
    }
    if (d2 < QUARTER) {
      int p2 = atomicAdd(&cur[d2], 1);
      edge_s[p2] = make_uint2((unsigned)nb.z, __float_as_uint(wv.z));
    }
    if (d3 < QUARTER) {
      int p3 = atomicAdd(&cur[d3], 1);
      edge_s[p3] = make_uint2((unsigned)nb.w, __float_as_uint(wv.w));
    }
  }
}

// K4: fused spmm + update. grid = 1250 blocks x 256 thr, 8 rows/block.
// Phase 1: 32 thr/row = 4 edge-slices x 8 col-subs, 16 B fp8 gathers
//   (16 cols each), 4-edge batches with next-batch edge prefetch; HW
//   cvt_pk_f32_fp8 dequant; slice partials via f32 LDS scratch; agg f16
//   into swizzled tile rows 0..7.
// Phase 2 (4 waves): MFMA on a 16-row tile with rows 8-15 zero-padded;
//   U1/U2 output fragments split 2-per-wave.
__global__ __launch_bounds__(256) void spmm_update_kernel(
    const int* __restrict__ row_start, const uint2* __restrict__ edge_s,
    const unsigned char* __restrict__ M8, const float* __restrict__ x,
    const _Float16* __restrict__ U1pk, const float* __restrict__ bu1,
    const _Float16* __restrict__ U2pk, const float* __restrict__ bu2,
    float* __restrict__ out) {
  __shared__ float scratch[3][8][128];
  __shared__ char tile[4096];
  int t = threadIdx.x;
  int row0 = blockIdx.x * 8;

  {
    int r = t >> 5;       // 0..7 local row
    int q = t & 31;
    int slice = q >> 3;   // 0..3
    int sub = q & 7;      // cols sub*16 .. sub*16+15
    int row = row0 + r;
    int s = row_start[row];
    int e_end = row_start[row + 1];
    float acc[16];
#pragma unroll
    for (int c = 0; c < 16; ++c) acc[c] = 0.f;
    const unsigned char* Mb = M8 + sub * 16;
    int base = s + slice * 4;
    uint2 pk[4];
#pragma unroll
    for (int k = 0; k < 4; ++k) {
      int e = base + k;
      pk[k] = edge_s[(e < e_end) ? e : s];
      if (e >= e_end) pk[k].y = 0u;
    }
    for (; base < e_end; base += 16) {
      uint2 pkn[4];
      int nb = base + 16;
#pragma unroll
      for (int k = 0; k < 4; ++k) {
        int e = nb + k;
        pkn[k] = edge_s[(e < e_end) ? e : s];
        if (e >= e_end) pkn[k].y = 0u;
      }
      uint4 raw[4];
#pragma unroll
      for (int k = 0; k < 4; ++k)
        raw[k] = *reinterpret_cast<const uint4*>(Mb + (size_t)pk[k].x * DIM);
#pragma unroll
      for (int k = 0; k < 4; ++k) {
        float w = __uint_as_float(pk[k].y);
        const unsigned* u32s = reinterpret_cast<const unsigned*>(&raw[k]);
#pragma unroll
        for (int qq = 0; qq < 4; ++qq) {
          auto f01 = __builtin_amdgcn_cvt_pk_f32_fp8(u32s[qq], false);
          auto f23 = __builtin_amdgcn_cvt_pk_f32_fp8(u32s[qq], true);
          acc[4 * qq + 0] = fmaf(w, f01[0], acc[4 * qq + 0]);
          acc[4 * qq + 1] = fmaf(w, f01[1], acc[4 * qq + 1]);
          acc[4 * qq + 2] = fmaf(w, f23[0], acc[4 * qq + 2]);
          acc[4 * qq + 3] = fmaf(w, f23[1], acc[4 * qq + 3]);
        }
      }
#pragma unroll
      for (int k = 0; k < 4; ++k) pk[k] = pkn[k];
    }
    if (slice >= 1) {
      float* dst = &scratch[slice - 1][r][sub * 16];
      *reinterpret_cast<float4*>(dst) = make_float4(acc[0], acc[1], acc[2], acc[3]);
      *reinterpret_cast<float4*>(dst + 4) = make_float4(acc[4], acc[5], acc[6], acc[7]);
      *reinterpret_cast<float4*>(dst + 8) = make_float4(acc[8], acc[9], acc[10], acc[11]);
      *reinterpret_cast<float4*>(dst + 12) = make_float4(acc[12], acc[13], acc[14], acc[15]);
    }
    __syncthreads();
    if (slice == 0) {
#pragma unroll
      for (int sl = 0; sl < 3; ++sl) {
        const float* src = &scratch[sl][r][sub * 16];
#pragma unroll
        for (int c = 0; c < 16; c += 4) {
          float4 o = *reinterpret_cast<const float4*>(src + c);
          acc[c] += o.x; acc[c + 1] += o.y; acc[c + 2] += o.z; acc[c + 3] += o.w;
        }
      }
      int cnt = e_end - s;
      float inv = 1.f / (float)(cnt > 0 ? cnt : 1);
      half8 hlo, hhi;
#pragma unroll
      for (int c = 0; c < 8; ++c) hlo[c] = (_Float16)(acc[c] * inv);
#pragma unroll
      for (int c = 0; c < 8; ++c) hhi[c] = (_Float16)(acc[8 + c] * inv);
      *reinterpret_cast<half8*>(tile + lds_swz(r, sub * 32)) = hlo;
      *reinterpret_cast<half8*>(tile + lds_swz(r, sub * 32 + 16)) = hhi;
    }
  }
  __syncthreads();

  int wid = t >> 6, lane = t & 63;
  int r = lane & 15, g = lane >> 4;
  half8 hzero;
#pragma unroll
  for (int i = 0; i < 8; ++i) hzero[i] = (_Float16)0.f;

  half8 a[8];
#pragma unroll
  for (int s = 0; s < 8; ++s) a[s] = hzero;
  if (r < 8) {
    const float* xp = x + (size_t)(row0 + r) * DIM;
#pragma unroll
    for (int s = 0; s < 4; ++s) {
      float4 lo = *reinterpret_cast<const float4*>(xp + s * 32 + g * 8);
      float4 hi = *reinterpret_cast<const float4*>(xp + s * 32 + g * 8 + 4);
      half8 h;
      h[0] = (_Float16)lo.x; h[1] = (_Float16)lo.y; h[2] = (_Float16)lo.z; h[3] = (_Float16)lo.w;
      h[4] = (_Float16)hi.x; h[5] = (_Float16)hi.y; h[6] = (_Float16)hi.z; h[7] = (_Float16)hi.w;
      a[s] = h;
    }
#pragma unroll
    for (int s = 0; s < 4; ++s)
      a[4 + s] = *reinterpret_cast<const half8*>(tile + lds_swz(r, (s * 32 + g * 8) * 2));
  }
  __syncthreads();  // agg-tile reads done before layer-1 overwrites tile

  f32x4 zero = {0.f, 0.f, 0.f, 0.f};
  {
    f32x4 acc1[2];
    acc1[0] = zero; acc1[1] = zero;
#pragma unroll
    for (int fi = 0; fi < 2; ++fi) {
      int f = wid * 2 + fi;
#pragma unroll
      for (int s = 0; s < 8; ++s) {
        half8 bfrag = *reinterpret_cast<const half8*>(U1pk + (size_t)((s * 8 + f) * 64 + lane) * 8);
        acc1[fi] = __builtin_amdgcn_mfma_f32_16x16x32_f16(a[s], bfrag, acc1[fi], 0, 0, 0);
      }
    }
#pragma unroll
    for (int fi = 0; fi < 2; ++fi) {
      int f = wid * 2 + fi;
      int col = f * 16 + r;
      float bv = bu1[col];
#pragma unroll
      for (int j = 0; j < 4; ++j) {
        int rl = g * 4 + j;
        float gv = gelu_exact(acc1[fi][j] + bv);
        *reinterpret_cast<_Float16*>(tile + lds_swz(rl, col * 2)) = (_Float16)gv;
      }
    }
  }
  __syncthreads();  // layer-1 tile complete before layer-2 reads

  {
    half8 a2[4];
#pragma unroll
    for (int s = 0; s < 4; ++s) a2[s] = hzero;
    if (r < 8) {
#pragma unroll
      for (int s = 0; s < 4; ++s)
        a2[s] = *reinterpret_cast<const half8*>(tile + lds_swz(r, (s * 32 + g * 8) * 2));
    }
    f32x4 acc2[2];
    acc2[0] = zero; acc2[1] = zero;
#pragma unroll
    for (int fi = 0; fi < 2; ++fi) {
      int f = wid * 2 + fi;
#pragma unroll
      for (int s = 0; s < 4; ++s) {
        half8 bfrag = *reinterpret_cast<const half8*>(U2pk + (size_t)((s * 8 + f) * 64 + lane) * 8);
        acc2[fi] = __builtin_amdgcn_mfma_f32_16x16x32_f16(a2[s], bfrag, acc2[fi], 0, 0, 0);
      }
    }
#pragma unroll
    for (int fi = 0; fi < 2; ++fi) {
      int f = wid * 2 + fi;
      int col = f * 16 + r;
      float bv = bu2[col];
#pragma unroll
      for (int j = 0; j < 4; ++j) {
        int rloc = g * 4 + j;
        if (rloc < 8)
          out[(size_t)(row0 + rloc) * DIM + col] = gelu_exact(acc2[fi][j] + bv);
      }
    }
  }
}

extern "C" void kernel_launch(void* const* d_in, const int* in_sizes, int n_in,
                              void* d_out, int out_size, void* d_ws, size_t ws_size,
                              hipStream_t stream) {
  const float* x = (const float*)d_in[0];
  const int* edges = (const int*)d_in[1];
  const float* ew = (const float*)d_in[2];

  const int* node_idx = edges;            // edges[0, :]
  const int* nbr_idx = edges + N_EDGES;   // edges[1, :]

  char* wsp = (char*)d_ws;
  auto alloc = [&](size_t bytes) {
    char* p = wsp;
    wsp += (bytes + 255) & ~(size_t)255;
    return p;
  };
  unsigned char* M8 = (unsigned char*)alloc((size_t)N_NODES * DIM);
  _Float16* W1pk = (_Float16*)alloc(128 * 128 * 2);
  _Float16* W2pk = (_Float16*)alloc(128 * 128 * 2);
  _Float16* U1pk = (_Float16*)alloc(256 * 128 * 2);
  _Float16* U2pk = (_Float16*)alloc(128 * 128 * 2);
  float* b1f = (float*)alloc(128 * 4);
  float* b2f = (float*)alloc(128 * 4);
  float* bu1 = (float*)alloc(128 * 4);
  float* bu2 = (float*)alloc(128 * 4);
  int* histq = (int*)alloc(4 * QPAD * 4);
  int* qtot = (int*)alloc(4 * 4);
  int* row_start = (int*)alloc((N_NODES + 1) * 4);
  unsigned char* part = (unsigned char*)alloc((size_t)PART_BLOCKS * N_NODES);
  uint2* edge_s = (uint2*)alloc((size_t)N_EDGES * 8);

  FoldAll fa;
  fa.g[0] = (const float*)d_in[3];  fa.bb[0] = (const float*)d_in[4];
  fa.m[0] = (const float*)d_in[5];  fa.v[0] = (const float*)d_in[6];
  fa.W[0] = (const float*)d_in[7];  fa.bias[0] = (const float*)d_in[8];
  fa.g[1] = (const float*)d_in[9];  fa.bb[1] = (const float*)d_in[10];
  fa.m[1] = (const float*)d_in[11]; fa.v[1] = (const float*)d_in[12];
  fa.W[1] = (const float*)d_in[13]; fa.bias[1] = (const float*)d_in[14];
  fa.g[2] = (const float*)d_in[15]; fa.bb[2] = (const float*)d_in[16];
  fa.m[2] = (const float*)d_in[17]; fa.v[2] = (const float*)d_in[18];
  fa.W[2] = (const float*)d_in[19]; fa.bias[2] = (const float*)d_in[20];
  fa.g[3] = (const float*)d_in[21]; fa.bb[3] = (const float*)d_in[22];
  fa.m[3] = (const float*)d_in[23]; fa.v[3] = (const float*)d_in[24];
  fa.W[3] = (const float*)d_in[25]; fa.bias[3] = (const float*)d_in[26];
  fa.pk[0] = W1pk; fa.pk[1] = W2pk; fa.pk[2] = U1pk; fa.pk[3] = U2pk;
  fa.bf[0] = b1f; fa.bf[1] = b2f; fa.bf[2] = bu1; fa.bf[3] = bu2;
  fa.din[0] = 128; fa.din[1] = 128; fa.din[2] = 256; fa.din[3] = 128;
  fa.S[0] = 4; fa.S[1] = 4; fa.S[2] = 8; fa.S[3] = 4;

  fold_hist_kernel<<<44 + PART_BLOCKS, 256, 0, stream>>>(fa, node_idx, part, histq, qtot);
  merge_msg_kernel<<<40 + MSG64_BLOCKS, 256, 0, stream>>>(
      part, histq, qtot, x, W1pk, b1f, W2pk, b2f, M8);
  scatter_kernel<<<SCAT_GRID, 256, 0, stream>>>(
      node_idx, nbr_idx, ew, histq, qtot, part, edge_s, row_start);
  spmm_update_kernel<<<SU_BLOCKS, 256, 0, stream>>>(
      row_start, edge_s, M8, x, U1pk, bu1, U2pk, bu2, (float*)d_out);
}

// Round 16
// 94.615 us; speedup vs baseline: 2.0830x; 1.0122x over previous
//
#include <hip/hip_runtime.h>
#include <hip/hip_bf16.h>
#include <hip/hip_fp16.h>
#include <math.h>

#define N_NODES 10000
#define DIM 128
#define N_EDGES 640000
#define BN_EPS 1e-3f

#define QUARTER 2500
#define QPAD 3072             // padded quarter stride
#define PART_BLOCKS 250       // edge chunks: 640000 / 2560
#define EDGES_PER_PART 2560
#define SCAT_GRID 1000        // 250 chunks x 4 quarters
#define MSG64_BLOCKS 157      // ceil(10000 / 64)
#define SU_BLOCKS 1250        // 10000 / 8

typedef _Float16 half8 __attribute__((ext_vector_type(8)));
typedef float f32x4 __attribute__((ext_vector_type(4)));

__device__ __forceinline__ float gelu_exact(float x) {
  return 0.5f * x * (1.0f + erff(x * 0.70710678f));
}

// Swizzled LDS tile: [16 rows][128 cols] f16, row stride 256 B.
__device__ __forceinline__ int lds_swz(int row, int colbyte) {
  return ((row * 256 + colbyte) ^ ((row & 7) << 4));
}

// f32 -> fp8 e4m3 (OCP on gfx950), single value via HW pack instruction.
__device__ __forceinline__ unsigned char f32_to_fp8(float v) {
  unsigned pk = __builtin_amdgcn_cvt_pk_fp8_f32(v, v, 0, false);
  return (unsigned char)(pk & 0xffu);
}

// Pack (nbr, weight) into one u32: high 16 = nbr, low 16 = bf16(w) (RTN).
__device__ __forceinline__ unsigned pack_edge(int nbr, float w) {
  return ((unsigned)nbr << 16) | ((__float_as_uint(w) + 0x8000u) >> 16);
}

struct FoldAll {
  const float* g[4];
  const float* bb[4];
  const float* m[4];
  const float* v[4];
  const float* W[4];
  const float* bias[4];
  _Float16* pk[4];
  float* bf[4];
  int din[4];
  int S[4];  // K/32
};

// K1: grid = 44 + PART_BLOCKS blocks x 256 thr.
// b in [0,40): pack W fragments (f16, B-frag layout, BN-scale folded).
// b in [40,44): folded bias; block 40+p also zeroes qtot (p==0) and the
//   padded tail of histq quarter p.
// b >= 44: single-pass PACKED-u16 LDS histogram (20 KB) of chunk eb ->
//   u8 partial rows in quarter-major layout part[(q*250+eb)*2500 + bp].
__global__ __launch_bounds__(256) void fold_hist_kernel(FoldAll fa,
                                                        const int* __restrict__ node_idx,
                                                        unsigned char* __restrict__ part,
                                                        int* __restrict__ histq,
                                                        int* __restrict__ qtot) {
  __shared__ int lh2[N_NODES / 2];
  __shared__ float t_sh[256];
  __shared__ float bpart[128];
  int b = blockIdx.x, t = threadIdx.x;
  if (b >= 44) {
    int eb = b - 44;
    for (int i = t; i < N_NODES / 2; i += 256) lh2[i] = 0;
    __syncthreads();
    int base0 = eb * EDGES_PER_PART;
#pragma unroll
    for (int s = 0; s < 3; ++s) {
      int off = s * 1024 + t * 4;
      if (off < EDGES_PER_PART) {
        int4 vv = *reinterpret_cast<const int4*>(&node_idx[base0 + off]);
        atomicAdd(&lh2[vv.x >> 1], 1 << ((vv.x & 1) << 4));
        atomicAdd(&lh2[vv.y >> 1], 1 << ((vv.y & 1) << 4));
        atomicAdd(&lh2[vv.z >> 1], 1 << ((vv.z & 1) << 4));
        atomicAdd(&lh2[vv.w >> 1], 1 << ((vv.w & 1) << 4));
      }
    }
    __syncthreads();
    for (int i = t; i < N_NODES; i += 256) {
      int c = (lh2[i >> 1] >> ((i & 1) << 4)) & 0xFFFF;
      int q = i / QUARTER;
      int bp = i - q * QUARTER;
      part[(size_t)(q * PART_BLOCKS + eb) * QUARTER + bp] = (unsigned char)c;
    }
    return;
  }
  if (b >= 40) {
    int p = b - 40;
    if (p == 0 && t < 4) qtot[t] = 0;
    for (int i = t; i < QPAD - QUARTER; i += 256) histq[p * QPAD + QUARTER + i] = 0;
    int din = fa.din[p];
    const float* W = fa.W[p];
    for (int k = t; k < din; k += 256) {
      float sc = fa.g[p][k] * rsqrtf(fa.v[p][k] + BN_EPS);
      t_sh[k] = fa.bb[p][k] - fa.m[p][k] * sc;
    }
    __syncthreads();
    int j = t & 127, kh = t >> 7;
    int half = din >> 1;
    float acc = 0.f;
    for (int k = kh * half; k < (kh + 1) * half; ++k)
      acc = fmaf(t_sh[k], W[k * 128 + j], acc);
    if (kh == 1) bpart[j] = acc;
    __syncthreads();
    if (kh == 0) fa.bf[p][j] = acc + bpart[j] + fa.bias[p][j];
    return;
  }
  int p, lf;
  if (b < 8)       { p = 0; lf = b * 256 + t; }
  else if (b < 16) { p = 1; lf = (b - 8) * 256 + t; }
  else if (b < 32) { p = 2; lf = (b - 16) * 256 + t; }
  else             { p = 3; lf = (b - 32) * 256 + t; }
  int S = fa.S[p];
  int l = lf & 63;
  int fs = lf >> 6;
  int f = fs & 7, s = fs >> 3;
  if (s >= S) return;
  const float* W = fa.W[p];
  const float* g = fa.g[p];
  const float* v = fa.v[p];
  int k0 = s * 32 + (l >> 4) * 8;
  int col = f * 16 + (l & 15);
  half8 h;
#pragma unroll
  for (int i = 0; i < 8; ++i) {
    int k = k0 + i;
    float sc = g[k] * rsqrtf(v[k] + BN_EPS);
    h[i] = (_Float16)(sc * W[k * 128 + col]);
  }
  *reinterpret_cast<half8*>(fa.pk[p] + (size_t)lf * 8) = h;
}

// K2: grid = 40 + MSG64_BLOCKS blocks x 256 thr.
// b in [0,40): merge — per bin, prefix over 250 u8 partials; total ->
//   histq[q*QPAD + bp]; per-quarter totals into qtot (LDS reduce + atomics).
// b >= 40: per-node message via f16 MFMA, 4 waves x 16 rows; M stored fp8.
__global__ __launch_bounds__(256) void merge_msg_kernel(
    unsigned char* __restrict__ part, int* __restrict__ histq,
    int* __restrict__ qtot,
    const float* __restrict__ x,
    const _Float16* __restrict__ W1pk, const float* __restrict__ b1f,
    const _Float16* __restrict__ W2pk, const float* __restrict__ b2f,
    unsigned char* __restrict__ M8) {
  __shared__ char lds_raw[4 * 4096];
  __shared__ int qsum[4];
  int b = blockIdx.x, t = threadIdx.x;
  if (b < 40) {
    int bin = b * 256 + t;
    int sum = 0;
    int q = 0;
    if (bin < N_NODES) {
      q = bin / QUARTER;
      int bp = bin - q * QUARTER;
      unsigned char* col = part + (size_t)q * PART_BLOCKS * QUARTER + bp;
#pragma unroll
      for (int c = 0; c < PART_BLOCKS; c += 25) {
        int vals[25];
#pragma unroll
        for (int i = 0; i < 25; ++i) vals[i] = col[(size_t)(c + i) * QUARTER];
#pragma unroll
        for (int i = 0; i < 25; ++i) {
          col[(size_t)(c + i) * QUARTER] = (unsigned char)sum;
          sum += vals[i];
        }
      }
      histq[q * QPAD + bp] = sum;
    }
    if (t < 4) qsum[t] = 0;
    __syncthreads();
    if (bin < N_NODES) atomicAdd(&qsum[q], sum);
    __syncthreads();
    if (t < 4) atomicAdd(&qtot[t], qsum[t]);
    return;
  }
  int wid = t >> 6, lane = t & 63;
  int r = lane & 15, g = lane >> 4;
  int row0 = (b - 40) * 64 + wid * 16;
  char* lbase = lds_raw + wid * 4096;

  int arow = row0 + r;
  if (arow > N_NODES - 1) arow = N_NODES - 1;
  const float* xp = x + (size_t)arow * DIM;

  half8 a[4];
#pragma unroll
  for (int s = 0; s < 4; ++s) {
    float4 lo = *reinterpret_cast<const float4*>(xp + s * 32 + g * 8);
    float4 hi = *reinterpret_cast<const float4*>(xp + s * 32 + g * 8 + 4);
    half8 h;
    h[0] = (_Float16)lo.x; h[1] = (_Float16)lo.y; h[2] = (_Float16)lo.z; h[3] = (_Float16)lo.w;
    h[4] = (_Float16)hi.x; h[5] = (_Float16)hi.y; h[6] = (_Float16)hi.z; h[7] = (_Float16)hi.w;
    a[s] = h;
  }

  f32x4 zero = {0.f, 0.f, 0.f, 0.f};
  f32x4 acc[8];
#pragma unroll
  for (int f = 0; f < 8; ++f) acc[f] = zero;
#pragma unroll
  for (int f = 0; f < 8; ++f)
#pragma unroll
    for (int s = 0; s < 4; ++s) {
      half8 bfrag = *reinterpret_cast<const half8*>(W1pk + (size_t)((s * 8 + f) * 64 + lane) * 8);
      acc[f] = __builtin_amdgcn_mfma_f32_16x16x32_f16(a[s], bfrag, acc[f], 0, 0, 0);
    }

#pragma unroll
  for (int f = 0; f < 8; ++f) {
    int col = f * 16 + r;
    float bv = b1f[col];
#pragma unroll
    for (int j = 0; j < 4; ++j) {
      int rl = g * 4 + j;
      float gv = gelu_exact(acc[f][j] + bv);
      *reinterpret_cast<_Float16*>(lbase + lds_swz(rl, col * 2)) = (_Float16)gv;
    }
  }

  half8 a2[4];
#pragma unroll
  for (int s = 0; s < 4; ++s)
    a2[s] = *reinterpret_cast<const half8*>(lbase + lds_swz(r, (s * 32 + g * 8) * 2));

  f32x4 acc2[8];
#pragma unroll
  for (int f = 0; f < 8; ++f) acc2[f] = zero;
#pragma unroll
  for (int f = 0; f < 8; ++f)
#pragma unroll
    for (int s = 0; s < 4; ++s) {
      half8 bfrag = *reinterpret_cast<const half8*>(W2pk + (size_t)((s * 8 + f) * 64 + lane) * 8);
      acc2[f] = __builtin_amdgcn_mfma_f32_16x16x32_f16(a2[s], bfrag, acc2[f], 0, 0, 0);
    }

#pragma unroll
  for (int f = 0; f < 8; ++f) {
    int col = f * 16 + r;
    float bv = b2f[col];
#pragma unroll
    for (int j = 0; j < 4; ++j) {
      int grow = row0 + g * 4 + j;
      if (grow < N_NODES)
        M8[(size_t)grow * DIM + col] = f32_to_fp8(gelu_exact(acc2[f][j] + bv));
    }
  }
}

// K3: quarter-partitioned scatter, grid = 1000 blocks x 256 thr.
// Block (eb, q): scans ONLY its quarter (3072 padded bins, 3 int4/thread),
// offsets by qpre from qtot; eb==0 blocks write row_start for their quarter;
// then scatters chunk eb's edges (4-byte packed records) via LDS atomics.
__global__ __launch_bounds__(256) void scatter_kernel(
    const int* __restrict__ node_idx, const int* __restrict__ nbr_idx,
    const float* __restrict__ ew, const int* __restrict__ histq,
    const int* __restrict__ qtot,
    const unsigned char* __restrict__ part, unsigned* __restrict__ edge_s,
    int* __restrict__ row_start) {
  __shared__ int cur[QUARTER];
  __shared__ int sums[256];
  int bk = blockIdx.x, t = threadIdx.x;
  int eb = bk >> 2;
  int q = bk & 3;
  int qbase = q * QUARTER;
  const int PER = 12;  // 256 * 12 = 3072 = QPAD
  int i0 = t * PER;
  const int* hq = histq + q * QPAD;
  int lh[PER];
  int total = 0;
#pragma unroll
  for (int i = 0; i < PER; i += 4) {
    int4 h4 = *reinterpret_cast<const int4*>(&hq[i0 + i]);
    lh[i] = h4.x; lh[i + 1] = h4.y; lh[i + 2] = h4.z; lh[i + 3] = h4.w;
    total += h4.x + h4.y + h4.z + h4.w;
  }
  sums[t] = total;
  __syncthreads();
  for (int off = 1; off < 256; off <<= 1) {
    int v = (t >= off) ? sums[t - off] : 0;
    __syncthreads();
    sums[t] += v;
    __syncthreads();
  }
  int q0 = qtot[0], q1 = qtot[1], q2 = qtot[2];
  int qpre = (q >= 1 ? q0 : 0) + (q >= 2 ? q1 : 0) + (q >= 3 ? q2 : 0);
  int running = qpre + sums[t] - total;  // global exclusive prefix at bin i0
  const unsigned char* prow = part + (size_t)(q * PART_BLOCKS + eb) * QUARTER;
  bool wrs = (eb == 0);
#pragma unroll
  for (int i = 0; i < PER; ++i) {
    int idx = i0 + i;
    if (idx < QUARTER) {
      cur[idx] = running + (int)prow[idx];
      if (wrs) row_start[qbase + idx] = running;
      running += lh[i];
    }
  }
  if (bk == 0 && t == 0) row_start[N_NODES] = N_EDGES;
  __syncthreads();

  int base0 = eb * EDGES_PER_PART;
#pragma unroll
  for (int s = 0; s < 3; ++s) {
    int off = s * 1024 + t * 4;
    if (off >= EDGES_PER_PART) break;
    int base = base0 + off;
    int4 ni = *reinterpret_cast<const int4*>(&node_idx[base]);
    int4 nb = *reinterpret_cast<const int4*>(&nbr_idx[base]);
    float4 wv = *reinterpret_cast<const float4*>(&ew[base]);
    unsigned d0 = (unsigned)(ni.x - qbase);
    unsigned d1 = (unsigned)(ni.y - qbase);
    unsigned d2 = (unsigned)(ni.z - qbase);
    unsigned d3 = (unsigned)(ni.w - qbase);
    if (d0 < QUARTER) {
      int p0 = atomicAdd(&cur[d0], 1);
      edge_s[p0] = pack_edge(nb.x, wv.x);
    }
    if (d1 < QUARTER) {
      int p1 = atomicAdd(&cur[d1], 1);
      edge_s[p1] = pack_edge(nb.y, wv.y);
    }
    if (d2 < QUARTER) {
      int p2 = atomicAdd(&cur[d2], 1);
      edge_s[p2] = pack_edge(nb.z, wv.z);
    }
    if (d3 < QUARTER) {
      int p3 = atomicAdd(&cur[d3], 1);
      edge_s[p3] = pack_edge(nb.w, wv.w);
    }
  }
}

// K4: fused spmm + update. grid = 1250 blocks x 256 thr, 8 rows/block.
// Phase 1: 32 thr/row = 4 edge-slices x 8 col-subs, 16 B fp8 gathers,
//   4-edge batches with next-batch edge prefetch; packed 4 B edge records
//   (nbr<<16 | bf16 w); HW cvt_pk_f32_fp8 dequant; slice partials via f32
//   LDS scratch; agg f16 into swizzled tile rows 0..7.
// Phase 2 (4 waves): MFMA on a 16-row tile with rows 8-15 zero-padded;
//   U1/U2 output fragments split 2-per-wave.
__global__ __launch_bounds__(256) void spmm_update_kernel(
    const int* __restrict__ row_start, const unsigned* __restrict__ edge_s,
    const unsigned char* __restrict__ M8, const float* __restrict__ x,
    const _Float16* __restrict__ U1pk, const float* __restrict__ bu1,
    const _Float16* __restrict__ U2pk, const float* __restrict__ bu2,
    float* __restrict__ out) {
  __shared__ float scratch[3][8][128];
  __shared__ char tile[4096];
  int t = threadIdx.x;
  int row0 = blockIdx.x * 8;

  {
    int r = t >> 5;       // 0..7 local row
    int q = t & 31;
    int slice = q >> 3;   // 0..3
    int sub = q & 7;      // cols sub*16 .. sub*16+15
    int row = row0 + r;
    int s = row_start[row];
    int e_end = row_start[row + 1];
    float acc[16];
#pragma unroll
    for (int c = 0; c < 16; ++c) acc[c] = 0.f;
    const unsigned char* Mb = M8 + sub * 16;
    int base = s + slice * 4;
    unsigned pk[4];
#pragma unroll
    for (int k = 0; k < 4; ++k) {
      int e = base + k;
      pk[k] = edge_s[(e < e_end) ? e : s];
      if (e >= e_end) pk[k] &= 0xFFFF0000u;  // weight -> 0 for padded lanes
    }
    for (; base < e_end; base += 16) {
      unsigned pkn[4];
      int nb = base + 16;
#pragma unroll
      for (int k = 0; k < 4; ++k) {
        int e = nb + k;
        pkn[k] = edge_s[(e < e_end) ? e : s];
        if (e >= e_end) pkn[k] &= 0xFFFF0000u;
      }
      uint4 raw[4];
#pragma unroll
      for (int k = 0; k < 4; ++k)
        raw[k] = *reinterpret_cast<const uint4*>(Mb + (size_t)(pk[k] >> 16) * DIM);
#pragma unroll
      for (int k = 0; k < 4; ++k) {
        float w = __uint_as_float(pk[k] << 16);
        const unsigned* u32s = reinterpret_cast<const unsigned*>(&raw[k]);
#pragma unroll
        for (int qq = 0; qq < 4; ++qq) {
          auto f01 = __builtin_amdgcn_cvt_pk_f32_fp8(u32s[qq], false);
          auto f23 = __builtin_amdgcn_cvt_pk_f32_fp8(u32s[qq], true);
          acc[4 * qq + 0] = fmaf(w, f01[0], acc[4 * qq + 0]);
          acc[4 * qq + 1] = fmaf(w, f01[1], acc[4 * qq + 1]);
          acc[4 * qq + 2] = fmaf(w, f23[0], acc[4 * qq + 2]);
          acc[4 * qq + 3] = fmaf(w, f23[1], acc[4 * qq + 3]);
        }
      }
#pragma unroll
      for (int k = 0; k < 4; ++k) pk[k] = pkn[k];
    }
    if (slice >= 1) {
      float* dst = &scratch[slice - 1][r][sub * 16];
      *reinterpret_cast<float4*>(dst) = make_float4(acc[0], acc[1], acc[2], acc[3]);
      *reinterpret_cast<float4*>(dst + 4) = make_float4(acc[4], acc[5], acc[6], acc[7]);
      *reinterpret_cast<float4*>(dst + 8) = make_float4(acc[8], acc[9], acc[10], acc[11]);
      *reinterpret_cast<float4*>(dst + 12) = make_float4(acc[12], acc[13], acc[14], acc[15]);
    }
    __syncthreads();
    if (slice == 0) {
#pragma unroll
      for (int sl = 0; sl < 3; ++sl) {
        const float* src = &scratch[sl][r][sub * 16];
#pragma unroll
        for (int c = 0; c < 16; c += 4) {
          float4 o = *reinterpret_cast<const float4*>(src + c);
          acc[c] += o.x; acc[c + 1] += o.y; acc[c + 2] += o.z; acc[c + 3] += o.w;
        }
      }
      int cnt = e_end - s;
      float inv = 1.f / (float)(cnt > 0 ? cnt : 1);
      half8 hlo, hhi;
#pragma unroll
      for (int c = 0; c < 8; ++c) hlo[c] = (_Float16)(acc[c] * inv);
#pragma unroll
      for (int c = 0; c < 8; ++c) hhi[c] = (_Float16)(acc[8 + c] * inv);
      *reinterpret_cast<half8*>(tile + lds_swz(r, sub * 32)) = hlo;
      *reinterpret_cast<half8*>(tile + lds_swz(r, sub * 32 + 16)) = hhi;
    }
  }
  __syncthreads();

  int wid = t >> 6, lane = t & 63;
  int r = lane & 15, g = lane >> 4;
  half8 hzero;
#pragma unroll
  for (int i = 0; i < 8; ++i) hzero[i] = (_Float16)0.f;

  half8 a[8];
#pragma unroll
  for (int s = 0; s < 8; ++s) a[s] = hzero;
  if (r < 8) {
    const float* xp = x + (size_t)(row0 + r) * DIM;
#pragma unroll
    for (int s = 0; s < 4; ++s) {
      float4 lo = *reinterpret_cast<const float4*>(xp + s * 32 + g * 8);
      float4 hi = *reinterpret_cast<const float4*>(xp + s * 32 + g * 8 + 4);
      half8 h;
      h[0] = (_Float16)lo.x; h[1] = (_Float16)lo.y; h[2] = (_Float16)lo.z; h[3] = (_Float16)lo.w;
      h[4] = (_Float16)hi.x; h[5] = (_Float16)hi.y; h[6] = (_Float16)hi.z; h[7] = (_Float16)hi.w;
      a[s] = h;
    }
#pragma unroll
    for (int s = 0; s < 4; ++s)
      a[4 + s] = *reinterpret_cast<const half8*>(tile + lds_swz(r, (s * 32 + g * 8) * 2));
  }
  __syncthreads();  // agg-tile reads done before layer-1 overwrites tile

  f32x4 zero = {0.f, 0.f, 0.f, 0.f};
  {
    f32x4 acc1[2];
    acc1[0] = zero; acc1[1] = zero;
#pragma unroll
    for (int fi = 0; fi < 2; ++fi) {
      int f = wid * 2 + fi;
#pragma unroll
      for (int s = 0; s < 8; ++s) {
        half8 bfrag = *reinterpret_cast<const half8*>(U1pk + (size_t)((s * 8 + f) * 64 + lane) * 8);
        acc1[fi] = __builtin_amdgcn_mfma_f32_16x16x32_f16(a[s], bfrag, acc1[fi], 0, 0, 0);
      }
    }
#pragma unroll
    for (int fi = 0; fi < 2; ++fi) {
      int f = wid * 2 + fi;
      int col = f * 16 + r;
      float bv = bu1[col];
#pragma unroll
      for (int j = 0; j < 4; ++j) {
        int rl = g * 4 + j;
        float gv = gelu_exact(acc1[fi][j] + bv);
        *reinterpret_cast<_Float16*>(tile + lds_swz(rl, col * 2)) = (_Float16)gv;
      }
    }
  }
  __syncthreads();  // layer-1 tile complete before layer-2 reads

  {
    half8 a2[4];
#pragma unroll
    for (int s = 0; s < 4; ++s) a2[s] = hzero;
    if (r < 8) {
#pragma unroll
      for (int s = 0; s < 4; ++s)
        a2[s] = *reinterpret_cast<const half8*>(tile + lds_swz(r, (s * 32 + g * 8) * 2));
    }
    f32x4 acc2[2];
    acc2[0] = zero; acc2[1] = zero;
#pragma unroll
    for (int fi = 0; fi < 2; ++fi) {
      int f = wid * 2 + fi;
#pragma unroll
      for (int s = 0; s < 4; ++s) {
        half8 bfrag = *reinterpret_cast<const half8*>(U2pk + (size_t)((s * 8 + f) * 64 + lane) * 8);
        acc2[fi] = __builtin_amdgcn_mfma_f32_16x16x32_f16(a2[s], bfrag, acc2[fi], 0, 0, 0);
      }
    }
#pragma unroll
    for (int fi = 0; fi < 2; ++fi) {
      int f = wid * 2 + fi;
      int col = f * 16 + r;
      float bv = bu2[col];
#pragma unroll
      for (int j = 0; j < 4; ++j) {
        int rloc = g * 4 + j;
        if (rloc < 8)
          out[(size_t)(row0 + rloc) * DIM + col] = gelu_exact(acc2[fi][j] + bv);
      }
    }
  }
}

extern "C" void kernel_launch(void* const* d_in, const int* in_sizes, int n_in,
                              void* d_out, int out_size, void* d_ws, size_t ws_size,
                              hipStream_t stream) {
  const float* x = (const float*)d_in[0];
  const int* edges = (const int*)d_in[1];
  const float* ew = (const float*)d_in[2];

  const int* node_idx = edges;            // edges[0, :]
  const int* nbr_idx = edges + N_EDGES;   // edges[1, :]

  char* wsp = (char*)d_ws;
  auto alloc = [&](size_t bytes) {
    char* p = wsp;
    wsp += (bytes + 255) & ~(size_t)255;
    return p;
  };
  unsigned char* M8 = (unsigned char*)alloc((size_t)N_NODES * DIM);
  _Float16* W1pk = (_Float16*)alloc(128 * 128 * 2);
  _Float16* W2pk = (_Float16*)alloc(128 * 128 * 2);
  _Float16* U1pk = (_Float16*)alloc(256 * 128 * 2);
  _Float16* U2pk = (_Float16*)alloc(128 * 128 * 2);
  float* b1f = (float*)alloc(128 * 4);
  float* b2f = (float*)alloc(128 * 4);
  float* bu1 = (float*)alloc(128 * 4);
  float* bu2 = (float*)alloc(128 * 4);
  int* histq = (int*)alloc(4 * QPAD * 4);
  int* qtot = (int*)alloc(4 * 4);
  int* row_start = (int*)alloc((N_NODES + 1) * 4);
  unsigned char* part = (unsigned char*)alloc((size_t)PART_BLOCKS * N_NODES);
  unsigned* edge_s = (unsigned*)alloc((size_t)N_EDGES * 4);

  FoldAll fa;
  fa.g[0] = (const float*)d_in[3];  fa.bb[0] = (const float*)d_in[4];
  fa.m[0] = (const float*)d_in[5];  fa.v[0] = (const float*)d_in[6];
  fa.W[0] = (const float*)d_in[7];  fa.bias[0] = (const float*)d_in[8];
  fa.g[1] = (const float*)d_in[9];  fa.bb[1] = (const float*)d_in[10];
  fa.m[1] = (const float*)d_in[11]; fa.v[1] = (const float*)d_in[12];
  fa.W[1] = (const float*)d_in[13]; fa.bias[1] = (const float*)d_in[14];
  fa.g[2] = (const float*)d_in[15]; fa.bb[2] = (const float*)d_in[16];
  fa.m[2] = (const float*)d_in[17]; fa.v[2] = (const float*)d_in[18];
  fa.W[2] = (const float*)d_in[19]; fa.bias[2] = (const float*)d_in[20];
  fa.g[3] = (const float*)d_in[21]; fa.bb[3] = (const float*)d_in[22];
  fa.m[3] = (const float*)d_in[23]; fa.v[3] = (const float*)d_in[24];
  fa.W[3] = (const float*)d_in[25]; fa.bias[3] = (const float*)d_in[26];
  fa.pk[0] = W1pk; fa.pk[1] = W2pk; fa.pk[2] = U1pk; fa.pk[3] = U2pk;
  fa.bf[0] = b1f; fa.bf[1] = b2f; fa.bf[2] = bu1; fa.bf[3] = bu2;
  fa.din[0] = 128; fa.din[1] = 128; fa.din[2] = 256; fa.din[3] = 128;
  fa.S[0] = 4; fa.S[1] = 4; fa.S[2] = 8; fa.S[3] = 4;

  fold_hist_kernel<<<44 + PART_BLOCKS, 256, 0, stream>>>(fa, node_idx, part, histq, qtot);
  merge_msg_kernel<<<40 + MSG64_BLOCKS, 256, 0, stream>>>(
      part, histq, qtot, x, W1pk, b1f, W2pk, b2f, M8);
  scatter_kernel<<<SCAT_GRID, 256, 0, stream>>>(
      node_idx, nbr_idx, ew, histq, qtot, part, edge_s, row_start);
  spmm_update_kernel<<<SU_BLOCKS, 256, 0, stream>>>(
      row_start, edge_s, M8, x, U1pk, bu1, U2pk, bu2, (float*)d_out);
}